// Round 5
// baseline (1284.218 us; speedup 1.0000x reference)
//
#include <hip/hip_runtime.h>

typedef unsigned short u16;
typedef _Float16 h16;
typedef __attribute__((ext_vector_type(8))) _Float16 h16x8;
typedef __attribute__((ext_vector_type(4))) _Float16 h16x4;
typedef __attribute__((ext_vector_type(4))) float f32x4;

__device__ __forceinline__ float b2f(u16 u) {
  unsigned x = ((unsigned)u) << 16;
  return __uint_as_float(x);
}
__device__ __forceinline__ unsigned fkey(float f) {
  unsigned b = __float_as_uint(f);
  return (b & 0x80000000u) ? ~b : (b | 0x80000000u);
}
__device__ __forceinline__ float unfkey(unsigned u) {
  unsigned b = (u & 0x80000000u) ? (u ^ 0x80000000u) : ~u;
  return __uint_as_float(b);
}
__device__ __forceinline__ f32x4 mfma16(h16x8 a, h16x8 b, f32x4 c) {
  return __builtin_amdgcn_mfma_f32_16x16x32_f16(a, b, c, 0, 0, 0);
}
__device__ __forceinline__ void gl_lds16(const void* g, void* l) {
  __builtin_amdgcn_global_load_lds(
      (const __attribute__((address_space(1))) unsigned*)g,
      (__attribute__((address_space(3))) unsigned*)l, 16, 0, 0);
}

// dtype detector (insurance): flag=1 means inputs are f32 (expected)
__global__ void detect_dtype(const u16* __restrict__ X, int* __restrict__ flag) {
  __shared__ int cnt;
  if (threadIdx.x == 0) cnt = 0;
  __syncthreads();
  int sane = 0;
#pragma unroll
  for (int j = 0; j < 16; ++j) {
    u16 u = X[(threadIdx.x * 16 + j) * 2];
    int e = (u >> 7) & 0xff;
    if (u == 0 || (e >= 112 && e <= 142)) sane++;
  }
  atomicAdd(&cnt, sane);
  __syncthreads();
  if (threadIdx.x == 0) *flag = (cnt < 3072) ? 1 : 0;
}

// split input to hi/lo fp16 + optional f32 copy
__global__ __launch_bounds__(256) void split_input3(
    const void* __restrict__ in, h16* __restrict__ hi, h16* __restrict__ lo,
    float* __restrict__ f32out, int n, const int* __restrict__ flag) {
  int f = *flag;
  int stride = gridDim.x * 256;
  for (int i = blockIdx.x * 256 + threadIdx.x; i < n; i += stride) {
    float x = f ? ((const float*)in)[i] : b2f(((const u16*)in)[i]);
    h16 h = (h16)x;
    hi[i] = h;
    lo[i] = (h16)(x - (float)h);
    if (f32out) f32out[i] = x;
  }
}

// split f32 buffer to hi/lo fp16
__global__ __launch_bounds__(256) void split_f32h(
    const float* __restrict__ in, h16* __restrict__ hi, h16* __restrict__ lo,
    int n) {
  int stride = gridDim.x * 256;
  for (int i = blockIdx.x * 256 + threadIdx.x; i < n; i += stride) {
    float x = in[i];
    h16 h = (h16)x;
    hi[i] = h;
    lo[i] = (h16)(x - (float)h);
  }
}

// canonicalize to f32 (theta, proj_b)
__global__ __launch_bounds__(256) void conv_f32(const void* __restrict__ in,
                                                float* __restrict__ out, int n,
                                                const int* __restrict__ flag) {
  int f = *flag;
  int stride = gridDim.x * 256;
  for (int i = blockIdx.x * 256 + threadIdx.x; i < n; i += stride)
    out[i] = f ? ((const float*)in)[i] : b2f(((const u16*)in)[i]);
}

// ---------------------------------------------------------------------------
// Split-precision NT GEMM (64x64 tile): C = alpha*(Ah Bh^T + Ah Bl^T + Al Bh^T)
// ---------------------------------------------------------------------------
template <bool BIAS>
__global__ __launch_bounds__(256) void gemm3_nt(
    const h16* __restrict__ Ah, const h16* __restrict__ Al,
    const h16* __restrict__ Bh, const h16* __restrict__ Bl,
    float* __restrict__ C, const float* __restrict__ bias, float alpha,
    int M, int Nc, int Kd, long batchA, long batchB, long batchC) {
  const h16* Abh = Ah + (size_t)blockIdx.z * batchA;
  const h16* Abl = Al + (size_t)blockIdx.z * batchA;
  const h16* Bbh = Bh + (size_t)blockIdx.z * batchB;
  const h16* Bbl = Bl + (size_t)blockIdx.z * batchB;
  float* Cb = C + (size_t)blockIdx.z * batchC;
  int bn = blockIdx.x, bm = blockIdx.y;
  int tid = threadIdx.x;
  int wid = tid >> 6, lane = tid & 63;
  __shared__ h16 Ash[64 * 40], Asl[64 * 40], Bsh[64 * 40], Bsl[64 * 40];
  f32x4 acc00 = {}, acc01 = {}, acc10 = {}, acc11 = {};
  int lr = tid >> 2;
  int lc = (tid & 3) << 3;
  size_t aoff = (size_t)(bm * 64 + lr) * Kd + lc;
  size_t boff = (size_t)(bn * 64 + lr) * Kd + lc;
  int wm = (wid & 1) * 32, wn = (wid >> 1) * 32;
  int fr = lane & 15;
  int fc = (lane >> 4) << 3;
  for (int k0 = 0; k0 < Kd; k0 += 32) {
    uint4 avh = *(const uint4*)(Abh + aoff + k0);
    uint4 avl = *(const uint4*)(Abl + aoff + k0);
    uint4 bvh = *(const uint4*)(Bbh + boff + k0);
    uint4 bvl = *(const uint4*)(Bbl + boff + k0);
    __syncthreads();
    *(uint4*)(Ash + lr * 40 + lc) = avh;
    *(uint4*)(Asl + lr * 40 + lc) = avl;
    *(uint4*)(Bsh + lr * 40 + lc) = bvh;
    *(uint4*)(Bsl + lr * 40 + lc) = bvl;
    __syncthreads();
    h16x8 a0h = *(const h16x8*)(Ash + (wm + fr) * 40 + fc);
    h16x8 a1h = *(const h16x8*)(Ash + (wm + 16 + fr) * 40 + fc);
    h16x8 b0h = *(const h16x8*)(Bsh + (wn + fr) * 40 + fc);
    h16x8 b1h = *(const h16x8*)(Bsh + (wn + 16 + fr) * 40 + fc);
    h16x8 a0l = *(const h16x8*)(Asl + (wm + fr) * 40 + fc);
    h16x8 a1l = *(const h16x8*)(Asl + (wm + 16 + fr) * 40 + fc);
    h16x8 b0l = *(const h16x8*)(Bsl + (wn + fr) * 40 + fc);
    h16x8 b1l = *(const h16x8*)(Bsl + (wn + 16 + fr) * 40 + fc);
    acc00 = mfma16(a0h, b0h, acc00);
    acc01 = mfma16(a0h, b1h, acc01);
    acc10 = mfma16(a1h, b0h, acc10);
    acc11 = mfma16(a1h, b1h, acc11);
    acc00 = mfma16(a0h, b0l, acc00);
    acc01 = mfma16(a0h, b1l, acc01);
    acc10 = mfma16(a1h, b0l, acc10);
    acc11 = mfma16(a1h, b1l, acc11);
    acc00 = mfma16(a0l, b0h, acc00);
    acc01 = mfma16(a0l, b1h, acc01);
    acc10 = mfma16(a1l, b0h, acc10);
    acc11 = mfma16(a1l, b1h, acc11);
  }
  int crow = (lane >> 4) << 2;
  int ccol = lane & 15;
  f32x4 accs[2][2] = {{acc00, acc01}, {acc10, acc11}};
#pragma unroll
  for (int i = 0; i < 2; ++i)
#pragma unroll
    for (int j = 0; j < 2; ++j) {
      int r0 = bm * 64 + wm + 16 * i + crow;
      int c0 = bn * 64 + wn + 16 * j + ccol;
#pragma unroll
      for (int rg = 0; rg < 4; ++rg) {
        float v = accs[i][j][rg] * alpha;
        if constexpr (BIAS) v += bias[c0];
        Cb[(size_t)(r0 + rg) * Nc + c0] = v;
      }
    }
}

// ---------------------------------------------------------------------------
// Split-precision NT GEMM, 128x128 tile, global_load_lds staging, XOR swizzle.
// Requires M,Nc mult of 128, Kd mult of 32.
// ---------------------------------------------------------------------------
__global__ __launch_bounds__(256) void gemm3_big(
    const h16* __restrict__ Ah, const h16* __restrict__ Al,
    const h16* __restrict__ Bh, const h16* __restrict__ Bl,
    float* __restrict__ C, float alpha, int M, int Nc, int Kd) {
  __shared__ h16 sAh[128 * 32], sAl[128 * 32], sBh[128 * 32], sBl[128 * 32];
  int tid = threadIdx.x, wid = tid >> 6, lane = tid & 63;
  int bm = blockIdx.y, bn = blockIdx.x;
  int srow = 32 * wid + (lane >> 2);  // +16h below
  int scnk = lane & 3;
  int fr = lane & 15, fcc = lane >> 4;
  f32x4 acc[4][4] = {};
  const h16* gA[2] = {Ah, Al};
  const h16* gB[2] = {Bh, Bl};
  h16* sA[2] = {sAh, sAl};
  h16* sB[2] = {sBh, sBl};
  int wm = (wid & 1) * 64, wn = (wid >> 1) * 64;
  for (int k0 = 0; k0 < Kd; k0 += 32) {
    __syncthreads();
#pragma unroll
    for (int h = 0; h < 2; ++h) {
      int r = srow + 16 * h;
      int cs = scnk ^ ((r >> 1) & 3);
      size_t goffA = (size_t)(bm * 128 + r) * Kd + k0 + cs * 8;
      size_t goffB = (size_t)(bn * 128 + r) * Kd + k0 + cs * 8;
      int loff = (32 * wid + 16 * h) * 32;
#pragma unroll
      for (int p = 0; p < 2; ++p) {
        gl_lds16(gA[p] + goffA, sA[p] + loff);
        gl_lds16(gB[p] + goffB, sB[p] + loff);
      }
    }
    __syncthreads();
    h16x8 fa[2][4], fb[2][4];
#pragma unroll
    for (int i = 0; i < 4; ++i) {
      int ra = wm + 16 * i + fr;
      int ca = (fcc ^ ((ra >> 1) & 3)) * 8;
      fa[0][i] = *(const h16x8*)(sAh + ra * 32 + ca);
      fa[1][i] = *(const h16x8*)(sAl + ra * 32 + ca);
      int rb = wn + 16 * i + fr;
      int cb = (fcc ^ ((rb >> 1) & 3)) * 8;
      fb[0][i] = *(const h16x8*)(sBh + rb * 32 + cb);
      fb[1][i] = *(const h16x8*)(sBl + rb * 32 + cb);
    }
#pragma unroll
    for (int i = 0; i < 4; ++i)
#pragma unroll
      for (int j = 0; j < 4; ++j) {
        acc[i][j] = mfma16(fa[0][i], fb[0][j], acc[i][j]);
        acc[i][j] = mfma16(fa[0][i], fb[1][j], acc[i][j]);
        acc[i][j] = mfma16(fa[1][i], fb[0][j], acc[i][j]);
      }
  }
  int crow = (lane >> 4) << 2, ccol = lane & 15;
#pragma unroll
  for (int i = 0; i < 4; ++i)
#pragma unroll
    for (int j = 0; j < 4; ++j) {
      int r0 = bm * 128 + wm + 16 * i + crow;
      int c0 = bn * 128 + wn + 16 * j + ccol;
#pragma unroll
      for (int rg = 0; rg < 4; ++rg)
        C[(size_t)(r0 + rg) * Nc + c0] = acc[i][j][rg] * alpha;
    }
}

// plain NT GEMM (fp16), accumulate with global-scale-ptr and per-row scale
template <bool ACCUM, bool SCALEPTR, bool ROWSCALE>
__global__ __launch_bounds__(256) void gemm_nt(
    const h16* __restrict__ A, const h16* __restrict__ B, float* __restrict__ C,
    const float* __restrict__ scptr, const float* __restrict__ rowsc,
    float alpha, int M, int Nc, int Kd) {
  int bn = blockIdx.x, bm = blockIdx.y;
  int tid = threadIdx.x;
  int wid = tid >> 6, lane = tid & 63;
  __shared__ h16 As[64 * 40];
  __shared__ h16 Bs[64 * 40];
  f32x4 acc00 = {}, acc01 = {}, acc10 = {}, acc11 = {};
  int lr = tid >> 2;
  int lc = (tid & 3) << 3;
  const h16* Ag = A + (size_t)(bm * 64 + lr) * Kd + lc;
  const h16* Bg = B + (size_t)(bn * 64 + lr) * Kd + lc;
  int wm = (wid & 1) * 32, wn = (wid >> 1) * 32;
  int fr = lane & 15;
  int fc = (lane >> 4) << 3;
  for (int k0 = 0; k0 < Kd; k0 += 32) {
    uint4 av = *(const uint4*)(Ag + k0);
    uint4 bv = *(const uint4*)(Bg + k0);
    __syncthreads();
    *(uint4*)(As + lr * 40 + lc) = av;
    *(uint4*)(Bs + lr * 40 + lc) = bv;
    __syncthreads();
    h16x8 a0 = *(const h16x8*)(As + (wm + fr) * 40 + fc);
    h16x8 a1 = *(const h16x8*)(As + (wm + 16 + fr) * 40 + fc);
    h16x8 b0 = *(const h16x8*)(Bs + (wn + fr) * 40 + fc);
    h16x8 b1 = *(const h16x8*)(Bs + (wn + 16 + fr) * 40 + fc);
    acc00 = mfma16(a0, b0, acc00);
    acc01 = mfma16(a0, b1, acc01);
    acc10 = mfma16(a1, b0, acc10);
    acc11 = mfma16(a1, b1, acc11);
  }
  float sc = alpha;
  if constexpr (SCALEPTR) sc *= *scptr;
  int crow = (lane >> 4) << 2;
  int ccol = lane & 15;
  f32x4 accs[2][2] = {{acc00, acc01}, {acc10, acc11}};
#pragma unroll
  for (int i = 0; i < 2; ++i)
#pragma unroll
    for (int j = 0; j < 2; ++j) {
      int r0 = bm * 64 + wm + 16 * i + crow;
      int c0 = bn * 64 + wn + 16 * j + ccol;
#pragma unroll
      for (int rg = 0; rg < 4; ++rg) {
        size_t off = (size_t)(r0 + rg) * Nc + c0;
        float v = accs[i][j][rg] * sc;
        if constexpr (ROWSCALE) v *= rowsc[r0 + rg];
        if constexpr (ACCUM)
          C[off] += v;
        else
          C[off] = v;
      }
    }
}

// 16-bit transpose (works for fp16/bf16 payloads)
__global__ __launch_bounds__(256) void transpose16(
    const u16* __restrict__ in, u16* __restrict__ out, int rows, int cols) {
  __shared__ u16 t[32][33];
  const u16* ib = in + (size_t)blockIdx.z * rows * cols;
  u16* ob = out + (size_t)blockIdx.z * rows * cols;
  int r0 = blockIdx.x * 32, c0 = blockIdx.y * 32;
  int tx = threadIdx.x & 31, ty = threadIdx.x >> 5;
#pragma unroll
  for (int i = 0; i < 32; i += 8)
    t[ty + i][tx] = ib[(size_t)(r0 + ty + i) * cols + c0 + tx];
  __syncthreads();
#pragma unroll
  for (int i = 0; i < 32; i += 8)
    ob[(size_t)(c0 + ty + i) * rows + r0 + tx] = t[tx][ty + i];
}

// scalars: w=softmax(alpha)->scal[0..3], rho=sigmoid(rho_raw)->scal[4]
__global__ void prep_scalars(const void* __restrict__ alpha,
                             const void* __restrict__ rho_raw,
                             float* __restrict__ scal,
                             const int* __restrict__ flag) {
  if (threadIdx.x == 0) {
    int f = *flag;
    float a[4], e[4], m = -1e30f, s = 0.f;
    for (int i = 0; i < 4; ++i) {
      a[i] = f ? ((const float*)alpha)[i] : b2f(((const u16*)alpha)[i]);
      m = fmaxf(m, a[i]);
    }
    for (int i = 0; i < 4; ++i) { e[i] = expf(a[i] - m); s += e[i]; }
    for (int i = 0; i < 4; ++i) scal[i] = e[i] / s;
    float rr = f ? ((const float*)rho_raw)[0] : b2f(((const u16*)rho_raw)[0]);
    scal[4] = 1.f / (1.f + expf(-rr));
  }
}

// ---------------------------------------------------------------------------
// fused per-row: max + top-16 (pass 1, no exp) then E=exp(v-m) fp16 + sum
// (pass 2, hw exp). E is UNNORMALIZED; 1/s applied in the PX GEMM epilogue.
// one wave per row
// ---------------------------------------------------------------------------
__global__ __launch_bounds__(256) void row_softmax_topk(
    const float* __restrict__ A, float* __restrict__ topv,
    int* __restrict__ topi, h16* __restrict__ E, float* __restrict__ rowSinv,
    int khead) {
  int wid = threadIdx.x >> 6, lane = threadIdx.x & 63;
  int row = blockIdx.x * 4 + wid;
  const float* arow = A + ((size_t)row << 12);
  float tv[16];
  int ti[16];
#pragma unroll
  for (int j = 0; j < 16; ++j) { tv[j] = -INFINITY; ti[j] = 0; }
  float m = -INFINITY;
  for (int t = 0; t < 64; ++t) {
    int c = lane + (t << 6);
    float v = arow[c];
    m = fmaxf(m, v);
    if (v > tv[15]) {
      tv[15] = v; ti[15] = c;
#pragma unroll
      for (int j = 15; j >= 1; --j) {
        if (tv[j] > tv[j - 1]) {
          float tf = tv[j]; tv[j] = tv[j - 1]; tv[j - 1] = tf;
          int tq = ti[j]; ti[j] = ti[j - 1]; ti[j - 1] = tq;
        }
      }
    }
  }
#pragma unroll
  for (int off = 32; off; off >>= 1) m = fmaxf(m, __shfl_xor(m, off));
  // pass 2: E + sum (rows are LLC-hot)
  h16* erow = E + ((size_t)row << 12);
  float s = 0.f;
  for (int t = 0; t < 16; ++t) {
    int c = (t << 8) + (lane << 2);
    float4 v = *(const float4*)(arow + c);
    float e0 = __expf(v.x - m), e1 = __expf(v.y - m);
    float e2 = __expf(v.z - m), e3 = __expf(v.w - m);
    s += (e0 + e1) + (e2 + e3);
    h16x4 hv = {(h16)e0, (h16)e1, (h16)e2, (h16)e3};
    *(h16x4*)(erow + c) = hv;
  }
#pragma unroll
  for (int off = 32; off; off >>= 1) s += __shfl_xor(s, off);
  if (lane == 0) rowSinv[row] = 1.f / s;
  // cross-lane top-16 merge (val desc, idx asc — jax tiebreak)
  float myv = 0.f; int myi = 0; float sum16 = 0.f;
  for (int r = 0; r < 16; ++r) {
    unsigned long long key =
        ((unsigned long long)fkey(tv[0]) << 32) | (unsigned)(~(unsigned)ti[0]);
    unsigned long long k2 = key;
#pragma unroll
    for (int off = 32; off; off >>= 1) {
      unsigned long long o = __shfl_xor(k2, off);
      if (o > k2) k2 = o;
    }
    float wv = unfkey((unsigned)(k2 >> 32));
    int wi = (int)(~(unsigned)(k2 & 0xffffffffu));
    if (key == k2) {
#pragma unroll
      for (int j = 0; j < 15; ++j) { tv[j] = tv[j + 1]; ti[j] = ti[j + 1]; }
      tv[15] = -INFINITY; ti[15] = 0;
    }
    sum16 += expf(wv - m);
    if (r == lane) { myv = wv; myi = wi; }
  }
  if (lane < 16) {
    size_t o = (((size_t)khead << 12) + row) * 16 + lane;
    topv[o] = expf(myv - m) / (sum16 + 1e-9f * s);
    topi[o] = myi;
  }
}

// ---------------------------------------------------------------------------
// sparse hypergraph: S_norm = C C^T, C[i,e]=Dvis[i]*val[e,p]*DeIS[e], i=idx[e,p]
// ---------------------------------------------------------------------------
__global__ __launch_bounds__(256) void edge_prep(
    const float* __restrict__ topv, const int* __restrict__ topi,
    float* __restrict__ Dv, int* __restrict__ cnt, float* __restrict__ DeIS) {
  int e = blockIdx.x * 256 + threadIdx.x;  // grid 64
  float s = 0.f;
#pragma unroll
  for (int p = 0; p < 16; ++p) {
    float v = topv[e * 16 + p];
    int i = topi[e * 16 + p];
    s += v;
    atomicAdd(&Dv[i], v);
    atomicAdd(&cnt[i], 1);
  }
  DeIS[e] = 1.0f / sqrtf(s + 1e-9f);
}

__global__ void dv_isqrt(const float* __restrict__ Dv, float* __restrict__ Dvis) {
  int i = blockIdx.x * 256 + threadIdx.x;
  Dvis[i] = sqrtf(1.0f / (Dv[i] + 1e-9f));
}

// exclusive scan of cnt[4096] -> rowptr[4097], cur=rowptr  (single block)
__global__ __launch_bounds__(256) void scan_rowptr(const int* __restrict__ cnt,
                                                   int* __restrict__ rowptr,
                                                   int* __restrict__ cur) {
  __shared__ int part[256];
  int tid = threadIdx.x;
  int base = tid * 16;
  int loc[16];
  int s = 0;
#pragma unroll
  for (int j = 0; j < 16; ++j) { loc[j] = s; s += cnt[base + j]; }
  part[tid] = s;
  __syncthreads();
  for (int off = 1; off < 256; off <<= 1) {
    int v = (tid >= off) ? part[tid - off] : 0;
    __syncthreads();
    part[tid] += v;
    __syncthreads();
  }
  int pre = (tid == 0) ? 0 : part[tid - 1];
#pragma unroll
  for (int j = 0; j < 16; ++j) {
    int r = pre + loc[j];
    rowptr[base + j] = r;
    cur[base + j] = r;
  }
  if (tid == 255) rowptr[4096] = part[255];
}

// fill per-edge cvals and CSR-transpose (colE, cvalR)
__global__ __launch_bounds__(256) void csr_fill(
    const float* __restrict__ topv, const int* __restrict__ topi,
    const float* __restrict__ Dvis, const float* __restrict__ DeIS,
    int* __restrict__ cur, float* __restrict__ cvals, int* __restrict__ colE,
    float* __restrict__ cvalR) {
  int e = blockIdx.x * 256 + threadIdx.x;  // grid 64
  float deis = DeIS[e];
#pragma unroll
  for (int p = 0; p < 16; ++p) {
    int i = topi[e * 16 + p];
    float c = Dvis[i] * topv[e * 16 + p] * deis;
    cvals[e * 16 + p] = c;
    int slot = atomicAdd(&cur[i], 1);
    colE[slot] = e;
    cvalR[slot] = c;
  }
}

// g[e] = sum_p c[e,p] * v[idx[e,p]]
__global__ __launch_bounds__(256) void spmv_edge(
    const float* __restrict__ cvals, const int* __restrict__ topi,
    const float* __restrict__ v, float* __restrict__ g) {
  int e = blockIdx.x * 256 + threadIdx.x;  // grid 64
  float acc = 0.f;
#pragma unroll
  for (int p = 0; p < 16; ++p)
    acc += cvals[e * 16 + p] * v[topi[e * 16 + p]];
  g[e] = acc;
}

// vout[i] = vin[i] - sum_{j in row i} cvalR[j]*g[colE[j]]   (L@v)
__global__ __launch_bounds__(256) void spmv_row(
    const int* __restrict__ rowptr, const int* __restrict__ colE,
    const float* __restrict__ cvalR, const float* __restrict__ g,
    const float* __restrict__ vin, float* __restrict__ vout) {
  int wid = threadIdx.x >> 6, lane = threadIdx.x & 63;
  int row = blockIdx.x * 4 + wid;  // grid 1024
  int s = rowptr[row], e = rowptr[row + 1];
  float acc = 0.f;
  for (int j = s + lane; j < e; j += 64) acc += cvalR[j] * g[colE[j]];
#pragma unroll
  for (int off = 32; off; off >>= 1) acc += __shfl_xor(acc, off);
  if (lane == 0) vout[row] = vin[row] - acc;
}

// G[e,:] = sum_p c[e,p] * M[idx[e,p],:]
__global__ __launch_bounds__(256) void spmm_edge(
    const float* __restrict__ cvals, const int* __restrict__ topi,
    const float* __restrict__ M, float* __restrict__ G) {
  int wid = threadIdx.x >> 6, lane = threadIdx.x & 63;
  int e = blockIdx.x * 4 + wid;  // grid 4096
  float4 acc = {0.f, 0.f, 0.f, 0.f};
#pragma unroll
  for (int p = 0; p < 16; ++p) {
    float c = cvals[e * 16 + p];
    int i = topi[e * 16 + p];
    float4 x = *(const float4*)(M + ((size_t)i << 8) + (lane << 2));
    acc.x += c * x.x; acc.y += c * x.y; acc.z += c * x.z; acc.w += c * x.w;
  }
  *(float4*)(G + ((size_t)e << 8) + (lane << 2)) = acc;
}

// Z[i,:] = sum_{j in row i} cvalR[j] * G[colE[j],:]   (= S_norm @ M)
__global__ __launch_bounds__(256) void spmm_row(
    const int* __restrict__ rowptr, const int* __restrict__ colE,
    const float* __restrict__ cvalR, const float* __restrict__ G,
    float* __restrict__ Z) {
  int wid = threadIdx.x >> 6, lane = threadIdx.x & 63;
  int row = blockIdx.x * 4 + wid;  // grid 1024
  float4 acc = {0.f, 0.f, 0.f, 0.f};
  int s = rowptr[row], e = rowptr[row + 1];
  for (int j = s; j < e; ++j) {
    float c = cvalR[j];
    int eg = colE[j];
    float4 gg = *(const float4*)(G + ((size_t)eg << 8) + (lane << 2));
    acc.x += c * gg.x; acc.y += c * gg.y; acc.z += c * gg.z; acc.w += c * gg.w;
  }
  *(float4*)(Z + ((size_t)row << 8) + (lane << 2)) = acc;
}

// v0: bit-exact jax.random.normal(key(1), (4096,1), f32)
__global__ __launch_bounds__(256) void init_v0(float* __restrict__ v) {
  int tid = blockIdx.x * 256 + threadIdx.x;
  unsigned j = (unsigned)(tid & 2047);
  unsigned x0 = j, x1 = j + 2048u;
  const unsigned ks0 = 0u, ks1 = 1u, ks2 = 0x1BD11BDAu;
  x0 += ks0; x1 += ks1;
#define TF_R(r)                                  \
  {                                              \
    x0 += x1;                                    \
    x1 = (x1 << (r)) | (x1 >> (32 - (r)));       \
    x1 ^= x0;                                    \
  }
  TF_R(13) TF_R(15) TF_R(26) TF_R(6)  x0 += ks1; x1 += ks2 + 1u;
  TF_R(17) TF_R(29) TF_R(16) TF_R(24) x0 += ks2; x1 += ks0 + 2u;
  TF_R(13) TF_R(15) TF_R(26) TF_R(6)  x0 += ks0; x1 += ks1 + 3u;
  TF_R(17) TF_R(29) TF_R(16) TF_R(24) x0 += ks1; x1 += ks2 + 4u;
  TF_R(13) TF_R(15) TF_R(26) TF_R(6)  x0 += ks2; x1 += ks0 + 5u;
#undef TF_R
  unsigned bits = (tid < 2048) ? x0 : x1;
  float u01 = __uint_as_float((bits >> 9) | 0x3f800000u) - 1.0f;
  const float lo = -0.99999994f;
  float u = fmaxf(lo, u01 * 2.0f + lo);
  float w = -log1pf(-u * u);
  float p;
  if (w < 5.0f) {
    float t = w - 2.5f;
    p = 2.81022636e-08f;
    p = 3.43273939e-07f + p * t;
    p = -3.5233877e-06f + p * t;
    p = -4.39150654e-06f + p * t;
    p = 0.00021858087f + p * t;
    p = -0.00125372503f + p * t;
    p = -0.00417768164f + p * t;
    p = 0.246640727f + p * t;
    p = 1.50140941f + p * t;
  } else {
    float t = sqrtf(w) - 3.0f;
    p = -0.000200214257f;
    p = 0.000100950558f + p * t;
    p = 0.00134934322f + p * t;
    p = -0.00367342844f + p * t;
    p = 0.00573950773f + p * t;
    p = -0.0076224613f + p * t;
    p = 0.00943887047f + p * t;
    p = 1.00167406f + p * t;
    p = 2.83297682f + p * t;
  }
  v[tid] = 1.41421354f * (p * u);
}

// lam = clip((w5.w6)/(w5.w5), 1e-3) -> scal[5]
__global__ __launch_bounds__(256) void pi_dots(const float* __restrict__ w5,
                                               const float* __restrict__ w6,
                                               float* __restrict__ scal) {
  __shared__ float r1[256], r2[256];
  int tid = threadIdx.x;
  float a = 0.f, b = 0.f;
  for (int i = tid; i < 4096; i += 256) {
    float x = w5[i];
    a += x * x;
    b += x * w6[i];
  }
  r1[tid] = a; r2[tid] = b;
  __syncthreads();
  for (int off = 128; off; off >>= 1) {
    if (tid < off) { r1[tid] += r1[tid + off]; r2[tid] += r2[tid + off]; }
    __syncthreads();
  }
  if (tid == 0) scal[5] = fmaxf(r2[0] / r1[0], 1e-3f);
}

// T1 = (c1-1)X - c1*SnX (all f32)
__global__ __launch_bounds__(256) void t1_simple(
    const float* __restrict__ SnX, const float* __restrict__ Xf,
    const float* __restrict__ scal, float* __restrict__ T1) {
  int i = blockIdx.x * 256 + threadIdx.x;  // grid 4096
  float c1 = 2.0f / scal[5];
  T1[i] = (c1 - 1.0f) * Xf[i] - c1 * SnX[i];
}

// T2, cheb combine, elu, mix -> Zmix split hi/lo fp16
__global__ __launch_bounds__(256) void combine_kernel(
    const float* __restrict__ Xf, const float* __restrict__ T1,
    const float* __restrict__ SnT1, const float* __restrict__ Zk,
    const float* __restrict__ thetaf, const float* __restrict__ scal,
    h16* __restrict__ Zmh, h16* __restrict__ Zml) {
  int idx = blockIdx.x * 256 + threadIdx.x;  // grid 4096
  int d = idx & 255;
  float c1 = 2.0f / scal[5];
  float rho = scal[4];
  float x = Xf[idx];
  float t1 = T1[idx];
  float t2 = 2.0f * ((c1 - 1.0f) * t1 - c1 * SnT1[idx]) - x;
  float o = x * thetaf[d] + t1 * thetaf[256 + d] + t2 * thetaf[512 + d];
  float zs = o > 0.0f ? o : expm1f(o);
  float zm = rho * zs + (1.0f - rho) * Zk[idx];
  h16 h = (h16)zm;
  Zmh[idx] = h;
  Zml[idx] = (h16)(zm - (float)h);
}

// ---------------------------------------------------------------------------
extern "C" void kernel_launch(void* const* d_in, const int* in_sizes, int n_in,
                              void* d_out, int out_size, void* d_ws,
                              size_t ws_size, hipStream_t stream) {
  (void)in_sizes; (void)n_in; (void)out_size;
  const void* Xin = d_in[0];
  const void* Lin = d_in[1];
  const void* alpha = d_in[2];
  const void* theta = d_in[3];
  const void* rho_raw = d_in[4];
  const void* Wpin = d_in[5];
  const void* bpin = d_in[6];
  float* out = (float*)d_out;

  char* base = (char*)d_ws;
  size_t off = 0;
  auto alloc = [&](size_t bytes) -> char* {
    char* p = base + off;
    off += (bytes + 255) & ~(size_t)255;
    return p;
  };
  float* Abuf = (float*)alloc((size_t)4096 * 4096 * 4);  // A per head; later G
  h16* Ebuf = (h16*)alloc((size_t)4096 * 4096 * 2);      // Yf alias; E per head
  h16* Yhi = (h16*)alloc((size_t)4 * 4096 * 256 * 2);
  h16* Ylo = (h16*)alloc((size_t)4 * 4096 * 256 * 2);
  h16* Xhi = (h16*)alloc((size_t)4096 * 256 * 2);
  h16* Xlo = (h16*)alloc((size_t)4096 * 256 * 2);
  float* Xf = (float*)alloc((size_t)4096 * 256 * 4);
  h16* XT = (h16*)alloc((size_t)256 * 4096 * 2);
  h16* Lhi = (h16*)alloc((size_t)4 * 256 * 256 * 2);
  h16* Llo = (h16*)alloc((size_t)4 * 256 * 256 * 2);
  h16* LThi = (h16*)alloc((size_t)4 * 256 * 256 * 2);
  h16* LTlo = (h16*)alloc((size_t)4 * 256 * 256 * 2);
  h16* Whi = (h16*)alloc((size_t)256 * 256 * 2);
  h16* Wlo = (h16*)alloc((size_t)256 * 256 * 2);
  float* Zk = (float*)alloc((size_t)4096 * 256 * 4);
  float* SnX = (float*)alloc((size_t)4096 * 256 * 4);  // then SnT1
  float* T1 = (float*)alloc((size_t)4096 * 256 * 4);
  h16* Zmh = (h16*)alloc((size_t)4096 * 256 * 2);
  h16* Zml = (h16*)alloc((size_t)4096 * 256 * 2);
  float* topv = (float*)alloc((size_t)4 * 4096 * 16 * 4);
  int* topi = (int*)alloc((size_t)4 * 4096 * 16 * 4);
  float* cvals = (float*)alloc((size_t)262144 * 4);
  int* colE = (int*)alloc((size_t)262144 * 4);
  float* cvalR = (float*)alloc((size_t)262144 * 4);
  int* rowptr = (int*)alloc(4097 * 4);
  int* cur = (int*)alloc(4096 * 4);
  int* cnt = (int*)alloc(4096 * 4);
  float* Dv = (float*)alloc(4096 * 4);
  float* Dvis = (float*)alloc(4096 * 4);
  float* DeIS = (float*)alloc(16384 * 4);
  float* gE = (float*)alloc(16384 * 4);
  float* wA = (float*)alloc(4096 * 4);
  float* wB = (float*)alloc(4096 * 4);
  float* rowSinv = (float*)alloc(4096 * 4);
  float* thetaf = (float*)alloc(768 * 4);
  float* biasf = (float*)alloc(256 * 4);
  float* scal = (float*)alloc(256);
  int* flag = (int*)alloc(256);
  if (off > ws_size) return;
  float* Yf = (float*)Ebuf;  // 16 MB alias; dead before E written
  float* G = (float*)Abuf;   // 16 MB alias; dead after last head's softmax

  detect_dtype<<<1, 256, 0, stream>>>((const u16*)Xin, flag);
  split_input3<<<1024, 256, 0, stream>>>(Xin, Xhi, Xlo, Xf, 4096 * 256, flag);
  split_input3<<<256, 256, 0, stream>>>(Lin, Lhi, Llo, nullptr, 4 * 256 * 256,
                                        flag);
  split_input3<<<64, 256, 0, stream>>>(Wpin, Whi, Wlo, nullptr, 256 * 256, flag);
  conv_f32<<<1, 256, 0, stream>>>(theta, thetaf, 768, flag);
  conv_f32<<<1, 256, 0, stream>>>(bpin, biasf, 256, flag);
  prep_scalars<<<1, 64, 0, stream>>>(alpha, rho_raw, scal, flag);
  transpose16<<<dim3(128, 8, 1), 256, 0, stream>>>((const u16*)Xhi, (u16*)XT,
                                                   4096, 256);
  transpose16<<<dim3(8, 8, 4), 256, 0, stream>>>((const u16*)Lhi, (u16*)LThi,
                                                 256, 256);
  transpose16<<<dim3(8, 8, 4), 256, 0, stream>>>((const u16*)Llo, (u16*)LTlo,
                                                 256, 256);
  // Yf = X @ L_k (split fp16, fused), batched z=4
  gemm3_nt<false><<<dim3(4, 64, 4), 256, 0, stream>>>(
      Xhi, Xlo, LThi, LTlo, Yf, nullptr, 1.0f, 4096, 256, 256,
      0L, 256L * 256L, 4096L * 256L);
  split_f32h<<<2048, 256, 0, stream>>>(Yf, Yhi, Ylo, 4 * 4096 * 256);
  hipMemsetAsync(Zk, 0, (size_t)4096 * 256 * 4, stream);
  for (int k = 0; k < 4; ++k) {
    // A = Y_k @ X^T / 16 (split fp16, 128x128 tile, global_load_lds)
    gemm3_big<<<dim3(32, 32), 256, 0, stream>>>(
        Yhi + (size_t)k * 4096 * 256, Ylo + (size_t)k * 4096 * 256, Xhi, Xlo,
        Abuf, 0.0625f, 4096, 4096, 256);
    row_softmax_topk<<<1024, 256, 0, stream>>>(Abuf, topv, topi, Ebuf, rowSinv,
                                               k);
    // Zk += w_k * invS[row] * (E @ X)
    gemm_nt<true, true, true><<<dim3(4, 64), 256, 0, stream>>>(
        Ebuf, XT, Zk, scal + k, rowSinv, 1.0f, 4096, 256, 4096);
  }
  // sparse hypergraph Laplacian (no dense S)
  hipMemsetAsync(Dv, 0, 4096 * 4, stream);
  hipMemsetAsync(cnt, 0, 4096 * 4, stream);
  edge_prep<<<64, 256, 0, stream>>>(topv, topi, Dv, cnt, DeIS);
  dv_isqrt<<<16, 256, 0, stream>>>(Dv, Dvis);
  scan_rowptr<<<1, 256, 0, stream>>>(cnt, rowptr, cur);
  csr_fill<<<64, 256, 0, stream>>>(topv, topi, Dvis, DeIS, cur, cvals, colE,
                                   cvalR);
  init_v0<<<16, 256, 0, stream>>>(wA);
  for (int it = 0; it < 6; ++it) {
    const float* vi = (it & 1) ? wB : wA;
    float* vo = (it & 1) ? wA : wB;
    spmv_edge<<<64, 256, 0, stream>>>(cvals, topi, vi, gE);
    spmv_row<<<1024, 256, 0, stream>>>(rowptr, colE, cvalR, gE, vi, vo);
  }
  pi_dots<<<1, 256, 0, stream>>>(wB, wA, scal);
  // SnX = S_norm @ X (sparse, f32-exact)
  spmm_edge<<<4096, 256, 0, stream>>>(cvals, topi, Xf, G);
  spmm_row<<<1024, 256, 0, stream>>>(rowptr, colE, cvalR, G, SnX);
  t1_simple<<<4096, 256, 0, stream>>>(SnX, Xf, scal, T1);
  // SnT1 = S_norm @ T1 (overwrite SnX)
  spmm_edge<<<4096, 256, 0, stream>>>(cvals, topi, T1, G);
  spmm_row<<<1024, 256, 0, stream>>>(rowptr, colE, cvalR, G, SnX);
  combine_kernel<<<4096, 256, 0, stream>>>(Xf, T1, SnX, Zk, thetaf, scal, Zmh,
                                           Zml);
  // out = Zmix @ proj_w^T + proj_b (split fp16, f32 out)
  gemm3_nt<true><<<dim3(4, 64, 1), 256, 0, stream>>>(
      Zmh, Zml, Whi, Wlo, out, biasf, 1.0f, 4096, 256, 256, 0L, 0L, 0L);
}

// Round 6
// 965.986 us; speedup vs baseline: 1.3294x; 1.3294x over previous
//
#include <hip/hip_runtime.h>

typedef unsigned short u16;
typedef unsigned long long u64;
typedef _Float16 h16;
typedef __attribute__((ext_vector_type(8))) _Float16 h16x8;
typedef __attribute__((ext_vector_type(4))) _Float16 h16x4;
typedef __attribute__((ext_vector_type(4))) float f32x4;

__device__ __forceinline__ float b2f(u16 u) {
  unsigned x = ((unsigned)u) << 16;
  return __uint_as_float(x);
}
__device__ __forceinline__ unsigned fkey(float f) {
  unsigned b = __float_as_uint(f);
  return (b & 0x80000000u) ? ~b : (b | 0x80000000u);
}
__device__ __forceinline__ float unfkey(unsigned u) {
  unsigned b = (u & 0x80000000u) ? (u ^ 0x80000000u) : ~u;
  return __uint_as_float(b);
}
__device__ __forceinline__ f32x4 mfma16(h16x8 a, h16x8 b, f32x4 c) {
  return __builtin_amdgcn_mfma_f32_16x16x32_f16(a, b, c, 0, 0, 0);
}
__device__ __forceinline__ void gl_lds16(const void* g, void* l) {
  __builtin_amdgcn_global_load_lds(
      (const __attribute__((address_space(1))) unsigned*)g,
      (__attribute__((address_space(3))) unsigned*)l, 16, 0, 0);
}
__device__ __forceinline__ u64 wave_max_u64(u64 k) {
#pragma unroll
  for (int off = 32; off; off >>= 1) {
    u64 o = __shfl_xor(k, off);
    if (o > k) k = o;
  }
  return k;
}

// dtype detector (insurance): flag=1 means inputs are f32 (expected)
__global__ void detect_dtype(const u16* __restrict__ X, int* __restrict__ flag) {
  __shared__ int cnt;
  if (threadIdx.x == 0) cnt = 0;
  __syncthreads();
  int sane = 0;
#pragma unroll
  for (int j = 0; j < 16; ++j) {
    u16 u = X[(threadIdx.x * 16 + j) * 2];
    int e = (u >> 7) & 0xff;
    if (u == 0 || (e >= 112 && e <= 142)) sane++;
  }
  atomicAdd(&cnt, sane);
  __syncthreads();
  if (threadIdx.x == 0) *flag = (cnt < 3072) ? 1 : 0;
}

// split input to hi/lo fp16 + optional f32 copy
__global__ __launch_bounds__(256) void split_input3(
    const void* __restrict__ in, h16* __restrict__ hi, h16* __restrict__ lo,
    float* __restrict__ f32out, int n, const int* __restrict__ flag) {
  int f = *flag;
  int stride = gridDim.x * 256;
  for (int i = blockIdx.x * 256 + threadIdx.x; i < n; i += stride) {
    float x = f ? ((const float*)in)[i] : b2f(((const u16*)in)[i]);
    h16 h = (h16)x;
    hi[i] = h;
    lo[i] = (h16)(x - (float)h);
    if (f32out) f32out[i] = x;
  }
}

// split f32 buffer to hi/lo fp16
__global__ __launch_bounds__(256) void split_f32h(
    const float* __restrict__ in, h16* __restrict__ hi, h16* __restrict__ lo,
    int n) {
  int stride = gridDim.x * 256;
  for (int i = blockIdx.x * 256 + threadIdx.x; i < n; i += stride) {
    float x = in[i];
    h16 h = (h16)x;
    hi[i] = h;
    lo[i] = (h16)(x - (float)h);
  }
}

// canonicalize to f32 (theta, proj_b)
__global__ __launch_bounds__(256) void conv_f32(const void* __restrict__ in,
                                                float* __restrict__ out, int n,
                                                const int* __restrict__ flag) {
  int f = *flag;
  int stride = gridDim.x * 256;
  for (int i = blockIdx.x * 256 + threadIdx.x; i < n; i += stride)
    out[i] = f ? ((const float*)in)[i] : b2f(((const u16*)in)[i]);
}

// ---------------------------------------------------------------------------
// Split-precision NT GEMM (64x64 tile): C = alpha*(Ah Bh^T + Ah Bl^T + Al Bh^T)
// ---------------------------------------------------------------------------
template <bool BIAS>
__global__ __launch_bounds__(256) void gemm3_nt(
    const h16* __restrict__ Ah, const h16* __restrict__ Al,
    const h16* __restrict__ Bh, const h16* __restrict__ Bl,
    float* __restrict__ C, const float* __restrict__ bias, float alpha,
    int M, int Nc, int Kd, long batchA, long batchB, long batchC) {
  const h16* Abh = Ah + (size_t)blockIdx.z * batchA;
  const h16* Abl = Al + (size_t)blockIdx.z * batchA;
  const h16* Bbh = Bh + (size_t)blockIdx.z * batchB;
  const h16* Bbl = Bl + (size_t)blockIdx.z * batchB;
  float* Cb = C + (size_t)blockIdx.z * batchC;
  int bn = blockIdx.x, bm = blockIdx.y;
  int tid = threadIdx.x;
  int wid = tid >> 6, lane = tid & 63;
  __shared__ h16 Ash[64 * 40], Asl[64 * 40], Bsh[64 * 40], Bsl[64 * 40];
  f32x4 acc00 = {}, acc01 = {}, acc10 = {}, acc11 = {};
  int lr = tid >> 2;
  int lc = (tid & 3) << 3;
  size_t aoff = (size_t)(bm * 64 + lr) * Kd + lc;
  size_t boff = (size_t)(bn * 64 + lr) * Kd + lc;
  int wm = (wid & 1) * 32, wn = (wid >> 1) * 32;
  int fr = lane & 15;
  int fc = (lane >> 4) << 3;
  for (int k0 = 0; k0 < Kd; k0 += 32) {
    uint4 avh = *(const uint4*)(Abh + aoff + k0);
    uint4 avl = *(const uint4*)(Abl + aoff + k0);
    uint4 bvh = *(const uint4*)(Bbh + boff + k0);
    uint4 bvl = *(const uint4*)(Bbl + boff + k0);
    __syncthreads();
    *(uint4*)(Ash + lr * 40 + lc) = avh;
    *(uint4*)(Asl + lr * 40 + lc) = avl;
    *(uint4*)(Bsh + lr * 40 + lc) = bvh;
    *(uint4*)(Bsl + lr * 40 + lc) = bvl;
    __syncthreads();
    h16x8 a0h = *(const h16x8*)(Ash + (wm + fr) * 40 + fc);
    h16x8 a1h = *(const h16x8*)(Ash + (wm + 16 + fr) * 40 + fc);
    h16x8 b0h = *(const h16x8*)(Bsh + (wn + fr) * 40 + fc);
    h16x8 b1h = *(const h16x8*)(Bsh + (wn + 16 + fr) * 40 + fc);
    h16x8 a0l = *(const h16x8*)(Asl + (wm + fr) * 40 + fc);
    h16x8 a1l = *(const h16x8*)(Asl + (wm + 16 + fr) * 40 + fc);
    h16x8 b0l = *(const h16x8*)(Bsl + (wn + fr) * 40 + fc);
    h16x8 b1l = *(const h16x8*)(Bsl + (wn + 16 + fr) * 40 + fc);
    acc00 = mfma16(a0h, b0h, acc00);
    acc01 = mfma16(a0h, b1h, acc01);
    acc10 = mfma16(a1h, b0h, acc10);
    acc11 = mfma16(a1h, b1h, acc11);
    acc00 = mfma16(a0h, b0l, acc00);
    acc01 = mfma16(a0h, b1l, acc01);
    acc10 = mfma16(a1h, b0l, acc10);
    acc11 = mfma16(a1h, b1l, acc11);
    acc00 = mfma16(a0l, b0h, acc00);
    acc01 = mfma16(a0l, b1h, acc01);
    acc10 = mfma16(a1l, b0h, acc10);
    acc11 = mfma16(a1l, b1h, acc11);
  }
  int crow = (lane >> 4) << 2;
  int ccol = lane & 15;
  f32x4 accs[2][2] = {{acc00, acc01}, {acc10, acc11}};
#pragma unroll
  for (int i = 0; i < 2; ++i)
#pragma unroll
    for (int j = 0; j < 2; ++j) {
      int r0 = bm * 64 + wm + 16 * i + crow;
      int c0 = bn * 64 + wn + 16 * j + ccol;
#pragma unroll
      for (int rg = 0; rg < 4; ++rg) {
        float v = accs[i][j][rg] * alpha;
        if constexpr (BIAS) v += bias[c0];
        Cb[(size_t)(r0 + rg) * Nc + c0] = v;
      }
    }
}

// ---------------------------------------------------------------------------
// Split-precision NT GEMM, 128x128 tile, global_load_lds staging, XOR swizzle.
// ---------------------------------------------------------------------------
__global__ __launch_bounds__(256) void gemm3_big(
    const h16* __restrict__ Ah, const h16* __restrict__ Al,
    const h16* __restrict__ Bh, const h16* __restrict__ Bl,
    float* __restrict__ C, float alpha, int M, int Nc, int Kd) {
  __shared__ h16 sAh[128 * 32], sAl[128 * 32], sBh[128 * 32], sBl[128 * 32];
  int tid = threadIdx.x, wid = tid >> 6, lane = tid & 63;
  int bm = blockIdx.y, bn = blockIdx.x;
  int srow = 32 * wid + (lane >> 2);
  int scnk = lane & 3;
  int fr = lane & 15, fcc = lane >> 4;
  f32x4 acc[4][4] = {};
  const h16* gA[2] = {Ah, Al};
  const h16* gB[2] = {Bh, Bl};
  h16* sA[2] = {sAh, sAl};
  h16* sB[2] = {sBh, sBl};
  int wm = (wid & 1) * 64, wn = (wid >> 1) * 64;
  for (int k0 = 0; k0 < Kd; k0 += 32) {
    __syncthreads();
#pragma unroll
    for (int h = 0; h < 2; ++h) {
      int r = srow + 16 * h;
      int cs = scnk ^ ((r >> 1) & 3);
      size_t goffA = (size_t)(bm * 128 + r) * Kd + k0 + cs * 8;
      size_t goffB = (size_t)(bn * 128 + r) * Kd + k0 + cs * 8;
      int loff = (32 * wid + 16 * h) * 32;
#pragma unroll
      for (int p = 0; p < 2; ++p) {
        gl_lds16(gA[p] + goffA, sA[p] + loff);
        gl_lds16(gB[p] + goffB, sB[p] + loff);
      }
    }
    __syncthreads();
    h16x8 fa[2][4], fb[2][4];
#pragma unroll
    for (int i = 0; i < 4; ++i) {
      int ra = wm + 16 * i + fr;
      int ca = (fcc ^ ((ra >> 1) & 3)) * 8;
      fa[0][i] = *(const h16x8*)(sAh + ra * 32 + ca);
      fa[1][i] = *(const h16x8*)(sAl + ra * 32 + ca);
      int rb = wn + 16 * i + fr;
      int cb = (fcc ^ ((rb >> 1) & 3)) * 8;
      fb[0][i] = *(const h16x8*)(sBh + rb * 32 + cb);
      fb[1][i] = *(const h16x8*)(sBl + rb * 32 + cb);
    }
#pragma unroll
    for (int i = 0; i < 4; ++i)
#pragma unroll
      for (int j = 0; j < 4; ++j) {
        acc[i][j] = mfma16(fa[0][i], fb[0][j], acc[i][j]);
        acc[i][j] = mfma16(fa[0][i], fb[1][j], acc[i][j]);
        acc[i][j] = mfma16(fa[1][i], fb[0][j], acc[i][j]);
      }
  }
  int crow = (lane >> 4) << 2, ccol = lane & 15;
#pragma unroll
  for (int i = 0; i < 4; ++i)
#pragma unroll
    for (int j = 0; j < 4; ++j) {
      int r0 = bm * 128 + wm + 16 * i + crow;
      int c0 = bn * 128 + wn + 16 * j + ccol;
#pragma unroll
      for (int rg = 0; rg < 4; ++rg)
        C[(size_t)(r0 + rg) * Nc + c0] = acc[i][j][rg] * alpha;
    }
}

// plain NT GEMM (fp16), accumulate with global-scale-ptr and per-row scale
template <bool ACCUM, bool SCALEPTR, bool ROWSCALE>
__global__ __launch_bounds__(256) void gemm_nt(
    const h16* __restrict__ A, const h16* __restrict__ B, float* __restrict__ C,
    const float* __restrict__ scptr, const float* __restrict__ rowsc,
    float alpha, int M, int Nc, int Kd) {
  int bn = blockIdx.x, bm = blockIdx.y;
  int tid = threadIdx.x;
  int wid = tid >> 6, lane = tid & 63;
  __shared__ h16 As[64 * 40];
  __shared__ h16 Bs[64 * 40];
  f32x4 acc00 = {}, acc01 = {}, acc10 = {}, acc11 = {};
  int lr = tid >> 2;
  int lc = (tid & 3) << 3;
  const h16* Ag = A + (size_t)(bm * 64 + lr) * Kd + lc;
  const h16* Bg = B + (size_t)(bn * 64 + lr) * Kd + lc;
  int wm = (wid & 1) * 32, wn = (wid >> 1) * 32;
  int fr = lane & 15;
  int fc = (lane >> 4) << 3;
  for (int k0 = 0; k0 < Kd; k0 += 32) {
    uint4 av = *(const uint4*)(Ag + k0);
    uint4 bv = *(const uint4*)(Bg + k0);
    __syncthreads();
    *(uint4*)(As + lr * 40 + lc) = av;
    *(uint4*)(Bs + lr * 40 + lc) = bv;
    __syncthreads();
    h16x8 a0 = *(const h16x8*)(As + (wm + fr) * 40 + fc);
    h16x8 a1 = *(const h16x8*)(As + (wm + 16 + fr) * 40 + fc);
    h16x8 b0 = *(const h16x8*)(Bs + (wn + fr) * 40 + fc);
    h16x8 b1 = *(const h16x8*)(Bs + (wn + 16 + fr) * 40 + fc);
    acc00 = mfma16(a0, b0, acc00);
    acc01 = mfma16(a0, b1, acc01);
    acc10 = mfma16(a1, b0, acc10);
    acc11 = mfma16(a1, b1, acc11);
  }
  float sc = alpha;
  if constexpr (SCALEPTR) sc *= *scptr;
  int crow = (lane >> 4) << 2;
  int ccol = lane & 15;
  f32x4 accs[2][2] = {{acc00, acc01}, {acc10, acc11}};
#pragma unroll
  for (int i = 0; i < 2; ++i)
#pragma unroll
    for (int j = 0; j < 2; ++j) {
      int r0 = bm * 64 + wm + 16 * i + crow;
      int c0 = bn * 64 + wn + 16 * j + ccol;
#pragma unroll
      for (int rg = 0; rg < 4; ++rg) {
        size_t off = (size_t)(r0 + rg) * Nc + c0;
        float v = accs[i][j][rg] * sc;
        if constexpr (ROWSCALE) v *= rowsc[r0 + rg];
        if constexpr (ACCUM)
          C[off] += v;
        else
          C[off] = v;
      }
    }
}

// 16-bit transpose
__global__ __launch_bounds__(256) void transpose16(
    const u16* __restrict__ in, u16* __restrict__ out, int rows, int cols) {
  __shared__ u16 t[32][33];
  const u16* ib = in + (size_t)blockIdx.z * rows * cols;
  u16* ob = out + (size_t)blockIdx.z * rows * cols;
  int r0 = blockIdx.x * 32, c0 = blockIdx.y * 32;
  int tx = threadIdx.x & 31, ty = threadIdx.x >> 5;
#pragma unroll
  for (int i = 0; i < 32; i += 8)
    t[ty + i][tx] = ib[(size_t)(r0 + ty + i) * cols + c0 + tx];
  __syncthreads();
#pragma unroll
  for (int i = 0; i < 32; i += 8)
    ob[(size_t)(c0 + ty + i) * rows + r0 + tx] = t[tx][ty + i];
}

// scalars: w=softmax(alpha)->scal[0..3], rho=sigmoid(rho_raw)->scal[4]
__global__ void prep_scalars(const void* __restrict__ alpha,
                             const void* __restrict__ rho_raw,
                             float* __restrict__ scal,
                             const int* __restrict__ flag) {
  if (threadIdx.x == 0) {
    int f = *flag;
    float a[4], e[4], m = -1e30f, s = 0.f;
    for (int i = 0; i < 4; ++i) {
      a[i] = f ? ((const float*)alpha)[i] : b2f(((const u16*)alpha)[i]);
      m = fmaxf(m, a[i]);
    }
    for (int i = 0; i < 4; ++i) { e[i] = expf(a[i] - m); s += e[i]; }
    for (int i = 0; i < 4; ++i) scal[i] = e[i] / s;
    float rr = f ? ((const float*)rho_raw)[0] : b2f(((const u16*)rho_raw)[0]);
    scal[4] = 1.f / (1.f + expf(-rr));
  }
}

// ---------------------------------------------------------------------------
// fused per-row (one wave per row):
//  pass A: vectorized lane-max + wave max m
//  T = 16th-largest lane max (provable lower bound for 16th-largest element)
//  pass B: E=exp(v-m) fp16 + sum s + candidate push (v>=T) to LDS
//  exact jax-tiebreak top-16 from candidates via 16 wave-argmax rounds
// ---------------------------------------------------------------------------
__global__ __launch_bounds__(256) void row_softmax_topk(
    const float* __restrict__ A, float* __restrict__ topv,
    int* __restrict__ topi, h16* __restrict__ E, float* __restrict__ rowSinv,
    int khead) {
  __shared__ u64 candK[4][256];
  __shared__ int candN[4];
  int wid = threadIdx.x >> 6, lane = threadIdx.x & 63;
  int row = blockIdx.x * 4 + wid;
  const float* arow = A + ((size_t)row << 12);
  if (lane == 0) candN[wid] = 0;
  __syncthreads();
  // pass A: lane max over 16 float4 chunks, wave max
  float lm = -INFINITY;
#pragma unroll
  for (int t = 0; t < 16; ++t) {
    float4 v = *(const float4*)(arow + (t << 8) + (lane << 2));
    lm = fmaxf(lm, fmaxf(fmaxf(v.x, v.y), fmaxf(v.z, v.w)));
  }
  float m = lm;
#pragma unroll
  for (int off = 32; off; off >>= 1) m = fmaxf(m, __shfl_xor(m, off));
  // T = 16th-largest lane max
  u64 lk = ((u64)fkey(lm) << 32) | (unsigned)lane;
  float T = 0.f;
  for (int r = 0; r < 16; ++r) {
    u64 k2 = wave_max_u64(lk);
    if (lk == k2) lk = 0;
    if (r == 15) T = unfkey((unsigned)(k2 >> 32));
  }
  // pass B: exp + sum + candidate push
  h16* erow = E + ((size_t)row << 12);
  int* cn = &candN[wid];
  u64* ck = candK[wid];
  float s = 0.f;
  for (int t = 0; t < 16; ++t) {
    int c = (t << 8) + (lane << 2);
    float4 v = *(const float4*)(arow + c);
    float e0 = __expf(v.x - m), e1 = __expf(v.y - m);
    float e2 = __expf(v.z - m), e3 = __expf(v.w - m);
    s += (e0 + e1) + (e2 + e3);
    h16x4 hv = {(h16)e0, (h16)e1, (h16)e2, (h16)e3};
    *(h16x4*)(erow + c) = hv;
    if (v.x >= T) {
      int sl = atomicAdd(cn, 1);
      if (sl < 256) ck[sl] = ((u64)fkey(v.x) << 32) | (unsigned)(~(unsigned)c);
    }
    if (v.y >= T) {
      int sl = atomicAdd(cn, 1);
      if (sl < 256) ck[sl] = ((u64)fkey(v.y) << 32) | (unsigned)(~(unsigned)(c + 1));
    }
    if (v.z >= T) {
      int sl = atomicAdd(cn, 1);
      if (sl < 256) ck[sl] = ((u64)fkey(v.z) << 32) | (unsigned)(~(unsigned)(c + 2));
    }
    if (v.w >= T) {
      int sl = atomicAdd(cn, 1);
      if (sl < 256) ck[sl] = ((u64)fkey(v.w) << 32) | (unsigned)(~(unsigned)(c + 3));
    }
  }
#pragma unroll
  for (int off = 32; off; off >>= 1) s += __shfl_xor(s, off);
  if (lane == 0) rowSinv[row] = 1.f / s;
  __syncthreads();  // drain candidate pushes
  int cnt = min(*cn, 256);
  // each lane takes up to 4 candidates, sorted desc
  u64 loc[4] = {0ull, 0ull, 0ull, 0ull};
  int nl = 0;
  for (int j = lane; j < cnt; j += 64)
    if (nl < 4) loc[nl++] = ck[j];
#define CSW(a, b)                     \
  {                                   \
    if (loc[b] > loc[a]) {            \
      u64 tt = loc[a];                \
      loc[a] = loc[b];                \
      loc[b] = tt;                    \
    }                                 \
  }
  CSW(0, 1) CSW(2, 3) CSW(0, 2) CSW(1, 3) CSW(1, 2)
#undef CSW
  // 16 rounds: global argmax (val desc, idx asc), pop winner
  float myv = 0.f;
  int myi = 0;
  float sum16 = 0.f;
  for (int r = 0; r < 16; ++r) {
    u64 key = loc[0];
    u64 k2 = wave_max_u64(key);
    float wv = unfkey((unsigned)(k2 >> 32));
    int wi = (int)(~(unsigned)(k2 & 0xffffffffu));
    if (key == k2 && key != 0ull) {
      loc[0] = loc[1];
      loc[1] = loc[2];
      loc[2] = loc[3];
      loc[3] = 0ull;
    }
    sum16 += expf(wv - m);
    if (r == lane) { myv = wv; myi = wi; }
  }
  if (lane < 16) {
    size_t o = (((size_t)khead << 12) + row) * 16 + lane;
    topv[o] = expf(myv - m) / (sum16 + 1e-9f * s);
    topi[o] = myi;
  }
}

// ---------------------------------------------------------------------------
// sparse hypergraph: S_norm = C C^T
// ---------------------------------------------------------------------------
__global__ __launch_bounds__(256) void edge_prep(
    const float* __restrict__ topv, const int* __restrict__ topi,
    float* __restrict__ Dv, int* __restrict__ cnt, float* __restrict__ DeIS) {
  int e = blockIdx.x * 256 + threadIdx.x;  // grid 64
  float s = 0.f;
#pragma unroll
  for (int p = 0; p < 16; ++p) {
    float v = topv[e * 16 + p];
    int i = topi[e * 16 + p];
    s += v;
    atomicAdd(&Dv[i], v);
    atomicAdd(&cnt[i], 1);
  }
  DeIS[e] = 1.0f / sqrtf(s + 1e-9f);
}

__global__ void dv_isqrt(const float* __restrict__ Dv, float* __restrict__ Dvis) {
  int i = blockIdx.x * 256 + threadIdx.x;
  Dvis[i] = sqrtf(1.0f / (Dv[i] + 1e-9f));
}

// exclusive scan of cnt[4096] -> rowptr[4097], cur=rowptr
__global__ __launch_bounds__(256) void scan_rowptr(const int* __restrict__ cnt,
                                                   int* __restrict__ rowptr,
                                                   int* __restrict__ cur) {
  __shared__ int part[256];
  int tid = threadIdx.x;
  int base = tid * 16;
  int loc[16];
  int s = 0;
#pragma unroll
  for (int j = 0; j < 16; ++j) { loc[j] = s; s += cnt[base + j]; }
  part[tid] = s;
  __syncthreads();
  for (int off = 1; off < 256; off <<= 1) {
    int v = (tid >= off) ? part[tid - off] : 0;
    __syncthreads();
    part[tid] += v;
    __syncthreads();
  }
  int pre = (tid == 0) ? 0 : part[tid - 1];
#pragma unroll
  for (int j = 0; j < 16; ++j) {
    int r = pre + loc[j];
    rowptr[base + j] = r;
    cur[base + j] = r;
  }
  if (tid == 255) rowptr[4096] = part[255];
}

// fill per-edge cvals and CSR-transpose (colE, cvalR)
__global__ __launch_bounds__(256) void csr_fill(
    const float* __restrict__ topv, const int* __restrict__ topi,
    const float* __restrict__ Dvis, const float* __restrict__ DeIS,
    int* __restrict__ cur, float* __restrict__ cvals, int* __restrict__ colE,
    float* __restrict__ cvalR) {
  int e = blockIdx.x * 256 + threadIdx.x;  // grid 64
  float deis = DeIS[e];
#pragma unroll
  for (int p = 0; p < 16; ++p) {
    int i = topi[e * 16 + p];
    float c = Dvis[i] * topv[e * 16 + p] * deis;
    cvals[e * 16 + p] = c;
    int slot = atomicAdd(&cur[i], 1);
    colE[slot] = e;
    cvalR[slot] = c;
  }
}

// g[e] = sum_p c[e,p] * v[idx[e,p]]
__global__ __launch_bounds__(256) void spmv_edge(
    const float* __restrict__ cvals, const int* __restrict__ topi,
    const float* __restrict__ v, float* __restrict__ g) {
  int e = blockIdx.x * 256 + threadIdx.x;  // grid 64
  float acc = 0.f;
#pragma unroll
  for (int p = 0; p < 16; ++p)
    acc += cvals[e * 16 + p] * v[topi[e * 16 + p]];
  g[e] = acc;
}

// vout[i] = vin[i] - sum_{j in row i} cvalR[j]*g[colE[j]]
__global__ __launch_bounds__(256) void spmv_row(
    const int* __restrict__ rowptr, const int* __restrict__ colE,
    const float* __restrict__ cvalR, const float* __restrict__ g,
    const float* __restrict__ vin, float* __restrict__ vout) {
  int wid = threadIdx.x >> 6, lane = threadIdx.x & 63;
  int row = blockIdx.x * 4 + wid;  // grid 1024
  int s = rowptr[row], e = rowptr[row + 1];
  float acc = 0.f;
  for (int j = s + lane; j < e; j += 64) acc += cvalR[j] * g[colE[j]];
#pragma unroll
  for (int off = 32; off; off >>= 1) acc += __shfl_xor(acc, off);
  if (lane == 0) vout[row] = vin[row] - acc;
}

// G[e,:] = sum_p c[e,p] * M[idx[e,p],:]
__global__ __launch_bounds__(256) void spmm_edge(
    const float* __restrict__ cvals, const int* __restrict__ topi,
    const float* __restrict__ M, float* __restrict__ G) {
  int wid = threadIdx.x >> 6, lane = threadIdx.x & 63;
  int e = blockIdx.x * 4 + wid;  // grid 4096
  float4 acc = {0.f, 0.f, 0.f, 0.f};
#pragma unroll
  for (int p = 0; p < 16; ++p) {
    float c = cvals[e * 16 + p];
    int i = topi[e * 16 + p];
    float4 x = *(const float4*)(M + ((size_t)i << 8) + (lane << 2));
    acc.x += c * x.x; acc.y += c * x.y; acc.z += c * x.z; acc.w += c * x.w;
  }
  *(float4*)(G + ((size_t)e << 8) + (lane << 2)) = acc;
}

// Z[i,:] = sum_{j in row i} cvalR[j] * G[colE[j],:]
__global__ __launch_bounds__(256) void spmm_row(
    const int* __restrict__ rowptr, const int* __restrict__ colE,
    const float* __restrict__ cvalR, const float* __restrict__ G,
    float* __restrict__ Z) {
  int wid = threadIdx.x >> 6, lane = threadIdx.x & 63;
  int row = blockIdx.x * 4 + wid;  // grid 1024
  float4 acc = {0.f, 0.f, 0.f, 0.f};
  int s = rowptr[row], e = rowptr[row + 1];
  for (int j = s; j < e; ++j) {
    float c = cvalR[j];
    int eg = colE[j];
    float4 gg = *(const float4*)(G + ((size_t)eg << 8) + (lane << 2));
    acc.x += c * gg.x; acc.y += c * gg.y; acc.z += c * gg.z; acc.w += c * gg.w;
  }
  *(float4*)(Z + ((size_t)row << 8) + (lane << 2)) = acc;
}

// v0: bit-exact jax.random.normal(key(1), (4096,1), f32)
__global__ __launch_bounds__(256) void init_v0(float* __restrict__ v) {
  int tid = blockIdx.x * 256 + threadIdx.x;
  unsigned j = (unsigned)(tid & 2047);
  unsigned x0 = j, x1 = j + 2048u;
  const unsigned ks0 = 0u, ks1 = 1u, ks2 = 0x1BD11BDAu;
  x0 += ks0; x1 += ks1;
#define TF_R(r)                                  \
  {                                              \
    x0 += x1;                                    \
    x1 = (x1 << (r)) | (x1 >> (32 - (r)));       \
    x1 ^= x0;                                    \
  }
  TF_R(13) TF_R(15) TF_R(26) TF_R(6)  x0 += ks1; x1 += ks2 + 1u;
  TF_R(17) TF_R(29) TF_R(16) TF_R(24) x0 += ks2; x1 += ks0 + 2u;
  TF_R(13) TF_R(15) TF_R(26) TF_R(6)  x0 += ks0; x1 += ks1 + 3u;
  TF_R(17) TF_R(29) TF_R(16) TF_R(24) x0 += ks1; x1 += ks2 + 4u;
  TF_R(13) TF_R(15) TF_R(26) TF_R(6)  x0 += ks2; x1 += ks0 + 5u;
#undef TF_R
  unsigned bits = (tid < 2048) ? x0 : x1;
  float u01 = __uint_as_float((bits >> 9) | 0x3f800000u) - 1.0f;
  const float lo = -0.99999994f;
  float u = fmaxf(lo, u01 * 2.0f + lo);
  float w = -log1pf(-u * u);
  float p;
  if (w < 5.0f) {
    float t = w - 2.5f;
    p = 2.81022636e-08f;
    p = 3.43273939e-07f + p * t;
    p = -3.5233877e-06f + p * t;
    p = -4.39150654e-06f + p * t;
    p = 0.00021858087f + p * t;
    p = -0.00125372503f + p * t;
    p = -0.00417768164f + p * t;
    p = 0.246640727f + p * t;
    p = 1.50140941f + p * t;
  } else {
    float t = sqrtf(w) - 3.0f;
    p = -0.000200214257f;
    p = 0.000100950558f + p * t;
    p = 0.00134934322f + p * t;
    p = -0.00367342844f + p * t;
    p = 0.00573950773f + p * t;
    p = -0.0076224613f + p * t;
    p = 0.00943887047f + p * t;
    p = 1.00167406f + p * t;
    p = 2.83297682f + p * t;
  }
  v[tid] = 1.41421354f * (p * u);
}

// lam = clip((w5.w6)/(w5.w5), 1e-3) -> scal[5]
__global__ __launch_bounds__(256) void pi_dots(const float* __restrict__ w5,
                                               const float* __restrict__ w6,
                                               float* __restrict__ scal) {
  __shared__ float r1[256], r2[256];
  int tid = threadIdx.x;
  float a = 0.f, b = 0.f;
  for (int i = tid; i < 4096; i += 256) {
    float x = w5[i];
    a += x * x;
    b += x * w6[i];
  }
  r1[tid] = a; r2[tid] = b;
  __syncthreads();
  for (int off = 128; off; off >>= 1) {
    if (tid < off) { r1[tid] += r1[tid + off]; r2[tid] += r2[tid + off]; }
    __syncthreads();
  }
  if (tid == 0) scal[5] = fmaxf(r2[0] / r1[0], 1e-3f);
}

// T1 = (c1-1)X - c1*SnX
__global__ __launch_bounds__(256) void t1_simple(
    const float* __restrict__ SnX, const float* __restrict__ Xf,
    const float* __restrict__ scal, float* __restrict__ T1) {
  int i = blockIdx.x * 256 + threadIdx.x;  // grid 4096
  float c1 = 2.0f / scal[5];
  T1[i] = (c1 - 1.0f) * Xf[i] - c1 * SnX[i];
}

// T2, cheb combine, elu, mix -> Zmix split hi/lo fp16
__global__ __launch_bounds__(256) void combine_kernel(
    const float* __restrict__ Xf, const float* __restrict__ T1,
    const float* __restrict__ SnT1, const float* __restrict__ Zk,
    const float* __restrict__ thetaf, const float* __restrict__ scal,
    h16* __restrict__ Zmh, h16* __restrict__ Zml) {
  int idx = blockIdx.x * 256 + threadIdx.x;  // grid 4096
  int d = idx & 255;
  float c1 = 2.0f / scal[5];
  float rho = scal[4];
  float x = Xf[idx];
  float t1 = T1[idx];
  float t2 = 2.0f * ((c1 - 1.0f) * t1 - c1 * SnT1[idx]) - x;
  float o = x * thetaf[d] + t1 * thetaf[256 + d] + t2 * thetaf[512 + d];
  float zs = o > 0.0f ? o : expm1f(o);
  float zm = rho * zs + (1.0f - rho) * Zk[idx];
  h16 h = (h16)zm;
  Zmh[idx] = h;
  Zml[idx] = (h16)(zm - (float)h);
}

// ---------------------------------------------------------------------------
extern "C" void kernel_launch(void* const* d_in, const int* in_sizes, int n_in,
                              void* d_out, int out_size, void* d_ws,
                              size_t ws_size, hipStream_t stream) {
  (void)in_sizes; (void)n_in; (void)out_size;
  const void* Xin = d_in[0];
  const void* Lin = d_in[1];
  const void* alpha = d_in[2];
  const void* theta = d_in[3];
  const void* rho_raw = d_in[4];
  const void* Wpin = d_in[5];
  const void* bpin = d_in[6];
  float* out = (float*)d_out;

  char* base = (char*)d_ws;
  size_t off = 0;
  auto alloc = [&](size_t bytes) -> char* {
    char* p = base + off;
    off += (bytes + 255) & ~(size_t)255;
    return p;
  };
  float* Abuf = (float*)alloc((size_t)4096 * 4096 * 4);  // A per head; later G
  h16* Ebuf = (h16*)alloc((size_t)4096 * 4096 * 2);      // Yf alias; E per head
  h16* Yhi = (h16*)alloc((size_t)4 * 4096 * 256 * 2);
  h16* Ylo = (h16*)alloc((size_t)4 * 4096 * 256 * 2);
  h16* Xhi = (h16*)alloc((size_t)4096 * 256 * 2);
  h16* Xlo = (h16*)alloc((size_t)4096 * 256 * 2);
  float* Xf = (float*)alloc((size_t)4096 * 256 * 4);
  h16* XT = (h16*)alloc((size_t)256 * 4096 * 2);
  h16* Lhi = (h16*)alloc((size_t)4 * 256 * 256 * 2);
  h16* Llo = (h16*)alloc((size_t)4 * 256 * 256 * 2);
  h16* LThi = (h16*)alloc((size_t)4 * 256 * 256 * 2);
  h16* LTlo = (h16*)alloc((size_t)4 * 256 * 256 * 2);
  h16* Whi = (h16*)alloc((size_t)256 * 256 * 2);
  h16* Wlo = (h16*)alloc((size_t)256 * 256 * 2);
  float* Zk = (float*)alloc((size_t)4096 * 256 * 4);
  float* SnX = (float*)alloc((size_t)4096 * 256 * 4);  // then SnT1
  float* T1 = (float*)alloc((size_t)4096 * 256 * 4);
  h16* Zmh = (h16*)alloc((size_t)4096 * 256 * 2);
  h16* Zml = (h16*)alloc((size_t)4096 * 256 * 2);
  float* topv = (float*)alloc((size_t)4 * 4096 * 16 * 4);
  int* topi = (int*)alloc((size_t)4 * 4096 * 16 * 4);
  float* cvals = (float*)alloc((size_t)262144 * 4);
  int* colE = (int*)alloc((size_t)262144 * 4);
  float* cvalR = (float*)alloc((size_t)262144 * 4);
  int* rowptr = (int*)alloc(4097 * 4);
  int* cur = (int*)alloc(4096 * 4);
  int* cnt = (int*)alloc(4096 * 4);
  float* Dv = (float*)alloc(4096 * 4);
  float* Dvis = (float*)alloc(4096 * 4);
  float* DeIS = (float*)alloc(16384 * 4);
  float* gE = (float*)alloc(16384 * 4);
  float* wA = (float*)alloc(4096 * 4);
  float* wB = (float*)alloc(4096 * 4);
  float* rowSinv = (float*)alloc(4096 * 4);
  float* thetaf = (float*)alloc(768 * 4);
  float* biasf = (float*)alloc(256 * 4);
  float* scal = (float*)alloc(256);
  int* flag = (int*)alloc(256);
  if (off > ws_size) return;
  float* Yf = (float*)Ebuf;  // 16 MB alias; dead before E written
  float* G = (float*)Abuf;   // 16 MB alias; dead after last head's softmax

  detect_dtype<<<1, 256, 0, stream>>>((const u16*)Xin, flag);
  split_input3<<<1024, 256, 0, stream>>>(Xin, Xhi, Xlo, Xf, 4096 * 256, flag);
  split_input3<<<256, 256, 0, stream>>>(Lin, Lhi, Llo, nullptr, 4 * 256 * 256,
                                        flag);
  split_input3<<<64, 256, 0, stream>>>(Wpin, Whi, Wlo, nullptr, 256 * 256, flag);
  conv_f32<<<1, 256, 0, stream>>>(theta, thetaf, 768, flag);
  conv_f32<<<1, 256, 0, stream>>>(bpin, biasf, 256, flag);
  prep_scalars<<<1, 64, 0, stream>>>(alpha, rho_raw, scal, flag);
  transpose16<<<dim3(128, 8, 1), 256, 0, stream>>>((const u16*)Xhi, (u16*)XT,
                                                   4096, 256);
  transpose16<<<dim3(8, 8, 4), 256, 0, stream>>>((const u16*)Lhi, (u16*)LThi,
                                                 256, 256);
  transpose16<<<dim3(8, 8, 4), 256, 0, stream>>>((const u16*)Llo, (u16*)LTlo,
                                                 256, 256);
  // Yf = X @ L_k (split fp16, fused), batched z=4
  gemm3_nt<false><<<dim3(4, 64, 4), 256, 0, stream>>>(
      Xhi, Xlo, LThi, LTlo, Yf, nullptr, 1.0f, 4096, 256, 256,
      0L, 256L * 256L, 4096L * 256L);
  split_f32h<<<2048, 256, 0, stream>>>(Yf, Yhi, Ylo, 4 * 4096 * 256);
  hipMemsetAsync(Zk, 0, (size_t)4096 * 256 * 4, stream);
  for (int k = 0; k < 4; ++k) {
    // A = Y_k @ X^T / 16 (split fp16, 128x128 tile, global_load_lds)
    gemm3_big<<<dim3(32, 32), 256, 0, stream>>>(
        Yhi + (size_t)k * 4096 * 256, Ylo + (size_t)k * 4096 * 256, Xhi, Xlo,
        Abuf, 0.0625f, 4096, 4096, 256);
    row_softmax_topk<<<1024, 256, 0, stream>>>(Abuf, topv, topi, Ebuf, rowSinv,
                                               k);
    // Zk += w_k * invS[row] * (E @ X)
    gemm_nt<true, true, true><<<dim3(4, 64), 256, 0, stream>>>(
        Ebuf, XT, Zk, scal + k, rowSinv, 1.0f, 4096, 256, 4096);
  }
  // sparse hypergraph Laplacian (no dense S)
  hipMemsetAsync(Dv, 0, 4096 * 4, stream);
  hipMemsetAsync(cnt, 0, 4096 * 4, stream);
  edge_prep<<<64, 256, 0, stream>>>(topv, topi, Dv, cnt, DeIS);
  dv_isqrt<<<16, 256, 0, stream>>>(Dv, Dvis);
  scan_rowptr<<<1, 256, 0, stream>>>(cnt, rowptr, cur);
  csr_fill<<<64, 256, 0, stream>>>(topv, topi, Dvis, DeIS, cur, cvals, colE,
                                   cvalR);
  init_v0<<<16, 256, 0, stream>>>(wA);
  for (int it = 0; it < 6; ++it) {
    const float* vi = (it & 1) ? wB : wA;
    float* vo = (it & 1) ? wA : wB;
    spmv_edge<<<64, 256, 0, stream>>>(cvals, topi, vi, gE);
    spmv_row<<<1024, 256, 0, stream>>>(rowptr, colE, cvalR, gE, vi, vo);
  }
  pi_dots<<<1, 256, 0, stream>>>(wB, wA, scal);
  // SnX = S_norm @ X (sparse, f32-exact)
  spmm_edge<<<4096, 256, 0, stream>>>(cvals, topi, Xf, G);
  spmm_row<<<1024, 256, 0, stream>>>(rowptr, colE, cvalR, G, SnX);
  t1_simple<<<4096, 256, 0, stream>>>(SnX, Xf, scal, T1);
  // SnT1 = S_norm @ T1 (overwrite SnX)
  spmm_edge<<<4096, 256, 0, stream>>>(cvals, topi, T1, G);
  spmm_row<<<1024, 256, 0, stream>>>(rowptr, colE, cvalR, G, SnX);
  combine_kernel<<<4096, 256, 0, stream>>>(Xf, T1, SnX, Zk, thetaf, scal, Zmh,
                                           Zml);
  // out = Zmix @ proj_w^T + proj_b (split fp16, f32 out)
  gemm3_nt<true><<<dim3(4, 64, 1), 256, 0, stream>>>(
      Zmh, Zml, Whi, Wlo, out, biasf, 1.0f, 4096, 256, 256, 0L, 0L, 0L);
}

// Round 7
// 761.421 us; speedup vs baseline: 1.6866x; 1.2687x over previous
//
#include <hip/hip_runtime.h>

typedef unsigned short u16;
typedef unsigned long long u64;
typedef _Float16 h16;
typedef __attribute__((ext_vector_type(8))) _Float16 h16x8;
typedef __attribute__((ext_vector_type(4))) _Float16 h16x4;
typedef __attribute__((ext_vector_type(4))) float f32x4;

__device__ __forceinline__ float b2f(u16 u) {
  unsigned x = ((unsigned)u) << 16;
  return __uint_as_float(x);
}
__device__ __forceinline__ unsigned fkey(float f) {
  unsigned b = __float_as_uint(f);
  return (b & 0x80000000u) ? ~b : (b | 0x80000000u);
}
__device__ __forceinline__ float unfkey(unsigned u) {
  unsigned b = (u & 0x80000000u) ? (u ^ 0x80000000u) : ~u;
  return __uint_as_float(b);
}
__device__ __forceinline__ f32x4 mfma16(h16x8 a, h16x8 b, f32x4 c) {
  return __builtin_amdgcn_mfma_f32_16x16x32_f16(a, b, c, 0, 0, 0);
}
__device__ __forceinline__ void gl_lds16(const void* g, void* l) {
  __builtin_amdgcn_global_load_lds(
      (const __attribute__((address_space(1))) unsigned*)g,
      (__attribute__((address_space(3))) unsigned*)l, 16, 0, 0);
}
__device__ __forceinline__ u64 wave_max_u64(u64 k) {
#pragma unroll
  for (int off = 32; off; off >>= 1) {
    u64 o = __shfl_xor(k, off);
    if (o > k) k = o;
  }
  return k;
}

// dtype detector (insurance): flag=1 means inputs are f32 (expected)
__global__ void detect_dtype(const u16* __restrict__ X, int* __restrict__ flag) {
  __shared__ int cnt;
  if (threadIdx.x == 0) cnt = 0;
  __syncthreads();
  int sane = 0;
#pragma unroll
  for (int j = 0; j < 16; ++j) {
    u16 u = X[(threadIdx.x * 16 + j) * 2];
    int e = (u >> 7) & 0xff;
    if (u == 0 || (e >= 112 && e <= 142)) sane++;
  }
  atomicAdd(&cnt, sane);
  __syncthreads();
  if (threadIdx.x == 0) *flag = (cnt < 3072) ? 1 : 0;
}

// split input to hi/lo fp16 + optional f32 copy
__global__ __launch_bounds__(256) void split_input3(
    const void* __restrict__ in, h16* __restrict__ hi, h16* __restrict__ lo,
    float* __restrict__ f32out, int n, const int* __restrict__ flag) {
  int f = *flag;
  int stride = gridDim.x * 256;
  for (int i = blockIdx.x * 256 + threadIdx.x; i < n; i += stride) {
    float x = f ? ((const float*)in)[i] : b2f(((const u16*)in)[i]);
    h16 h = (h16)x;
    hi[i] = h;
    lo[i] = (h16)(x - (float)h);
    if (f32out) f32out[i] = x;
  }
}

// split f32 buffer to hi/lo fp16
__global__ __launch_bounds__(256) void split_f32h(
    const float* __restrict__ in, h16* __restrict__ hi, h16* __restrict__ lo,
    int n) {
  int stride = gridDim.x * 256;
  for (int i = blockIdx.x * 256 + threadIdx.x; i < n; i += stride) {
    float x = in[i];
    h16 h = (h16)x;
    hi[i] = h;
    lo[i] = (h16)(x - (float)h);
  }
}

// canonicalize to f32 (theta, proj_b)
__global__ __launch_bounds__(256) void conv_f32(const void* __restrict__ in,
                                                float* __restrict__ out, int n,
                                                const int* __restrict__ flag) {
  int f = *flag;
  int stride = gridDim.x * 256;
  for (int i = blockIdx.x * 256 + threadIdx.x; i < n; i += stride)
    out[i] = f ? ((const float*)in)[i] : b2f(((const u16*)in)[i]);
}

// ---------------------------------------------------------------------------
// Split-precision NT GEMM (64x64 tile): C = alpha*(Ah Bh^T + Ah Bl^T + Al Bh^T)
// ---------------------------------------------------------------------------
template <bool BIAS>
__global__ __launch_bounds__(256) void gemm3_nt(
    const h16* __restrict__ Ah, const h16* __restrict__ Al,
    const h16* __restrict__ Bh, const h16* __restrict__ Bl,
    float* __restrict__ C, const float* __restrict__ bias, float alpha,
    int M, int Nc, int Kd, long batchA, long batchB, long batchC) {
  const h16* Abh = Ah + (size_t)blockIdx.z * batchA;
  const h16* Abl = Al + (size_t)blockIdx.z * batchA;
  const h16* Bbh = Bh + (size_t)blockIdx.z * batchB;
  const h16* Bbl = Bl + (size_t)blockIdx.z * batchB;
  float* Cb = C + (size_t)blockIdx.z * batchC;
  int bn = blockIdx.x, bm = blockIdx.y;
  int tid = threadIdx.x;
  int wid = tid >> 6, lane = tid & 63;
  __shared__ h16 Ash[64 * 40], Asl[64 * 40], Bsh[64 * 40], Bsl[64 * 40];
  f32x4 acc00 = {}, acc01 = {}, acc10 = {}, acc11 = {};
  int lr = tid >> 2;
  int lc = (tid & 3) << 3;
  size_t aoff = (size_t)(bm * 64 + lr) * Kd + lc;
  size_t boff = (size_t)(bn * 64 + lr) * Kd + lc;
  int wm = (wid & 1) * 32, wn = (wid >> 1) * 32;
  int fr = lane & 15;
  int fc = (lane >> 4) << 3;
  for (int k0 = 0; k0 < Kd; k0 += 32) {
    uint4 avh = *(const uint4*)(Abh + aoff + k0);
    uint4 avl = *(const uint4*)(Abl + aoff + k0);
    uint4 bvh = *(const uint4*)(Bbh + boff + k0);
    uint4 bvl = *(const uint4*)(Bbl + boff + k0);
    __syncthreads();
    *(uint4*)(Ash + lr * 40 + lc) = avh;
    *(uint4*)(Asl + lr * 40 + lc) = avl;
    *(uint4*)(Bsh + lr * 40 + lc) = bvh;
    *(uint4*)(Bsl + lr * 40 + lc) = bvl;
    __syncthreads();
    h16x8 a0h = *(const h16x8*)(Ash + (wm + fr) * 40 + fc);
    h16x8 a1h = *(const h16x8*)(Ash + (wm + 16 + fr) * 40 + fc);
    h16x8 b0h = *(const h16x8*)(Bsh + (wn + fr) * 40 + fc);
    h16x8 b1h = *(const h16x8*)(Bsh + (wn + 16 + fr) * 40 + fc);
    h16x8 a0l = *(const h16x8*)(Asl + (wm + fr) * 40 + fc);
    h16x8 a1l = *(const h16x8*)(Asl + (wm + 16 + fr) * 40 + fc);
    h16x8 b0l = *(const h16x8*)(Bsl + (wn + fr) * 40 + fc);
    h16x8 b1l = *(const h16x8*)(Bsl + (wn + 16 + fr) * 40 + fc);
    acc00 = mfma16(a0h, b0h, acc00);
    acc01 = mfma16(a0h, b1h, acc01);
    acc10 = mfma16(a1h, b0h, acc10);
    acc11 = mfma16(a1h, b1h, acc11);
    acc00 = mfma16(a0h, b0l, acc00);
    acc01 = mfma16(a0h, b1l, acc01);
    acc10 = mfma16(a1h, b0l, acc10);
    acc11 = mfma16(a1h, b1l, acc11);
    acc00 = mfma16(a0l, b0h, acc00);
    acc01 = mfma16(a0l, b1h, acc01);
    acc10 = mfma16(a1l, b0h, acc10);
    acc11 = mfma16(a1l, b1h, acc11);
  }
  int crow = (lane >> 4) << 2;
  int ccol = lane & 15;
  f32x4 accs[2][2] = {{acc00, acc01}, {acc10, acc11}};
#pragma unroll
  for (int i = 0; i < 2; ++i)
#pragma unroll
    for (int j = 0; j < 2; ++j) {
      int r0 = bm * 64 + wm + 16 * i + crow;
      int c0 = bn * 64 + wn + 16 * j + ccol;
#pragma unroll
      for (int rg = 0; rg < 4; ++rg) {
        float v = accs[i][j][rg] * alpha;
        if constexpr (BIAS) v += bias[c0];
        Cb[(size_t)(r0 + rg) * Nc + c0] = v;
      }
    }
}

// ---------------------------------------------------------------------------
// Split-precision NT GEMM, 128x128 tile, global_load_lds staging, XOR swizzle.
// ---------------------------------------------------------------------------
__global__ __launch_bounds__(256) void gemm3_big(
    const h16* __restrict__ Ah, const h16* __restrict__ Al,
    const h16* __restrict__ Bh, const h16* __restrict__ Bl,
    float* __restrict__ C, float alpha, int M, int Nc, int Kd) {
  __shared__ h16 sAh[128 * 32], sAl[128 * 32], sBh[128 * 32], sBl[128 * 32];
  int tid = threadIdx.x, wid = tid >> 6, lane = tid & 63;
  int bm = blockIdx.y, bn = blockIdx.x;
  int srow = 32 * wid + (lane >> 2);
  int scnk = lane & 3;
  int fr = lane & 15, fcc = lane >> 4;
  f32x4 acc[4][4] = {};
  const h16* gA[2] = {Ah, Al};
  const h16* gB[2] = {Bh, Bl};
  h16* sA[2] = {sAh, sAl};
  h16* sB[2] = {sBh, sBl};
  int wm = (wid & 1) * 64, wn = (wid >> 1) * 64;
  for (int k0 = 0; k0 < Kd; k0 += 32) {
    __syncthreads();
#pragma unroll
    for (int h = 0; h < 2; ++h) {
      int r = srow + 16 * h;
      int cs = scnk ^ ((r >> 1) & 3);
      size_t goffA = (size_t)(bm * 128 + r) * Kd + k0 + cs * 8;
      size_t goffB = (size_t)(bn * 128 + r) * Kd + k0 + cs * 8;
      int loff = (32 * wid + 16 * h) * 32;
#pragma unroll
      for (int p = 0; p < 2; ++p) {
        gl_lds16(gA[p] + goffA, sA[p] + loff);
        gl_lds16(gB[p] + goffB, sB[p] + loff);
      }
    }
    __syncthreads();
    h16x8 fa[2][4], fb[2][4];
#pragma unroll
    for (int i = 0; i < 4; ++i) {
      int ra = wm + 16 * i + fr;
      int ca = (fcc ^ ((ra >> 1) & 3)) * 8;
      fa[0][i] = *(const h16x8*)(sAh + ra * 32 + ca);
      fa[1][i] = *(const h16x8*)(sAl + ra * 32 + ca);
      int rb = wn + 16 * i + fr;
      int cb = (fcc ^ ((rb >> 1) & 3)) * 8;
      fb[0][i] = *(const h16x8*)(sBh + rb * 32 + cb);
      fb[1][i] = *(const h16x8*)(sBl + rb * 32 + cb);
    }
#pragma unroll
    for (int i = 0; i < 4; ++i)
#pragma unroll
      for (int j = 0; j < 4; ++j) {
        acc[i][j] = mfma16(fa[0][i], fb[0][j], acc[i][j]);
        acc[i][j] = mfma16(fa[0][i], fb[1][j], acc[i][j]);
        acc[i][j] = mfma16(fa[1][i], fb[0][j], acc[i][j]);
      }
  }
  int crow = (lane >> 4) << 2, ccol = lane & 15;
#pragma unroll
  for (int i = 0; i < 4; ++i)
#pragma unroll
    for (int j = 0; j < 4; ++j) {
      int r0 = bm * 128 + wm + 16 * i + crow;
      int c0 = bn * 128 + wn + 16 * j + ccol;
#pragma unroll
      for (int rg = 0; rg < 4; ++rg)
        C[(size_t)(r0 + rg) * Nc + c0] = acc[i][j][rg] * alpha;
    }
}

// ---------------------------------------------------------------------------
// Plain fp16 NT GEMM, 128x128 tile, K-SPLIT over blockIdx.z (Kc per slice).
// Writes f32 partials: Cpart[z][4096][256]. M=4096, Nc=256 fixed.
// ---------------------------------------------------------------------------
__global__ __launch_bounds__(256) void gemm_ks(
    const h16* __restrict__ A, const h16* __restrict__ B,
    float* __restrict__ Cpart, int Kd, int Kc) {
  __shared__ h16 sA[128 * 32], sB[128 * 32];
  int tid = threadIdx.x, wid = tid >> 6, lane = tid & 63;
  int bm = blockIdx.y, bn = blockIdx.x, kz = blockIdx.z;
  int kbase = kz * Kc;
  int srow = 32 * wid + (lane >> 2);
  int scnk = lane & 3;
  int fr = lane & 15, fcc = lane >> 4;
  f32x4 acc[4][4] = {};
  int wm = (wid & 1) * 64, wn = (wid >> 1) * 64;
  for (int k0 = 0; k0 < Kc; k0 += 32) {
    __syncthreads();
#pragma unroll
    for (int h = 0; h < 2; ++h) {
      int r = srow + 16 * h;
      int cs = scnk ^ ((r >> 1) & 3);
      size_t goffA = (size_t)(bm * 128 + r) * Kd + kbase + k0 + cs * 8;
      size_t goffB = (size_t)(bn * 128 + r) * Kd + kbase + k0 + cs * 8;
      int loff = (32 * wid + 16 * h) * 32;
      gl_lds16(A + goffA, sA + loff);
      gl_lds16(B + goffB, sB + loff);
    }
    __syncthreads();
    h16x8 fa[4], fb[4];
#pragma unroll
    for (int i = 0; i < 4; ++i) {
      int ra = wm + 16 * i + fr;
      int ca = (fcc ^ ((ra >> 1) & 3)) * 8;
      fa[i] = *(const h16x8*)(sA + ra * 32 + ca);
      int rb = wn + 16 * i + fr;
      int cb = (fcc ^ ((rb >> 1) & 3)) * 8;
      fb[i] = *(const h16x8*)(sB + rb * 32 + cb);
    }
#pragma unroll
    for (int i = 0; i < 4; ++i)
#pragma unroll
      for (int j = 0; j < 4; ++j)
        acc[i][j] = mfma16(fa[i], fb[j], acc[i][j]);
  }
  float* Cp = Cpart + (size_t)kz * 4096 * 256;
  int crow = (lane >> 4) << 2, ccol = lane & 15;
#pragma unroll
  for (int i = 0; i < 4; ++i)
#pragma unroll
    for (int j = 0; j < 4; ++j) {
      int r0 = bm * 128 + wm + 16 * i + crow;
      int c0 = bn * 128 + wn + 16 * j + ccol;
#pragma unroll
      for (int rg = 0; rg < 4; ++rg)
        Cp[(size_t)(r0 + rg) * 256 + c0] = acc[i][j][rg];
    }
}

// Zk += (*scptr) * rowSinv[row] * sum_z Cpart[z]
__global__ __launch_bounds__(256) void ks_reduce(
    const float* __restrict__ Cpart, const float* __restrict__ scptr,
    const float* __restrict__ rowSinv, float* __restrict__ Zk) {
  int i = (blockIdx.x * 256 + threadIdx.x) * 4;  // grid 1024
  float4 s = {0.f, 0.f, 0.f, 0.f};
#pragma unroll
  for (int z = 0; z < 8; ++z) {
    float4 p = *(const float4*)(Cpart + (size_t)z * 4096 * 256 + i);
    s.x += p.x; s.y += p.y; s.z += p.z; s.w += p.w;
  }
  float sc = (*scptr) * rowSinv[i >> 8];
  float4 zk = *(float4*)(Zk + i);
  zk.x += sc * s.x; zk.y += sc * s.y; zk.z += sc * s.z; zk.w += sc * s.w;
  *(float4*)(Zk + i) = zk;
}

// 16-bit transpose
__global__ __launch_bounds__(256) void transpose16(
    const u16* __restrict__ in, u16* __restrict__ out, int rows, int cols) {
  __shared__ u16 t[32][33];
  const u16* ib = in + (size_t)blockIdx.z * rows * cols;
  u16* ob = out + (size_t)blockIdx.z * rows * cols;
  int r0 = blockIdx.x * 32, c0 = blockIdx.y * 32;
  int tx = threadIdx.x & 31, ty = threadIdx.x >> 5;
#pragma unroll
  for (int i = 0; i < 32; i += 8)
    t[ty + i][tx] = ib[(size_t)(r0 + ty + i) * cols + c0 + tx];
  __syncthreads();
#pragma unroll
  for (int i = 0; i < 32; i += 8)
    ob[(size_t)(c0 + ty + i) * rows + r0 + tx] = t[tx][ty + i];
}

// scalars: w=softmax(alpha)->scal[0..3], rho=sigmoid(rho_raw)->scal[4]
__global__ void prep_scalars(const void* __restrict__ alpha,
                             const void* __restrict__ rho_raw,
                             float* __restrict__ scal,
                             const int* __restrict__ flag) {
  if (threadIdx.x == 0) {
    int f = *flag;
    float a[4], e[4], m = -1e30f, s = 0.f;
    for (int i = 0; i < 4; ++i) {
      a[i] = f ? ((const float*)alpha)[i] : b2f(((const u16*)alpha)[i]);
      m = fmaxf(m, a[i]);
    }
    for (int i = 0; i < 4; ++i) { e[i] = expf(a[i] - m); s += e[i]; }
    for (int i = 0; i < 4; ++i) scal[i] = e[i] / s;
    float rr = f ? ((const float*)rho_raw)[0] : b2f(((const u16*)rho_raw)[0]);
    scal[4] = 1.f / (1.f + expf(-rr));
  }
}

// ---------------------------------------------------------------------------
// fused per-row (one wave per row): max -> threshold T -> exp/E-write +
// candidate push -> exact jax-tiebreak top-16 from candidates
// ---------------------------------------------------------------------------
__global__ __launch_bounds__(256) void row_softmax_topk(
    const float* __restrict__ A, float* __restrict__ topv,
    int* __restrict__ topi, h16* __restrict__ E, float* __restrict__ rowSinv,
    int khead) {
  __shared__ u64 candK[4][256];
  __shared__ int candN[4];
  int wid = threadIdx.x >> 6, lane = threadIdx.x & 63;
  int row = blockIdx.x * 4 + wid;
  const float* arow = A + ((size_t)row << 12);
  if (lane == 0) candN[wid] = 0;
  __syncthreads();
  float lm = -INFINITY;
#pragma unroll
  for (int t = 0; t < 16; ++t) {
    float4 v = *(const float4*)(arow + (t << 8) + (lane << 2));
    lm = fmaxf(lm, fmaxf(fmaxf(v.x, v.y), fmaxf(v.z, v.w)));
  }
  float m = lm;
#pragma unroll
  for (int off = 32; off; off >>= 1) m = fmaxf(m, __shfl_xor(m, off));
  u64 lk = ((u64)fkey(lm) << 32) | (unsigned)lane;
  float T = 0.f;
  for (int r = 0; r < 16; ++r) {
    u64 k2 = wave_max_u64(lk);
    if (lk == k2) lk = 0;
    if (r == 15) T = unfkey((unsigned)(k2 >> 32));
  }
  h16* erow = E + ((size_t)row << 12);
  int* cn = &candN[wid];
  u64* ck = candK[wid];
  float s = 0.f;
  for (int t = 0; t < 16; ++t) {
    int c = (t << 8) + (lane << 2);
    float4 v = *(const float4*)(arow + c);
    float e0 = __expf(v.x - m), e1 = __expf(v.y - m);
    float e2 = __expf(v.z - m), e3 = __expf(v.w - m);
    s += (e0 + e1) + (e2 + e3);
    h16x4 hv = {(h16)e0, (h16)e1, (h16)e2, (h16)e3};
    *(h16x4*)(erow + c) = hv;
    if (v.x >= T) {
      int sl = atomicAdd(cn, 1);
      if (sl < 256) ck[sl] = ((u64)fkey(v.x) << 32) | (unsigned)(~(unsigned)c);
    }
    if (v.y >= T) {
      int sl = atomicAdd(cn, 1);
      if (sl < 256) ck[sl] = ((u64)fkey(v.y) << 32) | (unsigned)(~(unsigned)(c + 1));
    }
    if (v.z >= T) {
      int sl = atomicAdd(cn, 1);
      if (sl < 256) ck[sl] = ((u64)fkey(v.z) << 32) | (unsigned)(~(unsigned)(c + 2));
    }
    if (v.w >= T) {
      int sl = atomicAdd(cn, 1);
      if (sl < 256) ck[sl] = ((u64)fkey(v.w) << 32) | (unsigned)(~(unsigned)(c + 3));
    }
  }
#pragma unroll
  for (int off = 32; off; off >>= 1) s += __shfl_xor(s, off);
  if (lane == 0) rowSinv[row] = 1.f / s;
  __syncthreads();
  int cnt = min(*cn, 256);
  u64 loc[4] = {0ull, 0ull, 0ull, 0ull};
  int nl = 0;
  for (int j = lane; j < cnt; j += 64)
    if (nl < 4) loc[nl++] = ck[j];
#define CSW(a, b)                     \
  {                                   \
    if (loc[b] > loc[a]) {            \
      u64 tt = loc[a];                \
      loc[a] = loc[b];                \
      loc[b] = tt;                    \
    }                                 \
  }
  CSW(0, 1) CSW(2, 3) CSW(0, 2) CSW(1, 3) CSW(1, 2)
#undef CSW
  float myv = 0.f;
  int myi = 0;
  float sum16 = 0.f;
  for (int r = 0; r < 16; ++r) {
    u64 key = loc[0];
    u64 k2 = wave_max_u64(key);
    float wv = unfkey((unsigned)(k2 >> 32));
    int wi = (int)(~(unsigned)(k2 & 0xffffffffu));
    if (key == k2 && key != 0ull) {
      loc[0] = loc[1];
      loc[1] = loc[2];
      loc[2] = loc[3];
      loc[3] = 0ull;
    }
    sum16 += expf(wv - m);
    if (r == lane) { myv = wv; myi = wi; }
  }
  if (lane < 16) {
    size_t o = (((size_t)khead << 12) + row) * 16 + lane;
    topv[o] = expf(myv - m) / (sum16 + 1e-9f * s);
    topi[o] = myi;
  }
}

// ---------------------------------------------------------------------------
// sparse hypergraph: S_norm = C C^T
// ---------------------------------------------------------------------------
__global__ __launch_bounds__(256) void edge_prep(
    const float* __restrict__ topv, const int* __restrict__ topi,
    float* __restrict__ Dv, int* __restrict__ cnt, float* __restrict__ DeIS) {
  int e = blockIdx.x * 256 + threadIdx.x;  // grid 64
  float s = 0.f;
#pragma unroll
  for (int p = 0; p < 16; ++p) {
    float v = topv[e * 16 + p];
    int i = topi[e * 16 + p];
    s += v;
    atomicAdd(&Dv[i], v);
    atomicAdd(&cnt[i], 1);
  }
  DeIS[e] = 1.0f / sqrtf(s + 1e-9f);
}

__global__ void dv_isqrt(const float* __restrict__ Dv, float* __restrict__ Dvis) {
  int i = blockIdx.x * 256 + threadIdx.x;
  Dvis[i] = sqrtf(1.0f / (Dv[i] + 1e-9f));
}

// exclusive scan of cnt[4096] -> rowptr[4097], cur=rowptr
__global__ __launch_bounds__(256) void scan_rowptr(const int* __restrict__ cnt,
                                                   int* __restrict__ rowptr,
                                                   int* __restrict__ cur) {
  __shared__ int part[256];
  int tid = threadIdx.x;
  int base = tid * 16;
  int loc[16];
  int s = 0;
#pragma unroll
  for (int j = 0; j < 16; ++j) { loc[j] = s; s += cnt[base + j]; }
  part[tid] = s;
  __syncthreads();
  for (int off = 1; off < 256; off <<= 1) {
    int v = (tid >= off) ? part[tid - off] : 0;
    __syncthreads();
    part[tid] += v;
    __syncthreads();
  }
  int pre = (tid == 0) ? 0 : part[tid - 1];
#pragma unroll
  for (int j = 0; j < 16; ++j) {
    int r = pre + loc[j];
    rowptr[base + j] = r;
    cur[base + j] = r;
  }
  if (tid == 255) rowptr[4096] = part[255];
}

// fill per-edge cvals and CSR-transpose (colE, cvalR)
__global__ __launch_bounds__(256) void csr_fill(
    const float* __restrict__ topv, const int* __restrict__ topi,
    const float* __restrict__ Dvis, const float* __restrict__ DeIS,
    int* __restrict__ cur, float* __restrict__ cvals, int* __restrict__ colE,
    float* __restrict__ cvalR) {
  int e = blockIdx.x * 256 + threadIdx.x;  // grid 64
  float deis = DeIS[e];
#pragma unroll
  for (int p = 0; p < 16; ++p) {
    int i = topi[e * 16 + p];
    float c = Dvis[i] * topv[e * 16 + p] * deis;
    cvals[e * 16 + p] = c;
    int slot = atomicAdd(&cur[i], 1);
    colE[slot] = e;
    cvalR[slot] = c;
  }
}

// g[e] = sum_p c[e,p] * v[idx[e,p]]
__global__ __launch_bounds__(256) void spmv_edge(
    const float* __restrict__ cvals, const int* __restrict__ topi,
    const float* __restrict__ v, float* __restrict__ g) {
  int e = blockIdx.x * 256 + threadIdx.x;  // grid 64
  float acc = 0.f;
#pragma unroll
  for (int p = 0; p < 16; ++p)
    acc += cvals[e * 16 + p] * v[topi[e * 16 + p]];
  g[e] = acc;
}

// vout[i] = vin[i] - sum_{j in row i} cvalR[j]*g[colE[j]]
__global__ __launch_bounds__(256) void spmv_row(
    const int* __restrict__ rowptr, const int* __restrict__ colE,
    const float* __restrict__ cvalR, const float* __restrict__ g,
    const float* __restrict__ vin, float* __restrict__ vout) {
  int wid = threadIdx.x >> 6, lane = threadIdx.x & 63;
  int row = blockIdx.x * 4 + wid;  // grid 1024
  int s = rowptr[row], e = rowptr[row + 1];
  float acc = 0.f;
  for (int j = s + lane; j < e; j += 64) acc += cvalR[j] * g[colE[j]];
#pragma unroll
  for (int off = 32; off; off >>= 1) acc += __shfl_xor(acc, off);
  if (lane == 0) vout[row] = vin[row] - acc;
}

// G[e,:] = sum_p c[e,p] * M[idx[e,p],:]  — MLP-unrolled (16 gathers in flight)
__global__ __launch_bounds__(256) void spmm_edge(
    const float* __restrict__ cvals, const int* __restrict__ topi,
    const float* __restrict__ M, float* __restrict__ G) {
  int wid = threadIdx.x >> 6, lane = threadIdx.x & 63;
  int e = blockIdx.x * 4 + wid;  // grid 4096
  int cb = lane << 2;
  const float* cv = cvals + ((size_t)e << 4);
  const int* ti = topi + ((size_t)e << 4);
  float cc[16];
  int ix[16];
#pragma unroll
  for (int p = 0; p < 16; ++p) { cc[p] = cv[p]; ix[p] = ti[p]; }
  float4 acc[4] = {};
#pragma unroll
  for (int h = 0; h < 2; ++h) {
    float4 g[8];
#pragma unroll
    for (int p = 0; p < 8; ++p)
      g[p] = *(const float4*)(M + ((size_t)ix[h * 8 + p] << 8) + cb);
#pragma unroll
    for (int p = 0; p < 8; ++p) {
      float c = cc[h * 8 + p];
      float4 gg = g[p];
      int a = p & 3;
      acc[a].x += c * gg.x; acc[a].y += c * gg.y;
      acc[a].z += c * gg.z; acc[a].w += c * gg.w;
    }
  }
  float4 r;
  r.x = (acc[0].x + acc[1].x) + (acc[2].x + acc[3].x);
  r.y = (acc[0].y + acc[1].y) + (acc[2].y + acc[3].y);
  r.z = (acc[0].z + acc[1].z) + (acc[2].z + acc[3].z);
  r.w = (acc[0].w + acc[1].w) + (acc[2].w + acc[3].w);
  *(float4*)(G + ((size_t)e << 8) + cb) = r;
}

// Z[i,:] = sum_{j in row i} cvalR[j] * G[colE[j],:]  — 8-wide MLP unroll
__global__ __launch_bounds__(256) void spmm_row(
    const int* __restrict__ rowptr, const int* __restrict__ colE,
    const float* __restrict__ cvalR, const float* __restrict__ G,
    float* __restrict__ Z) {
  int wid = threadIdx.x >> 6, lane = threadIdx.x & 63;
  int row = blockIdx.x * 4 + wid;  // grid 1024
  int cb = lane << 2;
  int s = rowptr[row], e = rowptr[row + 1];
  float4 acc[4] = {};
  int j = s;
  for (; j + 8 <= e; j += 8) {
    int ix[8];
    float cc[8];
#pragma unroll
    for (int t = 0; t < 8; ++t) { ix[t] = colE[j + t]; cc[t] = cvalR[j + t]; }
    float4 g[8];
#pragma unroll
    for (int t = 0; t < 8; ++t)
      g[t] = *(const float4*)(G + ((size_t)ix[t] << 8) + cb);
#pragma unroll
    for (int t = 0; t < 8; ++t) {
      float c = cc[t];
      float4 gg = g[t];
      int a = t & 3;
      acc[a].x += c * gg.x; acc[a].y += c * gg.y;
      acc[a].z += c * gg.z; acc[a].w += c * gg.w;
    }
  }
  for (; j < e; ++j) {
    float c = cvalR[j];
    float4 gg = *(const float4*)(G + ((size_t)colE[j] << 8) + cb);
    acc[0].x += c * gg.x; acc[0].y += c * gg.y;
    acc[0].z += c * gg.z; acc[0].w += c * gg.w;
  }
  float4 r;
  r.x = (acc[0].x + acc[1].x) + (acc[2].x + acc[3].x);
  r.y = (acc[0].y + acc[1].y) + (acc[2].y + acc[3].y);
  r.z = (acc[0].z + acc[1].z) + (acc[2].z + acc[3].z);
  r.w = (acc[0].w + acc[1].w) + (acc[2].w + acc[3].w);
  *(float4*)(Z + ((size_t)row << 8) + cb) = r;
}

// v0: bit-exact jax.random.normal(key(1), (4096,1), f32)
__global__ __launch_bounds__(256) void init_v0(float* __restrict__ v) {
  int tid = blockIdx.x * 256 + threadIdx.x;
  unsigned j = (unsigned)(tid & 2047);
  unsigned x0 = j, x1 = j + 2048u;
  const unsigned ks0 = 0u, ks1 = 1u, ks2 = 0x1BD11BDAu;
  x0 += ks0; x1 += ks1;
#define TF_R(r)                                  \
  {                                              \
    x0 += x1;                                    \
    x1 = (x1 << (r)) | (x1 >> (32 - (r)));       \
    x1 ^= x0;                                    \
  }
  TF_R(13) TF_R(15) TF_R(26) TF_R(6)  x0 += ks1; x1 += ks2 + 1u;
  TF_R(17) TF_R(29) TF_R(16) TF_R(24) x0 += ks2; x1 += ks0 + 2u;
  TF_R(13) TF_R(15) TF_R(26) TF_R(6)  x0 += ks0; x1 += ks1 + 3u;
  TF_R(17) TF_R(29) TF_R(16) TF_R(24) x0 += ks1; x1 += ks2 + 4u;
  TF_R(13) TF_R(15) TF_R(26) TF_R(6)  x0 += ks2; x1 += ks0 + 5u;
#undef TF_R
  unsigned bits = (tid < 2048) ? x0 : x1;
  float u01 = __uint_as_float((bits >> 9) | 0x3f800000u) - 1.0f;
  const float lo = -0.99999994f;
  float u = fmaxf(lo, u01 * 2.0f + lo);
  float w = -log1pf(-u * u);
  float p;
  if (w < 5.0f) {
    float t = w - 2.5f;
    p = 2.81022636e-08f;
    p = 3.43273939e-07f + p * t;
    p = -3.5233877e-06f + p * t;
    p = -4.39150654e-06f + p * t;
    p = 0.00021858087f + p * t;
    p = -0.00125372503f + p * t;
    p = -0.00417768164f + p * t;
    p = 0.246640727f + p * t;
    p = 1.50140941f + p * t;
  } else {
    float t = sqrtf(w) - 3.0f;
    p = -0.000200214257f;
    p = 0.000100950558f + p * t;
    p = 0.00134934322f + p * t;
    p = -0.00367342844f + p * t;
    p = 0.00573950773f + p * t;
    p = -0.0076224613f + p * t;
    p = 0.00943887047f + p * t;
    p = 1.00167406f + p * t;
    p = 2.83297682f + p * t;
  }
  v[tid] = 1.41421354f * (p * u);
}

// lam = clip((w5.w6)/(w5.w5), 1e-3) -> scal[5]
__global__ __launch_bounds__(256) void pi_dots(const float* __restrict__ w5,
                                               const float* __restrict__ w6,
                                               float* __restrict__ scal) {
  __shared__ float r1[256], r2[256];
  int tid = threadIdx.x;
  float a = 0.f, b = 0.f;
  for (int i = tid; i < 4096; i += 256) {
    float x = w5[i];
    a += x * x;
    b += x * w6[i];
  }
  r1[tid] = a; r2[tid] = b;
  __syncthreads();
  for (int off = 128; off; off >>= 1) {
    if (tid < off) { r1[tid] += r1[tid + off]; r2[tid] += r2[tid + off]; }
    __syncthreads();
  }
  if (tid == 0) scal[5] = fmaxf(r2[0] / r1[0], 1e-3f);
}

// T1 = (c1-1)X - c1*SnX
__global__ __launch_bounds__(256) void t1_simple(
    const float* __restrict__ SnX, const float* __restrict__ Xf,
    const float* __restrict__ scal, float* __restrict__ T1) {
  int i = blockIdx.x * 256 + threadIdx.x;  // grid 4096
  float c1 = 2.0f / scal[5];
  T1[i] = (c1 - 1.0f) * Xf[i] - c1 * SnX[i];
}

// T2, cheb combine, elu, mix -> Zmix split hi/lo fp16
__global__ __launch_bounds__(256) void combine_kernel(
    const float* __restrict__ Xf, const float* __restrict__ T1,
    const float* __restrict__ SnT1, const float* __restrict__ Zk,
    const float* __restrict__ thetaf, const float* __restrict__ scal,
    h16* __restrict__ Zmh, h16* __restrict__ Zml) {
  int idx = blockIdx.x * 256 + threadIdx.x;  // grid 4096
  int d = idx & 255;
  float c1 = 2.0f / scal[5];
  float rho = scal[4];
  float x = Xf[idx];
  float t1 = T1[idx];
  float t2 = 2.0f * ((c1 - 1.0f) * t1 - c1 * SnT1[idx]) - x;
  float o = x * thetaf[d] + t1 * thetaf[256 + d] + t2 * thetaf[512 + d];
  float zs = o > 0.0f ? o : expm1f(o);
  float zm = rho * zs + (1.0f - rho) * Zk[idx];
  h16 h = (h16)zm;
  Zmh[idx] = h;
  Zml[idx] = (h16)(zm - (float)h);
}

// ---------------------------------------------------------------------------
extern "C" void kernel_launch(void* const* d_in, const int* in_sizes, int n_in,
                              void* d_out, int out_size, void* d_ws,
                              size_t ws_size, hipStream_t stream) {
  (void)in_sizes; (void)n_in; (void)out_size;
  const void* Xin = d_in[0];
  const void* Lin = d_in[1];
  const void* alpha = d_in[2];
  const void* theta = d_in[3];
  const void* rho_raw = d_in[4];
  const void* Wpin = d_in[5];
  const void* bpin = d_in[6];
  float* out = (float*)d_out;

  char* base = (char*)d_ws;
  size_t off = 0;
  auto alloc = [&](size_t bytes) -> char* {
    char* p = base + off;
    off += (bytes + 255) & ~(size_t)255;
    return p;
  };
  float* Abuf = (float*)alloc((size_t)4096 * 4096 * 4);  // A; ks-partials; G
  h16* Ebuf = (h16*)alloc((size_t)4096 * 4096 * 2);      // Yf alias; E per head
  h16* Yhi = (h16*)alloc((size_t)4 * 4096 * 256 * 2);
  h16* Ylo = (h16*)alloc((size_t)4 * 4096 * 256 * 2);
  h16* Xhi = (h16*)alloc((size_t)4096 * 256 * 2);
  h16* Xlo = (h16*)alloc((size_t)4096 * 256 * 2);
  float* Xf = (float*)alloc((size_t)4096 * 256 * 4);
  h16* XT = (h16*)alloc((size_t)256 * 4096 * 2);
  h16* Lhi = (h16*)alloc((size_t)4 * 256 * 256 * 2);
  h16* Llo = (h16*)alloc((size_t)4 * 256 * 256 * 2);
  h16* LThi = (h16*)alloc((size_t)4 * 256 * 256 * 2);
  h16* LTlo = (h16*)alloc((size_t)4 * 256 * 256 * 2);
  h16* Whi = (h16*)alloc((size_t)256 * 256 * 2);
  h16* Wlo = (h16*)alloc((size_t)256 * 256 * 2);
  float* Zk = (float*)alloc((size_t)4096 * 256 * 4);
  float* SnX = (float*)alloc((size_t)4096 * 256 * 4);  // then SnT1
  float* T1 = (float*)alloc((size_t)4096 * 256 * 4);
  h16* Zmh = (h16*)alloc((size_t)4096 * 256 * 2);
  h16* Zml = (h16*)alloc((size_t)4096 * 256 * 2);
  float* topv = (float*)alloc((size_t)4 * 4096 * 16 * 4);
  int* topi = (int*)alloc((size_t)4 * 4096 * 16 * 4);
  float* cvals = (float*)alloc((size_t)262144 * 4);
  int* colE = (int*)alloc((size_t)262144 * 4);
  float* cvalR = (float*)alloc((size_t)262144 * 4);
  int* rowptr = (int*)alloc(4097 * 4);
  int* cur = (int*)alloc(4096 * 4);
  int* cnt = (int*)alloc(4096 * 4);
  float* Dv = (float*)alloc(4096 * 4);
  float* Dvis = (float*)alloc(4096 * 4);
  float* DeIS = (float*)alloc(16384 * 4);
  float* gE = (float*)alloc(16384 * 4);
  float* wA = (float*)alloc(4096 * 4);
  float* wB = (float*)alloc(4096 * 4);
  float* rowSinv = (float*)alloc(4096 * 4);
  float* thetaf = (float*)alloc(768 * 4);
  float* biasf = (float*)alloc(256 * 4);
  float* scal = (float*)alloc(256);
  int* flag = (int*)alloc(256);
  if (off > ws_size) return;
  float* Yf = (float*)Ebuf;  // 16 MB alias; dead before E written
  float* G = (float*)Abuf;   // 16 MB alias; dead after last head's softmax
  float* Kpart = Abuf;       // 32 MB alias; A dead after row_softmax reads it

  detect_dtype<<<1, 256, 0, stream>>>((const u16*)Xin, flag);
  split_input3<<<1024, 256, 0, stream>>>(Xin, Xhi, Xlo, Xf, 4096 * 256, flag);
  split_input3<<<256, 256, 0, stream>>>(Lin, Lhi, Llo, nullptr, 4 * 256 * 256,
                                        flag);
  split_input3<<<64, 256, 0, stream>>>(Wpin, Whi, Wlo, nullptr, 256 * 256, flag);
  conv_f32<<<1, 256, 0, stream>>>(theta, thetaf, 768, flag);
  conv_f32<<<1, 256, 0, stream>>>(bpin, biasf, 256, flag);
  prep_scalars<<<1, 64, 0, stream>>>(alpha, rho_raw, scal, flag);
  transpose16<<<dim3(128, 8, 1), 256, 0, stream>>>((const u16*)Xhi, (u16*)XT,
                                                   4096, 256);
  transpose16<<<dim3(8, 8, 4), 256, 0, stream>>>((const u16*)Lhi, (u16*)LThi,
                                                 256, 256);
  transpose16<<<dim3(8, 8, 4), 256, 0, stream>>>((const u16*)Llo, (u16*)LTlo,
                                                 256, 256);
  // Yf = X @ L_k (split fp16, fused), batched z=4
  gemm3_nt<false><<<dim3(4, 64, 4), 256, 0, stream>>>(
      Xhi, Xlo, LThi, LTlo, Yf, nullptr, 1.0f, 4096, 256, 256,
      0L, 256L * 256L, 4096L * 256L);
  split_f32h<<<2048, 256, 0, stream>>>(Yf, Yhi, Ylo, 4 * 4096 * 256);
  hipMemsetAsync(Zk, 0, (size_t)4096 * 256 * 4, stream);
  for (int k = 0; k < 4; ++k) {
    // A = Y_k @ X^T / 16 (split fp16, 128x128 tile, global_load_lds)
    gemm3_big<<<dim3(32, 32), 256, 0, stream>>>(
        Yhi + (size_t)k * 4096 * 256, Ylo + (size_t)k * 4096 * 256, Xhi, Xlo,
        Abuf, 0.0625f, 4096, 4096, 256);
    row_softmax_topk<<<1024, 256, 0, stream>>>(Abuf, topv, topi, Ebuf, rowSinv,
                                               k);
    // E @ X via K-split MFMA into 8 f32 partials (A is dead; reuse Abuf)
    gemm_ks<<<dim3(2, 32, 8), 256, 0, stream>>>(Ebuf, XT, Kpart, 4096, 512);
    // Zk += w_k * invS[row] * sum_z partial[z]
    ks_reduce<<<1024, 256, 0, stream>>>(Kpart, scal + k, rowSinv, Zk);
  }
  // sparse hypergraph Laplacian (no dense S)
  hipMemsetAsync(Dv, 0, 4096 * 4, stream);
  hipMemsetAsync(cnt, 0, 4096 * 4, stream);
  edge_prep<<<64, 256, 0, stream>>>(topv, topi, Dv, cnt, DeIS);
  dv_isqrt<<<16, 256, 0, stream>>>(Dv, Dvis);
  scan_rowptr<<<1, 256, 0, stream>>>(cnt, rowptr, cur);
  csr_fill<<<64, 256, 0, stream>>>(topv, topi, Dvis, DeIS, cur, cvals, colE,
                                   cvalR);
  init_v0<<<16, 256, 0, stream>>>(wA);
  for (int it = 0; it < 6; ++it) {
    const float* vi = (it & 1) ? wB : wA;
    float* vo = (it & 1) ? wA : wB;
    spmv_edge<<<64, 256, 0, stream>>>(cvals, topi, vi, gE);
    spmv_row<<<1024, 256, 0, stream>>>(rowptr, colE, cvalR, gE, vi, vo);
  }
  pi_dots<<<1, 256, 0, stream>>>(wB, wA, scal);
  // SnX = S_norm @ X (sparse, f32-exact)
  spmm_edge<<<4096, 256, 0, stream>>>(cvals, topi, Xf, G);
  spmm_row<<<1024, 256, 0, stream>>>(rowptr, colE, cvalR, G, SnX);
  t1_simple<<<4096, 256, 0, stream>>>(SnX, Xf, scal, T1);
  // SnT1 = S_norm @ T1 (overwrite SnX)
  spmm_edge<<<4096, 256, 0, stream>>>(cvals, topi, T1, G);
  spmm_row<<<1024, 256, 0, stream>>>(rowptr, colE, cvalR, G, SnX);
  combine_kernel<<<4096, 256, 0, stream>>>(Xf, T1, SnX, Zk, thetaf, scal, Zmh,
                                           Zml);
  // out = Zmix @ proj_w^T + proj_b (split fp16, f32 out)
  gemm3_nt<true><<<dim3(4, 64, 1), 256, 0, stream>>>(
      Zmh, Zml, Whi, Wlo, out, biasf, 1.0f, 4096, 256, 256, 0L, 0L, 0L);
}

// Round 8
// 761.098 us; speedup vs baseline: 1.6873x; 1.0004x over previous
//
#include <hip/hip_runtime.h>

typedef unsigned short u16;
typedef unsigned long long u64;
typedef _Float16 h16;
typedef __attribute__((ext_vector_type(8))) _Float16 h16x8;
typedef __attribute__((ext_vector_type(4))) _Float16 h16x4;
typedef __attribute__((ext_vector_type(4))) float f32x4;

__device__ __forceinline__ float b2f(u16 u) {
  unsigned x = ((unsigned)u) << 16;
  return __uint_as_float(x);
}
__device__ __forceinline__ unsigned fkey(float f) {
  unsigned b = __float_as_uint(f);
  return (b & 0x80000000u) ? ~b : (b | 0x80000000u);
}
__device__ __forceinline__ float unfkey(unsigned u) {
  unsigned b = (u & 0x80000000u) ? (u ^ 0x80000000u) : ~u;
  return __uint_as_float(b);
}
__device__ __forceinline__ f32x4 mfma16(h16x8 a, h16x8 b, f32x4 c) {
  return __builtin_amdgcn_mfma_f32_16x16x32_f16(a, b, c, 0, 0, 0);
}
__device__ __forceinline__ void gl_lds16(const void* g, void* l) {
  __builtin_amdgcn_global_load_lds(
      (const __attribute__((address_space(1))) unsigned*)g,
      (__attribute__((address_space(3))) unsigned*)l, 16, 0, 0);
}
__device__ __forceinline__ u64 wave_max_u64(u64 k) {
#pragma unroll
  for (int off = 32; off; off >>= 1) {
    u64 o = __shfl_xor(k, off);
    if (o > k) k = o;
  }
  return k;
}

// dtype detector (insurance): flag=1 means inputs are f32 (expected)
__global__ void detect_dtype(const u16* __restrict__ X, int* __restrict__ flag) {
  __shared__ int cnt;
  if (threadIdx.x == 0) cnt = 0;
  __syncthreads();
  int sane = 0;
#pragma unroll
  for (int j = 0; j < 16; ++j) {
    u16 u = X[(threadIdx.x * 16 + j) * 2];
    int e = (u >> 7) & 0xff;
    if (u == 0 || (e >= 112 && e <= 142)) sane++;
  }
  atomicAdd(&cnt, sane);
  __syncthreads();
  if (threadIdx.x == 0) *flag = (cnt < 3072) ? 1 : 0;
}

// split input to hi/lo fp16 + optional f32 copy
__global__ __launch_bounds__(256) void split_input3(
    const void* __restrict__ in, h16* __restrict__ hi, h16* __restrict__ lo,
    float* __restrict__ f32out, int n, const int* __restrict__ flag) {
  int f = *flag;
  int stride = gridDim.x * 256;
  for (int i = blockIdx.x * 256 + threadIdx.x; i < n; i += stride) {
    float x = f ? ((const float*)in)[i] : b2f(((const u16*)in)[i]);
    h16 h = (h16)x;
    hi[i] = h;
    lo[i] = (h16)(x - (float)h);
    if (f32out) f32out[i] = x;
  }
}

// split f32 buffer to hi/lo fp16
__global__ __launch_bounds__(256) void split_f32h(
    const float* __restrict__ in, h16* __restrict__ hi, h16* __restrict__ lo,
    int n) {
  int stride = gridDim.x * 256;
  for (int i = blockIdx.x * 256 + threadIdx.x; i < n; i += stride) {
    float x = in[i];
    h16 h = (h16)x;
    hi[i] = h;
    lo[i] = (h16)(x - (float)h);
  }
}

// canonicalize to f32 (theta, proj_b)
__global__ __launch_bounds__(256) void conv_f32(const void* __restrict__ in,
                                                float* __restrict__ out, int n,
                                                const int* __restrict__ flag) {
  int f = *flag;
  int stride = gridDim.x * 256;
  for (int i = blockIdx.x * 256 + threadIdx.x; i < n; i += stride)
    out[i] = f ? ((const float*)in)[i] : b2f(((const u16*)in)[i]);
}

// ---------------------------------------------------------------------------
// Split-precision NT GEMM (64x64 tile): C = alpha*(Ah Bh^T + Ah Bl^T + Al Bh^T)
// ---------------------------------------------------------------------------
template <bool BIAS>
__global__ __launch_bounds__(256) void gemm3_nt(
    const h16* __restrict__ Ah, const h16* __restrict__ Al,
    const h16* __restrict__ Bh, const h16* __restrict__ Bl,
    float* __restrict__ C, const float* __restrict__ bias, float alpha,
    int M, int Nc, int Kd, long batchA, long batchB, long batchC) {
  const h16* Abh = Ah + (size_t)blockIdx.z * batchA;
  const h16* Abl = Al + (size_t)blockIdx.z * batchA;
  const h16* Bbh = Bh + (size_t)blockIdx.z * batchB;
  const h16* Bbl = Bl + (size_t)blockIdx.z * batchB;
  float* Cb = C + (size_t)blockIdx.z * batchC;
  int bn = blockIdx.x, bm = blockIdx.y;
  int tid = threadIdx.x;
  int wid = tid >> 6, lane = tid & 63;
  __shared__ h16 Ash[64 * 40], Asl[64 * 40], Bsh[64 * 40], Bsl[64 * 40];
  f32x4 acc00 = {}, acc01 = {}, acc10 = {}, acc11 = {};
  int lr = tid >> 2;
  int lc = (tid & 3) << 3;
  size_t aoff = (size_t)(bm * 64 + lr) * Kd + lc;
  size_t boff = (size_t)(bn * 64 + lr) * Kd + lc;
  int wm = (wid & 1) * 32, wn = (wid >> 1) * 32;
  int fr = lane & 15;
  int fc = (lane >> 4) << 3;
  for (int k0 = 0; k0 < Kd; k0 += 32) {
    uint4 avh = *(const uint4*)(Abh + aoff + k0);
    uint4 avl = *(const uint4*)(Abl + aoff + k0);
    uint4 bvh = *(const uint4*)(Bbh + boff + k0);
    uint4 bvl = *(const uint4*)(Bbl + boff + k0);
    __syncthreads();
    *(uint4*)(Ash + lr * 40 + lc) = avh;
    *(uint4*)(Asl + lr * 40 + lc) = avl;
    *(uint4*)(Bsh + lr * 40 + lc) = bvh;
    *(uint4*)(Bsl + lr * 40 + lc) = bvl;
    __syncthreads();
    h16x8 a0h = *(const h16x8*)(Ash + (wm + fr) * 40 + fc);
    h16x8 a1h = *(const h16x8*)(Ash + (wm + 16 + fr) * 40 + fc);
    h16x8 b0h = *(const h16x8*)(Bsh + (wn + fr) * 40 + fc);
    h16x8 b1h = *(const h16x8*)(Bsh + (wn + 16 + fr) * 40 + fc);
    h16x8 a0l = *(const h16x8*)(Asl + (wm + fr) * 40 + fc);
    h16x8 a1l = *(const h16x8*)(Asl + (wm + 16 + fr) * 40 + fc);
    h16x8 b0l = *(const h16x8*)(Bsl + (wn + fr) * 40 + fc);
    h16x8 b1l = *(const h16x8*)(Bsl + (wn + 16 + fr) * 40 + fc);
    acc00 = mfma16(a0h, b0h, acc00);
    acc01 = mfma16(a0h, b1h, acc01);
    acc10 = mfma16(a1h, b0h, acc10);
    acc11 = mfma16(a1h, b1h, acc11);
    acc00 = mfma16(a0h, b0l, acc00);
    acc01 = mfma16(a0h, b1l, acc01);
    acc10 = mfma16(a1h, b0l, acc10);
    acc11 = mfma16(a1h, b1l, acc11);
    acc00 = mfma16(a0l, b0h, acc00);
    acc01 = mfma16(a0l, b1h, acc01);
    acc10 = mfma16(a1l, b0h, acc10);
    acc11 = mfma16(a1l, b1h, acc11);
  }
  int crow = (lane >> 4) << 2;
  int ccol = lane & 15;
  f32x4 accs[2][2] = {{acc00, acc01}, {acc10, acc11}};
#pragma unroll
  for (int i = 0; i < 2; ++i)
#pragma unroll
    for (int j = 0; j < 2; ++j) {
      int r0 = bm * 64 + wm + 16 * i + crow;
      int c0 = bn * 64 + wn + 16 * j + ccol;
#pragma unroll
      for (int rg = 0; rg < 4; ++rg) {
        float v = accs[i][j][rg] * alpha;
        if constexpr (BIAS) v += bias[c0];
        Cb[(size_t)(r0 + rg) * Nc + c0] = v;
      }
    }
}

// ---------------------------------------------------------------------------
// Split-precision NT GEMM, 128x128 tile, global_load_lds staging, XOR swizzle.
// ---------------------------------------------------------------------------
__global__ __launch_bounds__(256) void gemm3_big(
    const h16* __restrict__ Ah, const h16* __restrict__ Al,
    const h16* __restrict__ Bh, const h16* __restrict__ Bl,
    float* __restrict__ C, float alpha, int M, int Nc, int Kd) {
  __shared__ h16 sAh[128 * 32], sAl[128 * 32], sBh[128 * 32], sBl[128 * 32];
  int tid = threadIdx.x, wid = tid >> 6, lane = tid & 63;
  int bm = blockIdx.y, bn = blockIdx.x;
  int srow = 32 * wid + (lane >> 2);
  int scnk = lane & 3;
  int fr = lane & 15, fcc = lane >> 4;
  f32x4 acc[4][4] = {};
  const h16* gA[2] = {Ah, Al};
  const h16* gB[2] = {Bh, Bl};
  h16* sA[2] = {sAh, sAl};
  h16* sB[2] = {sBh, sBl};
  int wm = (wid & 1) * 64, wn = (wid >> 1) * 64;
  for (int k0 = 0; k0 < Kd; k0 += 32) {
    __syncthreads();
#pragma unroll
    for (int h = 0; h < 2; ++h) {
      int r = srow + 16 * h;
      int cs = scnk ^ ((r >> 1) & 3);
      size_t goffA = (size_t)(bm * 128 + r) * Kd + k0 + cs * 8;
      size_t goffB = (size_t)(bn * 128 + r) * Kd + k0 + cs * 8;
      int loff = (32 * wid + 16 * h) * 32;
#pragma unroll
      for (int p = 0; p < 2; ++p) {
        gl_lds16(gA[p] + goffA, sA[p] + loff);
        gl_lds16(gB[p] + goffB, sB[p] + loff);
      }
    }
    __syncthreads();
    h16x8 fa[2][4], fb[2][4];
#pragma unroll
    for (int i = 0; i < 4; ++i) {
      int ra = wm + 16 * i + fr;
      int ca = (fcc ^ ((ra >> 1) & 3)) * 8;
      fa[0][i] = *(const h16x8*)(sAh + ra * 32 + ca);
      fa[1][i] = *(const h16x8*)(sAl + ra * 32 + ca);
      int rb = wn + 16 * i + fr;
      int cb = (fcc ^ ((rb >> 1) & 3)) * 8;
      fb[0][i] = *(const h16x8*)(sBh + rb * 32 + cb);
      fb[1][i] = *(const h16x8*)(sBl + rb * 32 + cb);
    }
#pragma unroll
    for (int i = 0; i < 4; ++i)
#pragma unroll
      for (int j = 0; j < 4; ++j) {
        acc[i][j] = mfma16(fa[0][i], fb[0][j], acc[i][j]);
        acc[i][j] = mfma16(fa[0][i], fb[1][j], acc[i][j]);
        acc[i][j] = mfma16(fa[1][i], fb[0][j], acc[i][j]);
      }
  }
  int crow = (lane >> 4) << 2, ccol = lane & 15;
#pragma unroll
  for (int i = 0; i < 4; ++i)
#pragma unroll
    for (int j = 0; j < 4; ++j) {
      int r0 = bm * 128 + wm + 16 * i + crow;
      int c0 = bn * 128 + wn + 16 * j + ccol;
#pragma unroll
      for (int rg = 0; rg < 4; ++rg)
        C[(size_t)(r0 + rg) * Nc + c0] = acc[i][j][rg] * alpha;
    }
}

// ---------------------------------------------------------------------------
// Plain fp16 NT GEMM, 128x128 tile, K-SPLIT over blockIdx.z (Kc per slice).
// Writes f32 partials: Cpart[z][4096][256]. M=4096, Nc=256 fixed.
// ---------------------------------------------------------------------------
__global__ __launch_bounds__(256) void gemm_ks(
    const h16* __restrict__ A, const h16* __restrict__ B,
    float* __restrict__ Cpart, int Kd, int Kc) {
  __shared__ h16 sA[128 * 32], sB[128 * 32];
  int tid = threadIdx.x, wid = tid >> 6, lane = tid & 63;
  int bm = blockIdx.y, bn = blockIdx.x, kz = blockIdx.z;
  int kbase = kz * Kc;
  int srow = 32 * wid + (lane >> 2);
  int scnk = lane & 3;
  int fr = lane & 15, fcc = lane >> 4;
  f32x4 acc[4][4] = {};
  int wm = (wid & 1) * 64, wn = (wid >> 1) * 64;
  for (int k0 = 0; k0 < Kc; k0 += 32) {
    __syncthreads();
#pragma unroll
    for (int h = 0; h < 2; ++h) {
      int r = srow + 16 * h;
      int cs = scnk ^ ((r >> 1) & 3);
      size_t goffA = (size_t)(bm * 128 + r) * Kd + kbase + k0 + cs * 8;
      size_t goffB = (size_t)(bn * 128 + r) * Kd + kbase + k0 + cs * 8;
      int loff = (32 * wid + 16 * h) * 32;
      gl_lds16(A + goffA, sA + loff);
      gl_lds16(B + goffB, sB + loff);
    }
    __syncthreads();
    h16x8 fa[4], fb[4];
#pragma unroll
    for (int i = 0; i < 4; ++i) {
      int ra = wm + 16 * i + fr;
      int ca = (fcc ^ ((ra >> 1) & 3)) * 8;
      fa[i] = *(const h16x8*)(sA + ra * 32 + ca);
      int rb = wn + 16 * i + fr;
      int cb = (fcc ^ ((rb >> 1) & 3)) * 8;
      fb[i] = *(const h16x8*)(sB + rb * 32 + cb);
    }
#pragma unroll
    for (int i = 0; i < 4; ++i)
#pragma unroll
      for (int j = 0; j < 4; ++j)
        acc[i][j] = mfma16(fa[i], fb[j], acc[i][j]);
  }
  float* Cp = Cpart + (size_t)kz * 4096 * 256;
  int crow = (lane >> 4) << 2, ccol = lane & 15;
#pragma unroll
  for (int i = 0; i < 4; ++i)
#pragma unroll
    for (int j = 0; j < 4; ++j) {
      int r0 = bm * 128 + wm + 16 * i + crow;
      int c0 = bn * 128 + wn + 16 * j + ccol;
#pragma unroll
      for (int rg = 0; rg < 4; ++rg)
        Cp[(size_t)(r0 + rg) * 256 + c0] = acc[i][j][rg];
    }
}

// Zk += (*scptr) * rowSinv[row] * sum_z Cpart[z]
__global__ __launch_bounds__(256) void ks_reduce(
    const float* __restrict__ Cpart, const float* __restrict__ scptr,
    const float* __restrict__ rowSinv, float* __restrict__ Zk) {
  int i = (blockIdx.x * 256 + threadIdx.x) * 4;  // grid 1024
  float4 s = {0.f, 0.f, 0.f, 0.f};
#pragma unroll
  for (int z = 0; z < 8; ++z) {
    float4 p = *(const float4*)(Cpart + (size_t)z * 4096 * 256 + i);
    s.x += p.x; s.y += p.y; s.z += p.z; s.w += p.w;
  }
  float sc = (*scptr) * rowSinv[i >> 8];
  float4 zk = *(float4*)(Zk + i);
  zk.x += sc * s.x; zk.y += sc * s.y; zk.z += sc * s.z; zk.w += sc * s.w;
  *(float4*)(Zk + i) = zk;
}

// 16-bit transpose
__global__ __launch_bounds__(256) void transpose16(
    const u16* __restrict__ in, u16* __restrict__ out, int rows, int cols) {
  __shared__ u16 t[32][33];
  const u16* ib = in + (size_t)blockIdx.z * rows * cols;
  u16* ob = out + (size_t)blockIdx.z * rows * cols;
  int r0 = blockIdx.x * 32, c0 = blockIdx.y * 32;
  int tx = threadIdx.x & 31, ty = threadIdx.x >> 5;
#pragma unroll
  for (int i = 0; i < 32; i += 8)
    t[ty + i][tx] = ib[(size_t)(r0 + ty + i) * cols + c0 + tx];
  __syncthreads();
#pragma unroll
  for (int i = 0; i < 32; i += 8)
    ob[(size_t)(c0 + ty + i) * rows + r0 + tx] = t[tx][ty + i];
}

// scalars: w=softmax(alpha)->scal[0..3], rho=sigmoid(rho_raw)->scal[4]
__global__ void prep_scalars(const void* __restrict__ alpha,
                             const void* __restrict__ rho_raw,
                             float* __restrict__ scal,
                             const int* __restrict__ flag) {
  if (threadIdx.x == 0) {
    int f = *flag;
    float a[4], e[4], m = -1e30f, s = 0.f;
    for (int i = 0; i < 4; ++i) {
      a[i] = f ? ((const float*)alpha)[i] : b2f(((const u16*)alpha)[i]);
      m = fmaxf(m, a[i]);
    }
    for (int i = 0; i < 4; ++i) { e[i] = expf(a[i] - m); s += e[i]; }
    for (int i = 0; i < 4; ++i) scal[i] = e[i] / s;
    float rr = f ? ((const float*)rho_raw)[0] : b2f(((const u16*)rho_raw)[0]);
    scal[4] = 1.f / (1.f + expf(-rr));
  }
}

// ---------------------------------------------------------------------------
// fused per-row (one wave per row): max -> threshold T -> exp/E-write +
// candidate push -> exact jax-tiebreak top-16 from candidates
// ---------------------------------------------------------------------------
__global__ __launch_bounds__(256) void row_softmax_topk(
    const float* __restrict__ A, float* __restrict__ topv,
    int* __restrict__ topi, h16* __restrict__ E, float* __restrict__ rowSinv,
    int khead) {
  __shared__ u64 candK[4][256];
  __shared__ int candN[4];
  int wid = threadIdx.x >> 6, lane = threadIdx.x & 63;
  int row = blockIdx.x * 4 + wid;
  const float* arow = A + ((size_t)row << 12);
  if (lane == 0) candN[wid] = 0;
  __syncthreads();
  float lm = -INFINITY;
#pragma unroll
  for (int t = 0; t < 16; ++t) {
    float4 v = *(const float4*)(arow + (t << 8) + (lane << 2));
    lm = fmaxf(lm, fmaxf(fmaxf(v.x, v.y), fmaxf(v.z, v.w)));
  }
  float m = lm;
#pragma unroll
  for (int off = 32; off; off >>= 1) m = fmaxf(m, __shfl_xor(m, off));
  u64 lk = ((u64)fkey(lm) << 32) | (unsigned)lane;
  float T = 0.f;
  for (int r = 0; r < 16; ++r) {
    u64 k2 = wave_max_u64(lk);
    if (lk == k2) lk = 0;
    if (r == 15) T = unfkey((unsigned)(k2 >> 32));
  }
  h16* erow = E + ((size_t)row << 12);
  int* cn = &candN[wid];
  u64* ck = candK[wid];
  float s = 0.f;
  for (int t = 0; t < 16; ++t) {
    int c = (t << 8) + (lane << 2);
    float4 v = *(const float4*)(arow + c);
    float e0 = __expf(v.x - m), e1 = __expf(v.y - m);
    float e2 = __expf(v.z - m), e3 = __expf(v.w - m);
    s += (e0 + e1) + (e2 + e3);
    h16x4 hv = {(h16)e0, (h16)e1, (h16)e2, (h16)e3};
    *(h16x4*)(erow + c) = hv;
    if (v.x >= T) {
      int sl = atomicAdd(cn, 1);
      if (sl < 256) ck[sl] = ((u64)fkey(v.x) << 32) | (unsigned)(~(unsigned)c);
    }
    if (v.y >= T) {
      int sl = atomicAdd(cn, 1);
      if (sl < 256) ck[sl] = ((u64)fkey(v.y) << 32) | (unsigned)(~(unsigned)(c + 1));
    }
    if (v.z >= T) {
      int sl = atomicAdd(cn, 1);
      if (sl < 256) ck[sl] = ((u64)fkey(v.z) << 32) | (unsigned)(~(unsigned)(c + 2));
    }
    if (v.w >= T) {
      int sl = atomicAdd(cn, 1);
      if (sl < 256) ck[sl] = ((u64)fkey(v.w) << 32) | (unsigned)(~(unsigned)(c + 3));
    }
  }
#pragma unroll
  for (int off = 32; off; off >>= 1) s += __shfl_xor(s, off);
  if (lane == 0) rowSinv[row] = 1.f / s;
  __syncthreads();
  int cnt = min(*cn, 256);
  u64 loc[4] = {0ull, 0ull, 0ull, 0ull};
  int nl = 0;
  for (int j = lane; j < cnt; j += 64)
    if (nl < 4) loc[nl++] = ck[j];
#define CSW(a, b)                     \
  {                                   \
    if (loc[b] > loc[a]) {            \
      u64 tt = loc[a];                \
      loc[a] = loc[b];                \
      loc[b] = tt;                    \
    }                                 \
  }
  CSW(0, 1) CSW(2, 3) CSW(0, 2) CSW(1, 3) CSW(1, 2)
#undef CSW
  float myv = 0.f;
  int myi = 0;
  float sum16 = 0.f;
  for (int r = 0; r < 16; ++r) {
    u64 key = loc[0];
    u64 k2 = wave_max_u64(key);
    float wv = unfkey((unsigned)(k2 >> 32));
    int wi = (int)(~(unsigned)(k2 & 0xffffffffu));
    if (key == k2 && key != 0ull) {
      loc[0] = loc[1];
      loc[1] = loc[2];
      loc[2] = loc[3];
      loc[3] = 0ull;
    }
    sum16 += expf(wv - m);
    if (r == lane) { myv = wv; myi = wi; }
  }
  if (lane < 16) {
    size_t o = (((size_t)khead << 12) + row) * 16 + lane;
    topv[o] = expf(myv - m) / (sum16 + 1e-9f * s);
    topi[o] = myi;
  }
}

// ---------------------------------------------------------------------------
// sparse hypergraph: S_norm = C C^T — entry-parallel build
// ---------------------------------------------------------------------------
// one thread per (e,p) entry: Dv/cnt histogram
__global__ __launch_bounds__(256) void edge_prep2(
    const float* __restrict__ topv, const int* __restrict__ topi,
    float* __restrict__ Dv, int* __restrict__ cnt) {
  int t = blockIdx.x * 256 + threadIdx.x;  // grid 1024 -> 262144
  float v = topv[t];
  int i = topi[t];
  atomicAdd(&Dv[i], v);
  atomicAdd(&cnt[i], 1);
}

// per-edge DeIS via 4 independent float4 loads
__global__ __launch_bounds__(256) void edge_deis(
    const float* __restrict__ topv, float* __restrict__ DeIS) {
  int e = blockIdx.x * 256 + threadIdx.x;  // grid 64
  const float4* p = (const float4*)(topv + ((size_t)e << 4));
  float4 a = p[0], b = p[1], c = p[2], d = p[3];
  float s = ((a.x + a.y) + (a.z + a.w)) + ((b.x + b.y) + (b.z + b.w)) +
            ((c.x + c.y) + (c.z + c.w)) + ((d.x + d.y) + (d.z + d.w));
  DeIS[e] = 1.0f / sqrtf(s + 1e-9f);
}

__global__ void dv_isqrt(const float* __restrict__ Dv, float* __restrict__ Dvis) {
  int i = blockIdx.x * 256 + threadIdx.x;
  Dvis[i] = sqrtf(1.0f / (Dv[i] + 1e-9f));
}

// exclusive scan of cnt[4096] -> rowptr[4097], cur=rowptr
__global__ __launch_bounds__(256) void scan_rowptr(const int* __restrict__ cnt,
                                                   int* __restrict__ rowptr,
                                                   int* __restrict__ cur) {
  __shared__ int part[256];
  int tid = threadIdx.x;
  int base = tid * 16;
  int loc[16];
  int s = 0;
#pragma unroll
  for (int j = 0; j < 16; ++j) { loc[j] = s; s += cnt[base + j]; }
  part[tid] = s;
  __syncthreads();
  for (int off = 1; off < 256; off <<= 1) {
    int v = (tid >= off) ? part[tid - off] : 0;
    __syncthreads();
    part[tid] += v;
    __syncthreads();
  }
  int pre = (tid == 0) ? 0 : part[tid - 1];
#pragma unroll
  for (int j = 0; j < 16; ++j) {
    int r = pre + loc[j];
    rowptr[base + j] = r;
    cur[base + j] = r;
  }
  if (tid == 255) rowptr[4096] = part[255];
}

// one thread per (e,p): fill cvals + CSR-transpose slots
__global__ __launch_bounds__(256) void csr_fill2(
    const float* __restrict__ topv, const int* __restrict__ topi,
    const float* __restrict__ Dvis, const float* __restrict__ DeIS,
    int* __restrict__ cur, float* __restrict__ cvals, int* __restrict__ colE,
    float* __restrict__ cvalR) {
  int t = blockIdx.x * 256 + threadIdx.x;  // grid 1024 -> 262144
  int e = t >> 4;
  int i = topi[t];
  float c = Dvis[i] * topv[t] * DeIS[e];
  cvals[t] = c;
  int slot = atomicAdd(&cur[i], 1);
  colE[slot] = e;
  cvalR[slot] = c;
}

// g[e] = sum_p c[e,p] * v[idx[e,p]]
__global__ __launch_bounds__(256) void spmv_edge(
    const float* __restrict__ cvals, const int* __restrict__ topi,
    const float* __restrict__ v, float* __restrict__ g) {
  int e = blockIdx.x * 256 + threadIdx.x;  // grid 64
  float acc = 0.f;
#pragma unroll
  for (int p = 0; p < 16; ++p)
    acc += cvals[e * 16 + p] * v[topi[e * 16 + p]];
  g[e] = acc;
}

// vout[i] = vin[i] - sum_{j in row i} cvalR[j]*g[colE[j]]
__global__ __launch_bounds__(256) void spmv_row(
    const int* __restrict__ rowptr, const int* __restrict__ colE,
    const float* __restrict__ cvalR, const float* __restrict__ g,
    const float* __restrict__ vin, float* __restrict__ vout) {
  int wid = threadIdx.x >> 6, lane = threadIdx.x & 63;
  int row = blockIdx.x * 4 + wid;  // grid 1024
  int s = rowptr[row], e = rowptr[row + 1];
  float acc = 0.f;
  for (int j = s + lane; j < e; j += 64) acc += cvalR[j] * g[colE[j]];
#pragma unroll
  for (int off = 32; off; off >>= 1) acc += __shfl_xor(acc, off);
  if (lane == 0) vout[row] = vin[row] - acc;
}

// G[e,:] = sum_p c[e,p] * M[idx[e,p],:]  — MLP-unrolled (16 gathers in flight)
__global__ __launch_bounds__(256) void spmm_edge(
    const float* __restrict__ cvals, const int* __restrict__ topi,
    const float* __restrict__ M, float* __restrict__ G) {
  int wid = threadIdx.x >> 6, lane = threadIdx.x & 63;
  int e = blockIdx.x * 4 + wid;  // grid 4096
  int cb = lane << 2;
  const float* cv = cvals + ((size_t)e << 4);
  const int* ti = topi + ((size_t)e << 4);
  float cc[16];
  int ix[16];
#pragma unroll
  for (int p = 0; p < 16; ++p) { cc[p] = cv[p]; ix[p] = ti[p]; }
  float4 acc[4] = {};
#pragma unroll
  for (int h = 0; h < 2; ++h) {
    float4 g[8];
#pragma unroll
    for (int p = 0; p < 8; ++p)
      g[p] = *(const float4*)(M + ((size_t)ix[h * 8 + p] << 8) + cb);
#pragma unroll
    for (int p = 0; p < 8; ++p) {
      float c = cc[h * 8 + p];
      float4 gg = g[p];
      int a = p & 3;
      acc[a].x += c * gg.x; acc[a].y += c * gg.y;
      acc[a].z += c * gg.z; acc[a].w += c * gg.w;
    }
  }
  float4 r;
  r.x = (acc[0].x + acc[1].x) + (acc[2].x + acc[3].x);
  r.y = (acc[0].y + acc[1].y) + (acc[2].y + acc[3].y);
  r.z = (acc[0].z + acc[1].z) + (acc[2].z + acc[3].z);
  r.w = (acc[0].w + acc[1].w) + (acc[2].w + acc[3].w);
  *(float4*)(G + ((size_t)e << 8) + cb) = r;
}

// Z[i,:] = sum_{j in row i} cvalR[j] * G[colE[j],:]  — 8-wide MLP unroll
__global__ __launch_bounds__(256) void spmm_row(
    const int* __restrict__ rowptr, const int* __restrict__ colE,
    const float* __restrict__ cvalR, const float* __restrict__ G,
    float* __restrict__ Z) {
  int wid = threadIdx.x >> 6, lane = threadIdx.x & 63;
  int row = blockIdx.x * 4 + wid;  // grid 1024
  int cb = lane << 2;
  int s = rowptr[row], e = rowptr[row + 1];
  float4 acc[4] = {};
  int j = s;
  for (; j + 8 <= e; j += 8) {
    int ix[8];
    float cc[8];
#pragma unroll
    for (int t = 0; t < 8; ++t) { ix[t] = colE[j + t]; cc[t] = cvalR[j + t]; }
    float4 g[8];
#pragma unroll
    for (int t = 0; t < 8; ++t)
      g[t] = *(const float4*)(G + ((size_t)ix[t] << 8) + cb);
#pragma unroll
    for (int t = 0; t < 8; ++t) {
      float c = cc[t];
      float4 gg = g[t];
      int a = t & 3;
      acc[a].x += c * gg.x; acc[a].y += c * gg.y;
      acc[a].z += c * gg.z; acc[a].w += c * gg.w;
    }
  }
  for (; j < e; ++j) {
    float c = cvalR[j];
    float4 gg = *(const float4*)(G + ((size_t)colE[j] << 8) + cb);
    acc[0].x += c * gg.x; acc[0].y += c * gg.y;
    acc[0].z += c * gg.z; acc[0].w += c * gg.w;
  }
  float4 r;
  r.x = (acc[0].x + acc[1].x) + (acc[2].x + acc[3].x);
  r.y = (acc[0].y + acc[1].y) + (acc[2].y + acc[3].y);
  r.z = (acc[0].z + acc[1].z) + (acc[2].z + acc[3].z);
  r.w = (acc[0].w + acc[1].w) + (acc[2].w + acc[3].w);
  *(float4*)(Z + ((size_t)row << 8) + cb) = r;
}

// v0: bit-exact jax.random.normal(key(1), (4096,1), f32)
__global__ __launch_bounds__(256) void init_v0(float* __restrict__ v) {
  int tid = blockIdx.x * 256 + threadIdx.x;
  unsigned j = (unsigned)(tid & 2047);
  unsigned x0 = j, x1 = j + 2048u;
  const unsigned ks0 = 0u, ks1 = 1u, ks2 = 0x1BD11BDAu;
  x0 += ks0; x1 += ks1;
#define TF_R(r)                                  \
  {                                              \
    x0 += x1;                                    \
    x1 = (x1 << (r)) | (x1 >> (32 - (r)));       \
    x1 ^= x0;                                    \
  }
  TF_R(13) TF_R(15) TF_R(26) TF_R(6)  x0 += ks1; x1 += ks2 + 1u;
  TF_R(17) TF_R(29) TF_R(16) TF_R(24) x0 += ks2; x1 += ks0 + 2u;
  TF_R(13) TF_R(15) TF_R(26) TF_R(6)  x0 += ks0; x1 += ks1 + 3u;
  TF_R(17) TF_R(29) TF_R(16) TF_R(24) x0 += ks1; x1 += ks2 + 4u;
  TF_R(13) TF_R(15) TF_R(26) TF_R(6)  x0 += ks2; x1 += ks0 + 5u;
#undef TF_R
  unsigned bits = (tid < 2048) ? x0 : x1;
  float u01 = __uint_as_float((bits >> 9) | 0x3f800000u) - 1.0f;
  const float lo = -0.99999994f;
  float u = fmaxf(lo, u01 * 2.0f + lo);
  float w = -log1pf(-u * u);
  float p;
  if (w < 5.0f) {
    float t = w - 2.5f;
    p = 2.81022636e-08f;
    p = 3.43273939e-07f + p * t;
    p = -3.5233877e-06f + p * t;
    p = -4.39150654e-06f + p * t;
    p = 0.00021858087f + p * t;
    p = -0.00125372503f + p * t;
    p = -0.00417768164f + p * t;
    p = 0.246640727f + p * t;
    p = 1.50140941f + p * t;
  } else {
    float t = sqrtf(w) - 3.0f;
    p = -0.000200214257f;
    p = 0.000100950558f + p * t;
    p = 0.00134934322f + p * t;
    p = -0.00367342844f + p * t;
    p = 0.00573950773f + p * t;
    p = -0.0076224613f + p * t;
    p = 0.00943887047f + p * t;
    p = 1.00167406f + p * t;
    p = 2.83297682f + p * t;
  }
  v[tid] = 1.41421354f * (p * u);
}

// lam = clip((w5.w6)/(w5.w5), 1e-3) -> scal[5]
__global__ __launch_bounds__(256) void pi_dots(const float* __restrict__ w5,
                                               const float* __restrict__ w6,
                                               float* __restrict__ scal) {
  __shared__ float r1[256], r2[256];
  int tid = threadIdx.x;
  float a = 0.f, b = 0.f;
  for (int i = tid; i < 4096; i += 256) {
    float x = w5[i];
    a += x * x;
    b += x * w6[i];
  }
  r1[tid] = a; r2[tid] = b;
  __syncthreads();
  for (int off = 128; off; off >>= 1) {
    if (tid < off) { r1[tid] += r1[tid + off]; r2[tid] += r2[tid + off]; }
    __syncthreads();
  }
  if (tid == 0) scal[5] = fmaxf(r2[0] / r1[0], 1e-3f);
}

// T1 = (c1-1)X - c1*SnX
__global__ __launch_bounds__(256) void t1_simple(
    const float* __restrict__ SnX, const float* __restrict__ Xf,
    const float* __restrict__ scal, float* __restrict__ T1) {
  int i = blockIdx.x * 256 + threadIdx.x;  // grid 4096
  float c1 = 2.0f / scal[5];
  T1[i] = (c1 - 1.0f) * Xf[i] - c1 * SnX[i];
}

// T2, cheb combine, elu, mix -> Zmix split hi/lo fp16
__global__ __launch_bounds__(256) void combine_kernel(
    const float* __restrict__ Xf, const float* __restrict__ T1,
    const float* __restrict__ SnT1, const float* __restrict__ Zk,
    const float* __restrict__ thetaf, const float* __restrict__ scal,
    h16* __restrict__ Zmh, h16* __restrict__ Zml) {
  int idx = blockIdx.x * 256 + threadIdx.x;  // grid 4096
  int d = idx & 255;
  float c1 = 2.0f / scal[5];
  float rho = scal[4];
  float x = Xf[idx];
  float t1 = T1[idx];
  float t2 = 2.0f * ((c1 - 1.0f) * t1 - c1 * SnT1[idx]) - x;
  float o = x * thetaf[d] + t1 * thetaf[256 + d] + t2 * thetaf[512 + d];
  float zs = o > 0.0f ? o : expm1f(o);
  float zm = rho * zs + (1.0f - rho) * Zk[idx];
  h16 h = (h16)zm;
  Zmh[idx] = h;
  Zml[idx] = (h16)(zm - (float)h);
}

// ---------------------------------------------------------------------------
extern "C" void kernel_launch(void* const* d_in, const int* in_sizes, int n_in,
                              void* d_out, int out_size, void* d_ws,
                              size_t ws_size, hipStream_t stream) {
  (void)in_sizes; (void)n_in; (void)out_size;
  const void* Xin = d_in[0];
  const void* Lin = d_in[1];
  const void* alpha = d_in[2];
  const void* theta = d_in[3];
  const void* rho_raw = d_in[4];
  const void* Wpin = d_in[5];
  const void* bpin = d_in[6];
  float* out = (float*)d_out;

  char* base = (char*)d_ws;
  size_t off = 0;
  auto alloc = [&](size_t bytes) -> char* {
    char* p = base + off;
    off += (bytes + 255) & ~(size_t)255;
    return p;
  };
  float* Abuf = (float*)alloc((size_t)4096 * 4096 * 4);  // A; ks-partials; G
  h16* Ebuf = (h16*)alloc((size_t)4096 * 4096 * 2);      // Yf alias; E per head
  h16* Yhi = (h16*)alloc((size_t)4 * 4096 * 256 * 2);
  h16* Ylo = (h16*)alloc((size_t)4 * 4096 * 256 * 2);
  h16* Xhi = (h16*)alloc((size_t)4096 * 256 * 2);
  h16* Xlo = (h16*)alloc((size_t)4096 * 256 * 2);
  float* Xf = (float*)alloc((size_t)4096 * 256 * 4);
  h16* XT = (h16*)alloc((size_t)256 * 4096 * 2);
  h16* Lhi = (h16*)alloc((size_t)4 * 256 * 256 * 2);
  h16* Llo = (h16*)alloc((size_t)4 * 256 * 256 * 2);
  h16* LThi = (h16*)alloc((size_t)4 * 256 * 256 * 2);
  h16* LTlo = (h16*)alloc((size_t)4 * 256 * 256 * 2);
  h16* Whi = (h16*)alloc((size_t)256 * 256 * 2);
  h16* Wlo = (h16*)alloc((size_t)256 * 256 * 2);
  float* Zk = (float*)alloc((size_t)4096 * 256 * 4);
  float* SnX = (float*)alloc((size_t)4096 * 256 * 4);  // then SnT1
  float* T1 = (float*)alloc((size_t)4096 * 256 * 4);
  h16* Zmh = (h16*)alloc((size_t)4096 * 256 * 2);
  h16* Zml = (h16*)alloc((size_t)4096 * 256 * 2);
  float* topv = (float*)alloc((size_t)4 * 4096 * 16 * 4);
  int* topi = (int*)alloc((size_t)4 * 4096 * 16 * 4);
  float* cvals = (float*)alloc((size_t)262144 * 4);
  int* colE = (int*)alloc((size_t)262144 * 4);
  float* cvalR = (float*)alloc((size_t)262144 * 4);
  int* rowptr = (int*)alloc(4097 * 4);
  int* cur = (int*)alloc(4096 * 4);
  int* cnt = (int*)alloc(4096 * 4);
  float* Dv = (float*)alloc(4096 * 4);
  float* Dvis = (float*)alloc(4096 * 4);
  float* DeIS = (float*)alloc(16384 * 4);
  float* gE = (float*)alloc(16384 * 4);
  float* wA = (float*)alloc(4096 * 4);
  float* wB = (float*)alloc(4096 * 4);
  float* rowSinv = (float*)alloc(4096 * 4);
  float* thetaf = (float*)alloc(768 * 4);
  float* biasf = (float*)alloc(256 * 4);
  float* scal = (float*)alloc(256);
  int* flag = (int*)alloc(256);
  if (off > ws_size) return;
  float* Yf = (float*)Ebuf;  // 16 MB alias; dead before E written
  float* G = (float*)Abuf;   // 16 MB alias; dead after last head's softmax
  float* Kpart = Abuf;       // 32 MB alias; A dead after row_softmax reads it

  detect_dtype<<<1, 256, 0, stream>>>((const u16*)Xin, flag);
  split_input3<<<1024, 256, 0, stream>>>(Xin, Xhi, Xlo, Xf, 4096 * 256, flag);
  split_input3<<<256, 256, 0, stream>>>(Lin, Lhi, Llo, nullptr, 4 * 256 * 256,
                                        flag);
  split_input3<<<64, 256, 0, stream>>>(Wpin, Whi, Wlo, nullptr, 256 * 256, flag);
  conv_f32<<<1, 256, 0, stream>>>(theta, thetaf, 768, flag);
  conv_f32<<<1, 256, 0, stream>>>(bpin, biasf, 256, flag);
  prep_scalars<<<1, 64, 0, stream>>>(alpha, rho_raw, scal, flag);
  transpose16<<<dim3(128, 8, 1), 256, 0, stream>>>((const u16*)Xhi, (u16*)XT,
                                                   4096, 256);
  transpose16<<<dim3(8, 8, 4), 256, 0, stream>>>((const u16*)Lhi, (u16*)LThi,
                                                 256, 256);
  transpose16<<<dim3(8, 8, 4), 256, 0, stream>>>((const u16*)Llo, (u16*)LTlo,
                                                 256, 256);
  // Yf = X @ L_k (split fp16, fused), batched z=4
  gemm3_nt<false><<<dim3(4, 64, 4), 256, 0, stream>>>(
      Xhi, Xlo, LThi, LTlo, Yf, nullptr, 1.0f, 4096, 256, 256,
      0L, 256L * 256L, 4096L * 256L);
  split_f32h<<<2048, 256, 0, stream>>>(Yf, Yhi, Ylo, 4 * 4096 * 256);
  hipMemsetAsync(Zk, 0, (size_t)4096 * 256 * 4, stream);
  for (int k = 0; k < 4; ++k) {
    // A = Y_k @ X^T / 16 (split fp16, 128x128 tile, global_load_lds)
    gemm3_big<<<dim3(32, 32), 256, 0, stream>>>(
        Yhi + (size_t)k * 4096 * 256, Ylo + (size_t)k * 4096 * 256, Xhi, Xlo,
        Abuf, 0.0625f, 4096, 4096, 256);
    row_softmax_topk<<<1024, 256, 0, stream>>>(Abuf, topv, topi, Ebuf, rowSinv,
                                               k);
    // E @ X via K-split MFMA into 8 f32 partials (A is dead; reuse Abuf)
    gemm_ks<<<dim3(2, 32, 8), 256, 0, stream>>>(Ebuf, XT, Kpart, 4096, 512);
    // Zk += w_k * invS[row] * sum_z partial[z]
    ks_reduce<<<1024, 256, 0, stream>>>(Kpart, scal + k, rowSinv, Zk);
  }
  // sparse hypergraph Laplacian (no dense S) — entry-parallel build
  hipMemsetAsync(Dv, 0, 4096 * 4, stream);
  hipMemsetAsync(cnt, 0, 4096 * 4, stream);
  edge_prep2<<<1024, 256, 0, stream>>>(topv, topi, Dv, cnt);
  edge_deis<<<64, 256, 0, stream>>>(topv, DeIS);
  dv_isqrt<<<16, 256, 0, stream>>>(Dv, Dvis);
  scan_rowptr<<<1, 256, 0, stream>>>(cnt, rowptr, cur);
  csr_fill2<<<1024, 256, 0, stream>>>(topv, topi, Dvis, DeIS, cur, cvals, colE,
                                      cvalR);
  init_v0<<<16, 256, 0, stream>>>(wA);
  for (int it = 0; it < 6; ++it) {
    const float* vi = (it & 1) ? wB : wA;
    float* vo = (it & 1) ? wA : wB;
    spmv_edge<<<64, 256, 0, stream>>>(cvals, topi, vi, gE);
    spmv_row<<<1024, 256, 0, stream>>>(rowptr, colE, cvalR, gE, vi, vo);
  }
  pi_dots<<<1, 256, 0, stream>>>(wB, wA, scal);
  // SnX = S_norm @ X (sparse, f32-exact)
  spmm_edge<<<4096, 256, 0, stream>>>(cvals, topi, Xf, G);
  spmm_row<<<1024, 256, 0, stream>>>(rowptr, colE, cvalR, G, SnX);
  t1_simple<<<4096, 256, 0, stream>>>(SnX, Xf, scal, T1);
  // SnT1 = S_norm @ T1 (overwrite SnX)
  spmm_edge<<<4096, 256, 0, stream>>>(cvals, topi, T1, G);
  spmm_row<<<1024, 256, 0, stream>>>(rowptr, colE, cvalR, G, SnX);
  combine_kernel<<<4096, 256, 0, stream>>>(Xf, T1, SnX, Zk, thetaf, scal, Zmh,
                                           Zml);
  // out = Zmix @ proj_w^T + proj_b (split fp16, f32 out)
  gemm3_nt<true><<<dim3(4, 64, 1), 256, 0, stream>>>(
      Zmh, Zml, Whi, Wlo, out, biasf, 1.0f, 4096, 256, 256, 0L, 0L, 0L);
}

// Round 9
// 717.863 us; speedup vs baseline: 1.7889x; 1.0602x over previous
//
#include <hip/hip_runtime.h>

typedef unsigned short u16;
typedef unsigned long long u64;
typedef _Float16 h16;
typedef __attribute__((ext_vector_type(8))) _Float16 h16x8;
typedef __attribute__((ext_vector_type(4))) _Float16 h16x4;
typedef __attribute__((ext_vector_type(4))) float f32x4;

__device__ __forceinline__ float b2f(u16 u) {
  unsigned x = ((unsigned)u) << 16;
  return __uint_as_float(x);
}
__device__ __forceinline__ unsigned fkey(float f) {
  unsigned b = __float_as_uint(f);
  return (b & 0x80000000u) ? ~b : (b | 0x80000000u);
}
__device__ __forceinline__ float unfkey(unsigned u) {
  unsigned b = (u & 0x80000000u) ? (u ^ 0x80000000u) : ~u;
  return __uint_as_float(b);
}
__device__ __forceinline__ f32x4 mfma16(h16x8 a, h16x8 b, f32x4 c) {
  return __builtin_amdgcn_mfma_f32_16x16x32_f16(a, b, c, 0, 0, 0);
}
__device__ __forceinline__ void gl_lds16(const void* g, void* l) {
  __builtin_amdgcn_global_load_lds(
      (const __attribute__((address_space(1))) unsigned*)g,
      (__attribute__((address_space(3))) unsigned*)l, 16, 0, 0);
}
__device__ __forceinline__ u64 wave_max_u64(u64 k) {
#pragma unroll
  for (int off = 32; off; off >>= 1) {
    u64 o = __shfl_xor(k, off);
    if (o > k) k = o;
  }
  return k;
}

// dtype detector (insurance): flag=1 means inputs are f32 (expected)
__global__ void detect_dtype(const u16* __restrict__ X, int* __restrict__ flag) {
  __shared__ int cnt;
  if (threadIdx.x == 0) cnt = 0;
  __syncthreads();
  int sane = 0;
#pragma unroll
  for (int j = 0; j < 16; ++j) {
    u16 u = X[(threadIdx.x * 16 + j) * 2];
    int e = (u >> 7) & 0xff;
    if (u == 0 || (e >= 112 && e <= 142)) sane++;
  }
  atomicAdd(&cnt, sane);
  __syncthreads();
  if (threadIdx.x == 0) *flag = (cnt < 3072) ? 1 : 0;
}

// split input to hi/lo fp16 + optional f32 copy
__global__ __launch_bounds__(256) void split_input3(
    const void* __restrict__ in, h16* __restrict__ hi, h16* __restrict__ lo,
    float* __restrict__ f32out, int n, const int* __restrict__ flag) {
  int f = *flag;
  int stride = gridDim.x * 256;
  for (int i = blockIdx.x * 256 + threadIdx.x; i < n; i += stride) {
    float x = f ? ((const float*)in)[i] : b2f(((const u16*)in)[i]);
    h16 h = (h16)x;
    hi[i] = h;
    lo[i] = (h16)(x - (float)h);
    if (f32out) f32out[i] = x;
  }
}

// split f32 buffer to hi/lo fp16
__global__ __launch_bounds__(256) void split_f32h(
    const float* __restrict__ in, h16* __restrict__ hi, h16* __restrict__ lo,
    int n) {
  int stride = gridDim.x * 256;
  for (int i = blockIdx.x * 256 + threadIdx.x; i < n; i += stride) {
    float x = in[i];
    h16 h = (h16)x;
    hi[i] = h;
    lo[i] = (h16)(x - (float)h);
  }
}

// canonicalize to f32 (theta, proj_b)
__global__ __launch_bounds__(256) void conv_f32(const void* __restrict__ in,
                                                float* __restrict__ out, int n,
                                                const int* __restrict__ flag) {
  int f = *flag;
  int stride = gridDim.x * 256;
  for (int i = blockIdx.x * 256 + threadIdx.x; i < n; i += stride)
    out[i] = f ? ((const float*)in)[i] : b2f(((const u16*)in)[i]);
}

// ---------------------------------------------------------------------------
// Split-precision NT GEMM (64x64 tile): C = alpha*(Ah Bh^T + Ah Bl^T + Al Bh^T)
// ---------------------------------------------------------------------------
template <bool BIAS>
__global__ __launch_bounds__(256) void gemm3_nt(
    const h16* __restrict__ Ah, const h16* __restrict__ Al,
    const h16* __restrict__ Bh, const h16* __restrict__ Bl,
    float* __restrict__ C, const float* __restrict__ bias, float alpha,
    int M, int Nc, int Kd, long batchA, long batchB, long batchC) {
  const h16* Abh = Ah + (size_t)blockIdx.z * batchA;
  const h16* Abl = Al + (size_t)blockIdx.z * batchA;
  const h16* Bbh = Bh + (size_t)blockIdx.z * batchB;
  const h16* Bbl = Bl + (size_t)blockIdx.z * batchB;
  float* Cb = C + (size_t)blockIdx.z * batchC;
  int bn = blockIdx.x, bm = blockIdx.y;
  int tid = threadIdx.x;
  int wid = tid >> 6, lane = tid & 63;
  __shared__ h16 Ash[64 * 40], Asl[64 * 40], Bsh[64 * 40], Bsl[64 * 40];
  f32x4 acc00 = {}, acc01 = {}, acc10 = {}, acc11 = {};
  int lr = tid >> 2;
  int lc = (tid & 3) << 3;
  size_t aoff = (size_t)(bm * 64 + lr) * Kd + lc;
  size_t boff = (size_t)(bn * 64 + lr) * Kd + lc;
  int wm = (wid & 1) * 32, wn = (wid >> 1) * 32;
  int fr = lane & 15;
  int fc = (lane >> 4) << 3;
  for (int k0 = 0; k0 < Kd; k0 += 32) {
    uint4 avh = *(const uint4*)(Abh + aoff + k0);
    uint4 avl = *(const uint4*)(Abl + aoff + k0);
    uint4 bvh = *(const uint4*)(Bbh + boff + k0);
    uint4 bvl = *(const uint4*)(Bbl + boff + k0);
    __syncthreads();
    *(uint4*)(Ash + lr * 40 + lc) = avh;
    *(uint4*)(Asl + lr * 40 + lc) = avl;
    *(uint4*)(Bsh + lr * 40 + lc) = bvh;
    *(uint4*)(Bsl + lr * 40 + lc) = bvl;
    __syncthreads();
    h16x8 a0h = *(const h16x8*)(Ash + (wm + fr) * 40 + fc);
    h16x8 a1h = *(const h16x8*)(Ash + (wm + 16 + fr) * 40 + fc);
    h16x8 b0h = *(const h16x8*)(Bsh + (wn + fr) * 40 + fc);
    h16x8 b1h = *(const h16x8*)(Bsh + (wn + 16 + fr) * 40 + fc);
    h16x8 a0l = *(const h16x8*)(Asl + (wm + fr) * 40 + fc);
    h16x8 a1l = *(const h16x8*)(Asl + (wm + 16 + fr) * 40 + fc);
    h16x8 b0l = *(const h16x8*)(Bsl + (wn + fr) * 40 + fc);
    h16x8 b1l = *(const h16x8*)(Bsl + (wn + 16 + fr) * 40 + fc);
    acc00 = mfma16(a0h, b0h, acc00);
    acc01 = mfma16(a0h, b1h, acc01);
    acc10 = mfma16(a1h, b0h, acc10);
    acc11 = mfma16(a1h, b1h, acc11);
    acc00 = mfma16(a0h, b0l, acc00);
    acc01 = mfma16(a0h, b1l, acc01);
    acc10 = mfma16(a1h, b0l, acc10);
    acc11 = mfma16(a1h, b1l, acc11);
    acc00 = mfma16(a0l, b0h, acc00);
    acc01 = mfma16(a0l, b1h, acc01);
    acc10 = mfma16(a1l, b0h, acc10);
    acc11 = mfma16(a1l, b1h, acc11);
  }
  int crow = (lane >> 4) << 2;
  int ccol = lane & 15;
  f32x4 accs[2][2] = {{acc00, acc01}, {acc10, acc11}};
#pragma unroll
  for (int i = 0; i < 2; ++i)
#pragma unroll
    for (int j = 0; j < 2; ++j) {
      int r0 = bm * 64 + wm + 16 * i + crow;
      int c0 = bn * 64 + wn + 16 * j + ccol;
#pragma unroll
      for (int rg = 0; rg < 4; ++rg) {
        float v = accs[i][j][rg] * alpha;
        if constexpr (BIAS) v += bias[c0];
        Cb[(size_t)(r0 + rg) * Nc + c0] = v;
      }
    }
}

// ---------------------------------------------------------------------------
// Split-precision NT GEMM, 128x128 tile, global_load_lds staging, XOR swizzle.
// ---------------------------------------------------------------------------
__global__ __launch_bounds__(256) void gemm3_big(
    const h16* __restrict__ Ah, const h16* __restrict__ Al,
    const h16* __restrict__ Bh, const h16* __restrict__ Bl,
    float* __restrict__ C, float alpha, int M, int Nc, int Kd) {
  __shared__ h16 sAh[128 * 32], sAl[128 * 32], sBh[128 * 32], sBl[128 * 32];
  int tid = threadIdx.x, wid = tid >> 6, lane = tid & 63;
  int bm = blockIdx.y, bn = blockIdx.x;
  int srow = 32 * wid + (lane >> 2);
  int scnk = lane & 3;
  int fr = lane & 15, fcc = lane >> 4;
  f32x4 acc[4][4] = {};
  const h16* gA[2] = {Ah, Al};
  const h16* gB[2] = {Bh, Bl};
  h16* sA[2] = {sAh, sAl};
  h16* sB[2] = {sBh, sBl};
  int wm = (wid & 1) * 64, wn = (wid >> 1) * 64;
  for (int k0 = 0; k0 < Kd; k0 += 32) {
    __syncthreads();
#pragma unroll
    for (int h = 0; h < 2; ++h) {
      int r = srow + 16 * h;
      int cs = scnk ^ ((r >> 1) & 3);
      size_t goffA = (size_t)(bm * 128 + r) * Kd + k0 + cs * 8;
      size_t goffB = (size_t)(bn * 128 + r) * Kd + k0 + cs * 8;
      int loff = (32 * wid + 16 * h) * 32;
#pragma unroll
      for (int p = 0; p < 2; ++p) {
        gl_lds16(gA[p] + goffA, sA[p] + loff);
        gl_lds16(gB[p] + goffB, sB[p] + loff);
      }
    }
    __syncthreads();
    h16x8 fa[2][4], fb[2][4];
#pragma unroll
    for (int i = 0; i < 4; ++i) {
      int ra = wm + 16 * i + fr;
      int ca = (fcc ^ ((ra >> 1) & 3)) * 8;
      fa[0][i] = *(const h16x8*)(sAh + ra * 32 + ca);
      fa[1][i] = *(const h16x8*)(sAl + ra * 32 + ca);
      int rb = wn + 16 * i + fr;
      int cb = (fcc ^ ((rb >> 1) & 3)) * 8;
      fb[0][i] = *(const h16x8*)(sBh + rb * 32 + cb);
      fb[1][i] = *(const h16x8*)(sBl + rb * 32 + cb);
    }
#pragma unroll
    for (int i = 0; i < 4; ++i)
#pragma unroll
      for (int j = 0; j < 4; ++j) {
        acc[i][j] = mfma16(fa[0][i], fb[0][j], acc[i][j]);
        acc[i][j] = mfma16(fa[0][i], fb[1][j], acc[i][j]);
        acc[i][j] = mfma16(fa[1][i], fb[0][j], acc[i][j]);
      }
  }
  int crow = (lane >> 4) << 2, ccol = lane & 15;
#pragma unroll
  for (int i = 0; i < 4; ++i)
#pragma unroll
    for (int j = 0; j < 4; ++j) {
      int r0 = bm * 128 + wm + 16 * i + crow;
      int c0 = bn * 128 + wn + 16 * j + ccol;
#pragma unroll
      for (int rg = 0; rg < 4; ++rg)
        C[(size_t)(r0 + rg) * Nc + c0] = acc[i][j][rg] * alpha;
    }
}

// ---------------------------------------------------------------------------
// Plain fp16 NT GEMM, 128x128 tile, K-SPLIT over blockIdx.z (Kc per slice).
// Writes f32 partials: Cpart[z][4096][256]. M=4096, Nc=256 fixed.
// ---------------------------------------------------------------------------
__global__ __launch_bounds__(256) void gemm_ks(
    const h16* __restrict__ A, const h16* __restrict__ B,
    float* __restrict__ Cpart, int Kd, int Kc) {
  __shared__ h16 sA[128 * 32], sB[128 * 32];
  int tid = threadIdx.x, wid = tid >> 6, lane = tid & 63;
  int bm = blockIdx.y, bn = blockIdx.x, kz = blockIdx.z;
  int kbase = kz * Kc;
  int srow = 32 * wid + (lane >> 2);
  int scnk = lane & 3;
  int fr = lane & 15, fcc = lane >> 4;
  f32x4 acc[4][4] = {};
  int wm = (wid & 1) * 64, wn = (wid >> 1) * 64;
  for (int k0 = 0; k0 < Kc; k0 += 32) {
    __syncthreads();
#pragma unroll
    for (int h = 0; h < 2; ++h) {
      int r = srow + 16 * h;
      int cs = scnk ^ ((r >> 1) & 3);
      size_t goffA = (size_t)(bm * 128 + r) * Kd + kbase + k0 + cs * 8;
      size_t goffB = (size_t)(bn * 128 + r) * Kd + kbase + k0 + cs * 8;
      int loff = (32 * wid + 16 * h) * 32;
      gl_lds16(A + goffA, sA + loff);
      gl_lds16(B + goffB, sB + loff);
    }
    __syncthreads();
    h16x8 fa[4], fb[4];
#pragma unroll
    for (int i = 0; i < 4; ++i) {
      int ra = wm + 16 * i + fr;
      int ca = (fcc ^ ((ra >> 1) & 3)) * 8;
      fa[i] = *(const h16x8*)(sA + ra * 32 + ca);
      int rb = wn + 16 * i + fr;
      int cb = (fcc ^ ((rb >> 1) & 3)) * 8;
      fb[i] = *(const h16x8*)(sB + rb * 32 + cb);
    }
#pragma unroll
    for (int i = 0; i < 4; ++i)
#pragma unroll
      for (int j = 0; j < 4; ++j)
        acc[i][j] = mfma16(fa[i], fb[j], acc[i][j]);
  }
  float* Cp = Cpart + (size_t)kz * 4096 * 256;
  int crow = (lane >> 4) << 2, ccol = lane & 15;
#pragma unroll
  for (int i = 0; i < 4; ++i)
#pragma unroll
    for (int j = 0; j < 4; ++j) {
      int r0 = bm * 128 + wm + 16 * i + crow;
      int c0 = bn * 128 + wn + 16 * j + ccol;
#pragma unroll
      for (int rg = 0; rg < 4; ++rg)
        Cp[(size_t)(r0 + rg) * 256 + c0] = acc[i][j][rg];
    }
}

// Zk += (*scptr) * rowSinv[row] * sum_z Cpart[z]
__global__ __launch_bounds__(256) void ks_reduce(
    const float* __restrict__ Cpart, const float* __restrict__ scptr,
    const float* __restrict__ rowSinv, float* __restrict__ Zk) {
  int i = (blockIdx.x * 256 + threadIdx.x) * 4;  // grid 1024
  float4 s = {0.f, 0.f, 0.f, 0.f};
#pragma unroll
  for (int z = 0; z < 8; ++z) {
    float4 p = *(const float4*)(Cpart + (size_t)z * 4096 * 256 + i);
    s.x += p.x; s.y += p.y; s.z += p.z; s.w += p.w;
  }
  float sc = (*scptr) * rowSinv[i >> 8];
  float4 zk = *(float4*)(Zk + i);
  zk.x += sc * s.x; zk.y += sc * s.y; zk.z += sc * s.z; zk.w += sc * s.w;
  *(float4*)(Zk + i) = zk;
}

// 16-bit transpose
__global__ __launch_bounds__(256) void transpose16(
    const u16* __restrict__ in, u16* __restrict__ out, int rows, int cols) {
  __shared__ u16 t[32][33];
  const u16* ib = in + (size_t)blockIdx.z * rows * cols;
  u16* ob = out + (size_t)blockIdx.z * rows * cols;
  int r0 = blockIdx.x * 32, c0 = blockIdx.y * 32;
  int tx = threadIdx.x & 31, ty = threadIdx.x >> 5;
#pragma unroll
  for (int i = 0; i < 32; i += 8)
    t[ty + i][tx] = ib[(size_t)(r0 + ty + i) * cols + c0 + tx];
  __syncthreads();
#pragma unroll
  for (int i = 0; i < 32; i += 8)
    ob[(size_t)(c0 + ty + i) * rows + r0 + tx] = t[tx][ty + i];
}

// scalars: w=softmax(alpha)->scal[0..3], rho=sigmoid(rho_raw)->scal[4]
__global__ void prep_scalars(const void* __restrict__ alpha,
                             const void* __restrict__ rho_raw,
                             float* __restrict__ scal,
                             const int* __restrict__ flag) {
  if (threadIdx.x == 0) {
    int f = *flag;
    float a[4], e[4], m = -1e30f, s = 0.f;
    for (int i = 0; i < 4; ++i) {
      a[i] = f ? ((const float*)alpha)[i] : b2f(((const u16*)alpha)[i]);
      m = fmaxf(m, a[i]);
    }
    for (int i = 0; i < 4; ++i) { e[i] = expf(a[i] - m); s += e[i]; }
    for (int i = 0; i < 4; ++i) scal[i] = e[i] / s;
    float rr = f ? ((const float*)rho_raw)[0] : b2f(((const u16*)rho_raw)[0]);
    scal[4] = 1.f / (1.f + expf(-rr));
  }
}

// ---------------------------------------------------------------------------
// fused per-row (one wave per row): max -> threshold T -> exp/E-write +
// candidate push -> exact jax-tiebreak top-16 from candidates
// ---------------------------------------------------------------------------
__global__ __launch_bounds__(256) void row_softmax_topk(
    const float* __restrict__ A, float* __restrict__ topv,
    int* __restrict__ topi, h16* __restrict__ E, float* __restrict__ rowSinv,
    int khead) {
  __shared__ u64 candK[4][256];
  __shared__ int candN[4];
  int wid = threadIdx.x >> 6, lane = threadIdx.x & 63;
  int row = blockIdx.x * 4 + wid;
  const float* arow = A + ((size_t)row << 12);
  if (lane == 0) candN[wid] = 0;
  __syncthreads();
  float lm = -INFINITY;
#pragma unroll
  for (int t = 0; t < 16; ++t) {
    float4 v = *(const float4*)(arow + (t << 8) + (lane << 2));
    lm = fmaxf(lm, fmaxf(fmaxf(v.x, v.y), fmaxf(v.z, v.w)));
  }
  float m = lm;
#pragma unroll
  for (int off = 32; off; off >>= 1) m = fmaxf(m, __shfl_xor(m, off));
  u64 lk = ((u64)fkey(lm) << 32) | (unsigned)lane;
  float T = 0.f;
  for (int r = 0; r < 16; ++r) {
    u64 k2 = wave_max_u64(lk);
    if (lk == k2) lk = 0;
    if (r == 15) T = unfkey((unsigned)(k2 >> 32));
  }
  h16* erow = E + ((size_t)row << 12);
  int* cn = &candN[wid];
  u64* ck = candK[wid];
  float s = 0.f;
  for (int t = 0; t < 16; ++t) {
    int c = (t << 8) + (lane << 2);
    float4 v = *(const float4*)(arow + c);
    float e0 = __expf(v.x - m), e1 = __expf(v.y - m);
    float e2 = __expf(v.z - m), e3 = __expf(v.w - m);
    s += (e0 + e1) + (e2 + e3);
    h16x4 hv = {(h16)e0, (h16)e1, (h16)e2, (h16)e3};
    *(h16x4*)(erow + c) = hv;
    if (v.x >= T) {
      int sl = atomicAdd(cn, 1);
      if (sl < 256) ck[sl] = ((u64)fkey(v.x) << 32) | (unsigned)(~(unsigned)c);
    }
    if (v.y >= T) {
      int sl = atomicAdd(cn, 1);
      if (sl < 256) ck[sl] = ((u64)fkey(v.y) << 32) | (unsigned)(~(unsigned)(c + 1));
    }
    if (v.z >= T) {
      int sl = atomicAdd(cn, 1);
      if (sl < 256) ck[sl] = ((u64)fkey(v.z) << 32) | (unsigned)(~(unsigned)(c + 2));
    }
    if (v.w >= T) {
      int sl = atomicAdd(cn, 1);
      if (sl < 256) ck[sl] = ((u64)fkey(v.w) << 32) | (unsigned)(~(unsigned)(c + 3));
    }
  }
#pragma unroll
  for (int off = 32; off; off >>= 1) s += __shfl_xor(s, off);
  if (lane == 0) rowSinv[row] = 1.f / s;
  __syncthreads();
  int cnt = min(*cn, 256);
  u64 loc[4] = {0ull, 0ull, 0ull, 0ull};
  int nl = 0;
  for (int j = lane; j < cnt; j += 64)
    if (nl < 4) loc[nl++] = ck[j];
#define CSW(a, b)                     \
  {                                   \
    if (loc[b] > loc[a]) {            \
      u64 tt = loc[a];                \
      loc[a] = loc[b];                \
      loc[b] = tt;                    \
    }                                 \
  }
  CSW(0, 1) CSW(2, 3) CSW(0, 2) CSW(1, 3) CSW(1, 2)
#undef CSW
  float myv = 0.f;
  int myi = 0;
  float sum16 = 0.f;
  for (int r = 0; r < 16; ++r) {
    u64 key = loc[0];
    u64 k2 = wave_max_u64(key);
    float wv = unfkey((unsigned)(k2 >> 32));
    int wi = (int)(~(unsigned)(k2 & 0xffffffffu));
    if (key == k2 && key != 0ull) {
      loc[0] = loc[1];
      loc[1] = loc[2];
      loc[2] = loc[3];
      loc[3] = 0ull;
    }
    sum16 += expf(wv - m);
    if (r == lane) { myv = wv; myi = wi; }
  }
  if (lane < 16) {
    size_t o = (((size_t)khead << 12) + row) * 16 + lane;
    topv[o] = expf(myv - m) / (sum16 + 1e-9f * s);
    topi[o] = myi;
  }
}

// ---------------------------------------------------------------------------
// sparse hypergraph build — NO global atomics (two-level LDS histogram)
// 262144 entries, 64 blocks x 4096 entries
// ---------------------------------------------------------------------------
__global__ __launch_bounds__(256) void hist_part(
    const float* __restrict__ topv, const int* __restrict__ topi,
    int* __restrict__ pCnt, float* __restrict__ pDv) {
  __shared__ int lc[4096];
  __shared__ float ld[4096];
  int tid = threadIdx.x, b = blockIdx.x;  // grid 64
  for (int j = tid; j < 4096; j += 256) { lc[j] = 0; ld[j] = 0.f; }
  __syncthreads();
  int base = b * 4096;
#pragma unroll
  for (int j = 0; j < 16; ++j) {
    int t = base + j * 256 + tid;
    atomicAdd(&lc[topi[t]], 1);
    atomicAdd(&ld[topi[t]], topv[t]);
  }
  __syncthreads();
  for (int j = tid; j < 4096; j += 256) {
    pCnt[base + j] = lc[j];
    pDv[base + j] = ld[j];
  }
}

// per-bin reduce over 64 blocks: cnt, Dvis, within-bin block prefix
__global__ __launch_bounds__(256) void col_scan(
    const int* __restrict__ pCnt, const float* __restrict__ pDv,
    int* __restrict__ cnt, float* __restrict__ Dvis,
    int* __restrict__ blockBase) {
  int i = blockIdx.x * 256 + threadIdx.x;  // grid 16 -> 4096
  int run = 0;
  float dv = 0.f;
#pragma unroll
  for (int b = 0; b < 64; ++b) {
    blockBase[b * 4096 + i] = run;
    run += pCnt[b * 4096 + i];
    dv += pDv[b * 4096 + i];
  }
  cnt[i] = run;
  Dvis[i] = sqrtf(1.0f / (dv + 1e-9f));
}

// per-edge DeIS via 4 independent float4 loads
__global__ __launch_bounds__(256) void edge_deis(
    const float* __restrict__ topv, float* __restrict__ DeIS) {
  int e = blockIdx.x * 256 + threadIdx.x;  // grid 64
  const float4* p = (const float4*)(topv + ((size_t)e << 4));
  float4 a = p[0], b = p[1], c = p[2], d = p[3];
  float s = ((a.x + a.y) + (a.z + a.w)) + ((b.x + b.y) + (b.z + b.w)) +
            ((c.x + c.y) + (c.z + c.w)) + ((d.x + d.y) + (d.z + d.w));
  DeIS[e] = 1.0f / sqrtf(s + 1e-9f);
}

// exclusive scan of cnt[4096] -> rowptr[4097]
__global__ __launch_bounds__(256) void scan_rowptr(const int* __restrict__ cnt,
                                                   int* __restrict__ rowptr) {
  __shared__ int part[256];
  int tid = threadIdx.x;
  int base = tid * 16;
  int loc[16];
  int s = 0;
#pragma unroll
  for (int j = 0; j < 16; ++j) { loc[j] = s; s += cnt[base + j]; }
  part[tid] = s;
  __syncthreads();
  for (int off = 1; off < 256; off <<= 1) {
    int v = (tid >= off) ? part[tid - off] : 0;
    __syncthreads();
    part[tid] += v;
    __syncthreads();
  }
  int pre = (tid == 0) ? 0 : part[tid - 1];
#pragma unroll
  for (int j = 0; j < 16; ++j) rowptr[base + j] = pre + loc[j];
  if (tid == 255) rowptr[4096] = part[255];
}

// fill cvals + CSR transpose via LDS cursors (no global atomics)
__global__ __launch_bounds__(256) void csr_fill3(
    const float* __restrict__ topv, const int* __restrict__ topi,
    const float* __restrict__ Dvis, const float* __restrict__ DeIS,
    const int* __restrict__ rowptr, const int* __restrict__ blockBase,
    float* __restrict__ cvals, int* __restrict__ colE,
    float* __restrict__ cvalR) {
  __shared__ int lcur[4096];
  int tid = threadIdx.x, b = blockIdx.x;  // grid 64
  int base = b * 4096;
  for (int j = tid; j < 4096; j += 256)
    lcur[j] = rowptr[j] + blockBase[base + j];
  __syncthreads();
#pragma unroll
  for (int j = 0; j < 16; ++j) {
    int t = base + j * 256 + tid;
    int i = topi[t];
    int e = t >> 4;
    float c = Dvis[i] * topv[t] * DeIS[e];
    cvals[t] = c;
    int slot = atomicAdd(&lcur[i], 1);
    colE[slot] = e;
    cvalR[slot] = c;
  }
}

// g[e] = sum_p c[e,p] * v[idx[e,p]]
__global__ __launch_bounds__(256) void spmv_edge(
    const float* __restrict__ cvals, const int* __restrict__ topi,
    const float* __restrict__ v, float* __restrict__ g) {
  int e = blockIdx.x * 256 + threadIdx.x;  // grid 64
  float acc = 0.f;
#pragma unroll
  for (int p = 0; p < 16; ++p)
    acc += cvals[e * 16 + p] * v[topi[e * 16 + p]];
  g[e] = acc;
}

// vout[i] = vin[i] - sum_{j in row i} cvalR[j]*g[colE[j]]
__global__ __launch_bounds__(256) void spmv_row(
    const int* __restrict__ rowptr, const int* __restrict__ colE,
    const float* __restrict__ cvalR, const float* __restrict__ g,
    const float* __restrict__ vin, float* __restrict__ vout) {
  int wid = threadIdx.x >> 6, lane = threadIdx.x & 63;
  int row = blockIdx.x * 4 + wid;  // grid 1024
  int s = rowptr[row], e = rowptr[row + 1];
  float acc = 0.f;
  for (int j = s + lane; j < e; j += 64) acc += cvalR[j] * g[colE[j]];
#pragma unroll
  for (int off = 32; off; off >>= 1) acc += __shfl_xor(acc, off);
  if (lane == 0) vout[row] = vin[row] - acc;
}

// G[e,:] = sum_p c[e,p] * M[idx[e,p],:]  — MLP-unrolled (16 gathers in flight)
__global__ __launch_bounds__(256) void spmm_edge(
    const float* __restrict__ cvals, const int* __restrict__ topi,
    const float* __restrict__ M, float* __restrict__ G) {
  int wid = threadIdx.x >> 6, lane = threadIdx.x & 63;
  int e = blockIdx.x * 4 + wid;  // grid 4096
  int cb = lane << 2;
  const float* cv = cvals + ((size_t)e << 4);
  const int* ti = topi + ((size_t)e << 4);
  float cc[16];
  int ix[16];
#pragma unroll
  for (int p = 0; p < 16; ++p) { cc[p] = cv[p]; ix[p] = ti[p]; }
  float4 acc[4] = {};
#pragma unroll
  for (int h = 0; h < 2; ++h) {
    float4 g[8];
#pragma unroll
    for (int p = 0; p < 8; ++p)
      g[p] = *(const float4*)(M + ((size_t)ix[h * 8 + p] << 8) + cb);
#pragma unroll
    for (int p = 0; p < 8; ++p) {
      float c = cc[h * 8 + p];
      float4 gg = g[p];
      int a = p & 3;
      acc[a].x += c * gg.x; acc[a].y += c * gg.y;
      acc[a].z += c * gg.z; acc[a].w += c * gg.w;
    }
  }
  float4 r;
  r.x = (acc[0].x + acc[1].x) + (acc[2].x + acc[3].x);
  r.y = (acc[0].y + acc[1].y) + (acc[2].y + acc[3].y);
  r.z = (acc[0].z + acc[1].z) + (acc[2].z + acc[3].z);
  r.w = (acc[0].w + acc[1].w) + (acc[2].w + acc[3].w);
  *(float4*)(G + ((size_t)e << 8) + cb) = r;
}

// Z[i,:] = sum_{j in row i} cvalR[j] * G[colE[j],:]  — 8-wide MLP unroll
__global__ __launch_bounds__(256) void spmm_row(
    const int* __restrict__ rowptr, const int* __restrict__ colE,
    const float* __restrict__ cvalR, const float* __restrict__ G,
    float* __restrict__ Z) {
  int wid = threadIdx.x >> 6, lane = threadIdx.x & 63;
  int row = blockIdx.x * 4 + wid;  // grid 1024
  int cb = lane << 2;
  int s = rowptr[row], e = rowptr[row + 1];
  float4 acc[4] = {};
  int j = s;
  for (; j + 8 <= e; j += 8) {
    int ix[8];
    float cc[8];
#pragma unroll
    for (int t = 0; t < 8; ++t) { ix[t] = colE[j + t]; cc[t] = cvalR[j + t]; }
    float4 g[8];
#pragma unroll
    for (int t = 0; t < 8; ++t)
      g[t] = *(const float4*)(G + ((size_t)ix[t] << 8) + cb);
#pragma unroll
    for (int t = 0; t < 8; ++t) {
      float c = cc[t];
      float4 gg = g[t];
      int a = t & 3;
      acc[a].x += c * gg.x; acc[a].y += c * gg.y;
      acc[a].z += c * gg.z; acc[a].w += c * gg.w;
    }
  }
  for (; j < e; ++j) {
    float c = cvalR[j];
    float4 gg = *(const float4*)(G + ((size_t)colE[j] << 8) + cb);
    acc[0].x += c * gg.x; acc[0].y += c * gg.y;
    acc[0].z += c * gg.z; acc[0].w += c * gg.w;
  }
  float4 r;
  r.x = (acc[0].x + acc[1].x) + (acc[2].x + acc[3].x);
  r.y = (acc[0].y + acc[1].y) + (acc[2].y + acc[3].y);
  r.z = (acc[0].z + acc[1].z) + (acc[2].z + acc[3].z);
  r.w = (acc[0].w + acc[1].w) + (acc[2].w + acc[3].w);
  *(float4*)(Z + ((size_t)row << 8) + cb) = r;
}

// v0: bit-exact jax.random.normal(key(1), (4096,1), f32)
__global__ __launch_bounds__(256) void init_v0(float* __restrict__ v) {
  int tid = blockIdx.x * 256 + threadIdx.x;
  unsigned j = (unsigned)(tid & 2047);
  unsigned x0 = j, x1 = j + 2048u;
  const unsigned ks0 = 0u, ks1 = 1u, ks2 = 0x1BD11BDAu;
  x0 += ks0; x1 += ks1;
#define TF_R(r)                                  \
  {                                              \
    x0 += x1;                                    \
    x1 = (x1 << (r)) | (x1 >> (32 - (r)));       \
    x1 ^= x0;                                    \
  }
  TF_R(13) TF_R(15) TF_R(26) TF_R(6)  x0 += ks1; x1 += ks2 + 1u;
  TF_R(17) TF_R(29) TF_R(16) TF_R(24) x0 += ks2; x1 += ks0 + 2u;
  TF_R(13) TF_R(15) TF_R(26) TF_R(6)  x0 += ks0; x1 += ks1 + 3u;
  TF_R(17) TF_R(29) TF_R(16) TF_R(24) x0 += ks1; x1 += ks2 + 4u;
  TF_R(13) TF_R(15) TF_R(26) TF_R(6)  x0 += ks2; x1 += ks0 + 5u;
#undef TF_R
  unsigned bits = (tid < 2048) ? x0 : x1;
  float u01 = __uint_as_float((bits >> 9) | 0x3f800000u) - 1.0f;
  const float lo = -0.99999994f;
  float u = fmaxf(lo, u01 * 2.0f + lo);
  float w = -log1pf(-u * u);
  float p;
  if (w < 5.0f) {
    float t = w - 2.5f;
    p = 2.81022636e-08f;
    p = 3.43273939e-07f + p * t;
    p = -3.5233877e-06f + p * t;
    p = -4.39150654e-06f + p * t;
    p = 0.00021858087f + p * t;
    p = -0.00125372503f + p * t;
    p = -0.00417768164f + p * t;
    p = 0.246640727f + p * t;
    p = 1.50140941f + p * t;
  } else {
    float t = sqrtf(w) - 3.0f;
    p = -0.000200214257f;
    p = 0.000100950558f + p * t;
    p = 0.00134934322f + p * t;
    p = -0.00367342844f + p * t;
    p = 0.00573950773f + p * t;
    p = -0.0076224613f + p * t;
    p = 0.00943887047f + p * t;
    p = 1.00167406f + p * t;
    p = 2.83297682f + p * t;
  }
  v[tid] = 1.41421354f * (p * u);
}

// lam = clip((w5.w6)/(w5.w5), 1e-3) -> scal[5]
__global__ __launch_bounds__(256) void pi_dots(const float* __restrict__ w5,
                                               const float* __restrict__ w6,
                                               float* __restrict__ scal) {
  __shared__ float r1[256], r2[256];
  int tid = threadIdx.x;
  float a = 0.f, b = 0.f;
  for (int i = tid; i < 4096; i += 256) {
    float x = w5[i];
    a += x * x;
    b += x * w6[i];
  }
  r1[tid] = a; r2[tid] = b;
  __syncthreads();
  for (int off = 128; off; off >>= 1) {
    if (tid < off) { r1[tid] += r1[tid + off]; r2[tid] += r2[tid + off]; }
    __syncthreads();
  }
  if (tid == 0) scal[5] = fmaxf(r2[0] / r1[0], 1e-3f);
}

// T1 = (c1-1)X - c1*SnX
__global__ __launch_bounds__(256) void t1_simple(
    const float* __restrict__ SnX, const float* __restrict__ Xf,
    const float* __restrict__ scal, float* __restrict__ T1) {
  int i = blockIdx.x * 256 + threadIdx.x;  // grid 4096
  float c1 = 2.0f / scal[5];
  T1[i] = (c1 - 1.0f) * Xf[i] - c1 * SnX[i];
}

// T2, cheb combine, elu, mix -> Zmix split hi/lo fp16
__global__ __launch_bounds__(256) void combine_kernel(
    const float* __restrict__ Xf, const float* __restrict__ T1,
    const float* __restrict__ SnT1, const float* __restrict__ Zk,
    const float* __restrict__ thetaf, const float* __restrict__ scal,
    h16* __restrict__ Zmh, h16* __restrict__ Zml) {
  int idx = blockIdx.x * 256 + threadIdx.x;  // grid 4096
  int d = idx & 255;
  float c1 = 2.0f / scal[5];
  float rho = scal[4];
  float x = Xf[idx];
  float t1 = T1[idx];
  float t2 = 2.0f * ((c1 - 1.0f) * t1 - c1 * SnT1[idx]) - x;
  float o = x * thetaf[d] + t1 * thetaf[256 + d] + t2 * thetaf[512 + d];
  float zs = o > 0.0f ? o : expm1f(o);
  float zm = rho * zs + (1.0f - rho) * Zk[idx];
  h16 h = (h16)zm;
  Zmh[idx] = h;
  Zml[idx] = (h16)(zm - (float)h);
}

// ---------------------------------------------------------------------------
extern "C" void kernel_launch(void* const* d_in, const int* in_sizes, int n_in,
                              void* d_out, int out_size, void* d_ws,
                              size_t ws_size, hipStream_t stream) {
  (void)in_sizes; (void)n_in; (void)out_size;
  const void* Xin = d_in[0];
  const void* Lin = d_in[1];
  const void* alpha = d_in[2];
  const void* theta = d_in[3];
  const void* rho_raw = d_in[4];
  const void* Wpin = d_in[5];
  const void* bpin = d_in[6];
  float* out = (float*)d_out;

  char* base = (char*)d_ws;
  size_t off = 0;
  auto alloc = [&](size_t bytes) -> char* {
    char* p = base + off;
    off += (bytes + 255) & ~(size_t)255;
    return p;
  };
  float* Abuf = (float*)alloc((size_t)4096 * 4096 * 4);  // A; ks-partials; G
  h16* Ebuf = (h16*)alloc((size_t)4096 * 4096 * 2);      // Yf alias; E per head
  h16* Yhi = (h16*)alloc((size_t)4 * 4096 * 256 * 2);
  h16* Ylo = (h16*)alloc((size_t)4 * 4096 * 256 * 2);
  h16* Xhi = (h16*)alloc((size_t)4096 * 256 * 2);
  h16* Xlo = (h16*)alloc((size_t)4096 * 256 * 2);
  float* Xf = (float*)alloc((size_t)4096 * 256 * 4);
  h16* XT = (h16*)alloc((size_t)256 * 4096 * 2);
  h16* Lhi = (h16*)alloc((size_t)4 * 256 * 256 * 2);
  h16* Llo = (h16*)alloc((size_t)4 * 256 * 256 * 2);
  h16* LThi = (h16*)alloc((size_t)4 * 256 * 256 * 2);
  h16* LTlo = (h16*)alloc((size_t)4 * 256 * 256 * 2);
  h16* Whi = (h16*)alloc((size_t)256 * 256 * 2);
  h16* Wlo = (h16*)alloc((size_t)256 * 256 * 2);
  float* Zk = (float*)alloc((size_t)4096 * 256 * 4);
  float* SnX = (float*)alloc((size_t)4096 * 256 * 4);  // then SnT1
  float* T1 = (float*)alloc((size_t)4096 * 256 * 4);
  h16* Zmh = (h16*)alloc((size_t)4096 * 256 * 2);
  h16* Zml = (h16*)alloc((size_t)4096 * 256 * 2);
  float* topv = (float*)alloc((size_t)4 * 4096 * 16 * 4);
  int* topi = (int*)alloc((size_t)4 * 4096 * 16 * 4);
  float* cvals = (float*)alloc((size_t)262144 * 4);
  int* colE = (int*)alloc((size_t)262144 * 4);
  float* cvalR = (float*)alloc((size_t)262144 * 4);
  int* pCnt = (int*)alloc((size_t)64 * 4096 * 4);
  float* pDv = (float*)alloc((size_t)64 * 4096 * 4);
  int* blockBase = (int*)alloc((size_t)64 * 4096 * 4);
  int* rowptr = (int*)alloc(4097 * 4);
  int* cnt = (int*)alloc(4096 * 4);
  float* Dvis = (float*)alloc(4096 * 4);
  float* DeIS = (float*)alloc(16384 * 4);
  float* gE = (float*)alloc(16384 * 4);
  float* wA = (float*)alloc(4096 * 4);
  float* wB = (float*)alloc(4096 * 4);
  float* rowSinv = (float*)alloc(4096 * 4);
  float* thetaf = (float*)alloc(768 * 4);
  float* biasf = (float*)alloc(256 * 4);
  float* scal = (float*)alloc(256);
  int* flag = (int*)alloc(256);
  if (off > ws_size) return;
  float* Yf = (float*)Ebuf;  // 16 MB alias; dead before E written
  float* G = (float*)Abuf;   // 16 MB alias; dead after last head's softmax
  float* Kpart = Abuf;       // 32 MB alias; A dead after row_softmax reads it

  detect_dtype<<<1, 256, 0, stream>>>((const u16*)Xin, flag);
  split_input3<<<1024, 256, 0, stream>>>(Xin, Xhi, Xlo, Xf, 4096 * 256, flag);
  split_input3<<<256, 256, 0, stream>>>(Lin, Lhi, Llo, nullptr, 4 * 256 * 256,
                                        flag);
  split_input3<<<64, 256, 0, stream>>>(Wpin, Whi, Wlo, nullptr, 256 * 256, flag);
  conv_f32<<<1, 256, 0, stream>>>(theta, thetaf, 768, flag);
  conv_f32<<<1, 256, 0, stream>>>(bpin, biasf, 256, flag);
  prep_scalars<<<1, 64, 0, stream>>>(alpha, rho_raw, scal, flag);
  transpose16<<<dim3(128, 8, 1), 256, 0, stream>>>((const u16*)Xhi, (u16*)XT,
                                                   4096, 256);
  transpose16<<<dim3(8, 8, 4), 256, 0, stream>>>((const u16*)Lhi, (u16*)LThi,
                                                 256, 256);
  transpose16<<<dim3(8, 8, 4), 256, 0, stream>>>((const u16*)Llo, (u16*)LTlo,
                                                 256, 256);
  // Yf = X @ L_k (split fp16, fused), batched z=4
  gemm3_nt<false><<<dim3(4, 64, 4), 256, 0, stream>>>(
      Xhi, Xlo, LThi, LTlo, Yf, nullptr, 1.0f, 4096, 256, 256,
      0L, 256L * 256L, 4096L * 256L);
  split_f32h<<<2048, 256, 0, stream>>>(Yf, Yhi, Ylo, 4 * 4096 * 256);
  hipMemsetAsync(Zk, 0, (size_t)4096 * 256 * 4, stream);
  for (int k = 0; k < 4; ++k) {
    // A = Y_k @ X^T / 16 (split fp16, 128x128 tile, global_load_lds)
    gemm3_big<<<dim3(32, 32), 256, 0, stream>>>(
        Yhi + (size_t)k * 4096 * 256, Ylo + (size_t)k * 4096 * 256, Xhi, Xlo,
        Abuf, 0.0625f, 4096, 4096, 256);
    row_softmax_topk<<<1024, 256, 0, stream>>>(Abuf, topv, topi, Ebuf, rowSinv,
                                               k);
    // E @ X via K-split MFMA into 8 f32 partials (A is dead; reuse Abuf)
    gemm_ks<<<dim3(2, 32, 8), 256, 0, stream>>>(Ebuf, XT, Kpart, 4096, 512);
    // Zk += w_k * invS[row] * sum_z partial[z]
    ks_reduce<<<1024, 256, 0, stream>>>(Kpart, scal + k, rowSinv, Zk);
  }
  // sparse hypergraph Laplacian — atomic-free two-level histogram build
  hist_part<<<64, 256, 0, stream>>>(topv, topi, pCnt, pDv);
  col_scan<<<16, 256, 0, stream>>>(pCnt, pDv, cnt, Dvis, blockBase);
  edge_deis<<<64, 256, 0, stream>>>(topv, DeIS);
  scan_rowptr<<<1, 256, 0, stream>>>(cnt, rowptr);
  csr_fill3<<<64, 256, 0, stream>>>(topv, topi, Dvis, DeIS, rowptr, blockBase,
                                    cvals, colE, cvalR);
  init_v0<<<16, 256, 0, stream>>>(wA);
  for (int it = 0; it < 6; ++it) {
    const float* vi = (it & 1) ? wB : wA;
    float* vo = (it & 1) ? wA : wB;
    spmv_edge<<<64, 256, 0, stream>>>(cvals, topi, vi, gE);
    spmv_row<<<1024, 256, 0, stream>>>(rowptr, colE, cvalR, gE, vi, vo);
  }
  pi_dots<<<1, 256, 0, stream>>>(wB, wA, scal);
  // SnX = S_norm @ X (sparse, f32-exact)
  spmm_edge<<<4096, 256, 0, stream>>>(cvals, topi, Xf, G);
  spmm_row<<<1024, 256, 0, stream>>>(rowptr, colE, cvalR, G, SnX);
  t1_simple<<<4096, 256, 0, stream>>>(SnX, Xf, scal, T1);
  // SnT1 = S_norm @ T1 (overwrite SnX)
  spmm_edge<<<4096, 256, 0, stream>>>(cvals, topi, T1, G);
  spmm_row<<<1024, 256, 0, stream>>>(rowptr, colE, cvalR, G, SnX);
  combine_kernel<<<4096, 256, 0, stream>>>(Xf, T1, SnX, Zk, thetaf, scal, Zmh,
                                           Zml);
  // out = Zmix @ proj_w^T + proj_b (split fp16, f32 out)
  gemm3_nt<true><<<dim3(4, 64, 1), 256, 0, stream>>>(
      Zmh, Zml, Whi, Wlo, out, biasf, 1.0f, 4096, 256, 256, 0L, 0L, 0L);
}

// Round 10
// 682.613 us; speedup vs baseline: 1.8813x; 1.0516x over previous
//
#include <hip/hip_runtime.h>

typedef unsigned short u16;
typedef unsigned long long u64;
typedef _Float16 h16;
typedef __attribute__((ext_vector_type(8))) _Float16 h16x8;
typedef __attribute__((ext_vector_type(4))) _Float16 h16x4;
typedef __attribute__((ext_vector_type(4))) float f32x4;

__device__ __forceinline__ float b2f(u16 u) {
  unsigned x = ((unsigned)u) << 16;
  return __uint_as_float(x);
}
__device__ __forceinline__ unsigned fkey(float f) {
  unsigned b = __float_as_uint(f);
  return (b & 0x80000000u) ? ~b : (b | 0x80000000u);
}
__device__ __forceinline__ float unfkey(unsigned u) {
  unsigned b = (u & 0x80000000u) ? (u ^ 0x80000000u) : ~u;
  return __uint_as_float(b);
}
__device__ __forceinline__ f32x4 mfma16(h16x8 a, h16x8 b, f32x4 c) {
  return __builtin_amdgcn_mfma_f32_16x16x32_f16(a, b, c, 0, 0, 0);
}
__device__ __forceinline__ void gl_lds16(const void* g, void* l) {
  __builtin_amdgcn_global_load_lds(
      (const __attribute__((address_space(1))) unsigned*)g,
      (__attribute__((address_space(3))) unsigned*)l, 16, 0, 0);
}
__device__ __forceinline__ u64 wave_max_u64(u64 k) {
#pragma unroll
  for (int off = 32; off; off >>= 1) {
    u64 o = __shfl_xor(k, off);
    if (o > k) k = o;
  }
  return k;
}
__device__ __forceinline__ float cvt_in(const void* p, int i, int f) {
  return f ? ((const float*)p)[i] : b2f(((const u16*)p)[i]);
}

// dtype detector (insurance): flag=1 means inputs are f32 (expected)
__global__ void detect_dtype(const u16* __restrict__ X, int* __restrict__ flag) {
  __shared__ int cnt;
  if (threadIdx.x == 0) cnt = 0;
  __syncthreads();
  int sane = 0;
#pragma unroll
  for (int j = 0; j < 16; ++j) {
    u16 u = X[(threadIdx.x * 16 + j) * 2];
    int e = (u >> 7) & 0xff;
    if (u == 0 || (e >= 112 && e <= 142)) sane++;
  }
  atomicAdd(&cnt, sane);
  __syncthreads();
  if (threadIdx.x == 0) *flag = (cnt < 3072) ? 1 : 0;
}

// split X to hi/lo fp16 + f32 copy
__global__ __launch_bounds__(256) void split_input3(
    const void* __restrict__ in, h16* __restrict__ hi, h16* __restrict__ lo,
    float* __restrict__ f32out, int n, const int* __restrict__ flag) {
  int f = *flag;
  int stride = gridDim.x * 256;
  for (int i = blockIdx.x * 256 + threadIdx.x; i < n; i += stride) {
    float x = cvt_in(in, i, f);
    h16 h = (h16)x;
    hi[i] = h;
    lo[i] = (h16)(x - (float)h);
    if (f32out) f32out[i] = x;
  }
}

// split L (262144 elems, blocks 0..255) and W (65536 elems, blocks 256..319)
__global__ __launch_bounds__(256) void split_LW(
    const void* __restrict__ Lin, h16* __restrict__ Lhi, h16* __restrict__ Llo,
    const void* __restrict__ Win, h16* __restrict__ Whi, h16* __restrict__ Wlo,
    const int* __restrict__ flag) {
  int f = *flag;
  int tid = threadIdx.x;
  if (blockIdx.x < 256) {
#pragma unroll
    for (int j = 0; j < 4; ++j) {
      int i = blockIdx.x * 1024 + j * 256 + tid;
      float x = cvt_in(Lin, i, f);
      h16 h = (h16)x;
      Lhi[i] = h;
      Llo[i] = (h16)(x - (float)h);
    }
  } else {
    int b = blockIdx.x - 256;
#pragma unroll
    for (int j = 0; j < 4; ++j) {
      int i = b * 1024 + j * 256 + tid;
      float x = cvt_in(Win, i, f);
      h16 h = (h16)x;
      Whi[i] = h;
      Wlo[i] = (h16)(x - (float)h);
    }
  }
}

// split f32 buffer to hi/lo fp16
__global__ __launch_bounds__(256) void split_f32h(
    const float* __restrict__ in, h16* __restrict__ hi, h16* __restrict__ lo,
    int n) {
  int stride = gridDim.x * 256;
  for (int i = blockIdx.x * 256 + threadIdx.x; i < n; i += stride) {
    float x = in[i];
    h16 h = (h16)x;
    hi[i] = h;
    lo[i] = (h16)(x - (float)h);
  }
}

// theta+bias conv + scalars, one block of 1024 threads
__global__ __launch_bounds__(1024) void prep_small(
    const void* __restrict__ theta, const void* __restrict__ bpin,
    const void* __restrict__ alpha, const void* __restrict__ rho_raw,
    float* __restrict__ thetaf, float* __restrict__ biasf,
    float* __restrict__ scal, const int* __restrict__ flag) {
  int f = *flag;
  int tid = threadIdx.x;
  if (tid < 768)
    thetaf[tid] = cvt_in(theta, tid, f);
  else
    biasf[tid - 768] = cvt_in(bpin, tid - 768, f);
  if (tid == 0) {
    float a[4], e[4], m = -1e30f, s = 0.f;
    for (int i = 0; i < 4; ++i) {
      a[i] = cvt_in(alpha, i, f);
      m = fmaxf(m, a[i]);
    }
    for (int i = 0; i < 4; ++i) { e[i] = expf(a[i] - m); s += e[i]; }
    for (int i = 0; i < 4; ++i) scal[i] = e[i] / s;
    float rr = cvt_in(rho_raw, 0, f);
    scal[4] = 1.f / (1.f + expf(-rr));
  }
}

// ---------------------------------------------------------------------------
// Split-precision NT GEMM (64x64 tile): C = alpha*(Ah Bh^T + Ah Bl^T + Al Bh^T)
// ---------------------------------------------------------------------------
template <bool BIAS>
__global__ __launch_bounds__(256) void gemm3_nt(
    const h16* __restrict__ Ah, const h16* __restrict__ Al,
    const h16* __restrict__ Bh, const h16* __restrict__ Bl,
    float* __restrict__ C, const float* __restrict__ bias, float alpha,
    int M, int Nc, int Kd, long batchA, long batchB, long batchC) {
  const h16* Abh = Ah + (size_t)blockIdx.z * batchA;
  const h16* Abl = Al + (size_t)blockIdx.z * batchA;
  const h16* Bbh = Bh + (size_t)blockIdx.z * batchB;
  const h16* Bbl = Bl + (size_t)blockIdx.z * batchB;
  float* Cb = C + (size_t)blockIdx.z * batchC;
  int bn = blockIdx.x, bm = blockIdx.y;
  int tid = threadIdx.x;
  int wid = tid >> 6, lane = tid & 63;
  __shared__ h16 Ash[64 * 40], Asl[64 * 40], Bsh[64 * 40], Bsl[64 * 40];
  f32x4 acc00 = {}, acc01 = {}, acc10 = {}, acc11 = {};
  int lr = tid >> 2;
  int lc = (tid & 3) << 3;
  size_t aoff = (size_t)(bm * 64 + lr) * Kd + lc;
  size_t boff = (size_t)(bn * 64 + lr) * Kd + lc;
  int wm = (wid & 1) * 32, wn = (wid >> 1) * 32;
  int fr = lane & 15;
  int fc = (lane >> 4) << 3;
  for (int k0 = 0; k0 < Kd; k0 += 32) {
    uint4 avh = *(const uint4*)(Abh + aoff + k0);
    uint4 avl = *(const uint4*)(Abl + aoff + k0);
    uint4 bvh = *(const uint4*)(Bbh + boff + k0);
    uint4 bvl = *(const uint4*)(Bbl + boff + k0);
    __syncthreads();
    *(uint4*)(Ash + lr * 40 + lc) = avh;
    *(uint4*)(Asl + lr * 40 + lc) = avl;
    *(uint4*)(Bsh + lr * 40 + lc) = bvh;
    *(uint4*)(Bsl + lr * 40 + lc) = bvl;
    __syncthreads();
    h16x8 a0h = *(const h16x8*)(Ash + (wm + fr) * 40 + fc);
    h16x8 a1h = *(const h16x8*)(Ash + (wm + 16 + fr) * 40 + fc);
    h16x8 b0h = *(const h16x8*)(Bsh + (wn + fr) * 40 + fc);
    h16x8 b1h = *(const h16x8*)(Bsh + (wn + 16 + fr) * 40 + fc);
    h16x8 a0l = *(const h16x8*)(Asl + (wm + fr) * 40 + fc);
    h16x8 a1l = *(const h16x8*)(Asl + (wm + 16 + fr) * 40 + fc);
    h16x8 b0l = *(const h16x8*)(Bsl + (wn + fr) * 40 + fc);
    h16x8 b1l = *(const h16x8*)(Bsl + (wn + 16 + fr) * 40 + fc);
    acc00 = mfma16(a0h, b0h, acc00);
    acc01 = mfma16(a0h, b1h, acc01);
    acc10 = mfma16(a1h, b0h, acc10);
    acc11 = mfma16(a1h, b1h, acc11);
    acc00 = mfma16(a0h, b0l, acc00);
    acc01 = mfma16(a0h, b1l, acc01);
    acc10 = mfma16(a1h, b0l, acc10);
    acc11 = mfma16(a1h, b1l, acc11);
    acc00 = mfma16(a0l, b0h, acc00);
    acc01 = mfma16(a0l, b1h, acc01);
    acc10 = mfma16(a1l, b0h, acc10);
    acc11 = mfma16(a1l, b1h, acc11);
  }
  int crow = (lane >> 4) << 2;
  int ccol = lane & 15;
  f32x4 accs[2][2] = {{acc00, acc01}, {acc10, acc11}};
#pragma unroll
  for (int i = 0; i < 2; ++i)
#pragma unroll
    for (int j = 0; j < 2; ++j) {
      int r0 = bm * 64 + wm + 16 * i + crow;
      int c0 = bn * 64 + wn + 16 * j + ccol;
#pragma unroll
      for (int rg = 0; rg < 4; ++rg) {
        float v = accs[i][j][rg] * alpha;
        if constexpr (BIAS) v += bias[c0];
        Cb[(size_t)(r0 + rg) * Nc + c0] = v;
      }
    }
}

// ---------------------------------------------------------------------------
// Split-precision NT GEMM, 128x128 tile, global_load_lds staging, XOR swizzle.
// ---------------------------------------------------------------------------
__global__ __launch_bounds__(256) void gemm3_big(
    const h16* __restrict__ Ah, const h16* __restrict__ Al,
    const h16* __restrict__ Bh, const h16* __restrict__ Bl,
    float* __restrict__ C, float alpha, int M, int Nc, int Kd) {
  __shared__ h16 sAh[128 * 32], sAl[128 * 32], sBh[128 * 32], sBl[128 * 32];
  int tid = threadIdx.x, wid = tid >> 6, lane = tid & 63;
  int bm = blockIdx.y, bn = blockIdx.x;
  int srow = 32 * wid + (lane >> 2);
  int scnk = lane & 3;
  int fr = lane & 15, fcc = lane >> 4;
  f32x4 acc[4][4] = {};
  const h16* gA[2] = {Ah, Al};
  const h16* gB[2] = {Bh, Bl};
  h16* sA[2] = {sAh, sAl};
  h16* sB[2] = {sBh, sBl};
  int wm = (wid & 1) * 64, wn = (wid >> 1) * 64;
  for (int k0 = 0; k0 < Kd; k0 += 32) {
    __syncthreads();
#pragma unroll
    for (int h = 0; h < 2; ++h) {
      int r = srow + 16 * h;
      int cs = scnk ^ ((r >> 1) & 3);
      size_t goffA = (size_t)(bm * 128 + r) * Kd + k0 + cs * 8;
      size_t goffB = (size_t)(bn * 128 + r) * Kd + k0 + cs * 8;
      int loff = (32 * wid + 16 * h) * 32;
#pragma unroll
      for (int p = 0; p < 2; ++p) {
        gl_lds16(gA[p] + goffA, sA[p] + loff);
        gl_lds16(gB[p] + goffB, sB[p] + loff);
      }
    }
    __syncthreads();
    h16x8 fa[2][4], fb[2][4];
#pragma unroll
    for (int i = 0; i < 4; ++i) {
      int ra = wm + 16 * i + fr;
      int ca = (fcc ^ ((ra >> 1) & 3)) * 8;
      fa[0][i] = *(const h16x8*)(sAh + ra * 32 + ca);
      fa[1][i] = *(const h16x8*)(sAl + ra * 32 + ca);
      int rb = wn + 16 * i + fr;
      int cb = (fcc ^ ((rb >> 1) & 3)) * 8;
      fb[0][i] = *(const h16x8*)(sBh + rb * 32 + cb);
      fb[1][i] = *(const h16x8*)(sBl + rb * 32 + cb);
    }
#pragma unroll
    for (int i = 0; i < 4; ++i)
#pragma unroll
      for (int j = 0; j < 4; ++j) {
        acc[i][j] = mfma16(fa[0][i], fb[0][j], acc[i][j]);
        acc[i][j] = mfma16(fa[0][i], fb[1][j], acc[i][j]);
        acc[i][j] = mfma16(fa[1][i], fb[0][j], acc[i][j]);
      }
  }
  int crow = (lane >> 4) << 2, ccol = lane & 15;
#pragma unroll
  for (int i = 0; i < 4; ++i)
#pragma unroll
    for (int j = 0; j < 4; ++j) {
      int r0 = bm * 128 + wm + 16 * i + crow;
      int c0 = bn * 128 + wn + 16 * j + ccol;
#pragma unroll
      for (int rg = 0; rg < 4; ++rg)
        C[(size_t)(r0 + rg) * Nc + c0] = acc[i][j][rg] * alpha;
    }
}

// ---------------------------------------------------------------------------
// fp16 NT GEMM for all 4 heads' E@X, K-split: z = head*4 + kslice (Kc=1024).
// Writes f32 partials Cpart[z][4096][256].
// ---------------------------------------------------------------------------
__global__ __launch_bounds__(256) void gemm_ks4(
    const h16* __restrict__ Eall, const h16* __restrict__ B,
    float* __restrict__ Cpart) {
  __shared__ h16 sA[128 * 32], sB[128 * 32];
  int tid = threadIdx.x, wid = tid >> 6, lane = tid & 63;
  int bm = blockIdx.y, bn = blockIdx.x, zz = blockIdx.z;
  int head = zz >> 2, kz = zz & 3;
  const h16* A = Eall + (size_t)head * 4096 * 4096;
  int kbase = kz * 1024;
  int srow = 32 * wid + (lane >> 2);
  int scnk = lane & 3;
  int fr = lane & 15, fcc = lane >> 4;
  f32x4 acc[4][4] = {};
  int wm = (wid & 1) * 64, wn = (wid >> 1) * 64;
  for (int k0 = 0; k0 < 1024; k0 += 32) {
    __syncthreads();
#pragma unroll
    for (int h = 0; h < 2; ++h) {
      int r = srow + 16 * h;
      int cs = scnk ^ ((r >> 1) & 3);
      size_t goffA = (size_t)(bm * 128 + r) * 4096 + kbase + k0 + cs * 8;
      size_t goffB = (size_t)(bn * 128 + r) * 4096 + kbase + k0 + cs * 8;
      int loff = (32 * wid + 16 * h) * 32;
      gl_lds16(A + goffA, sA + loff);
      gl_lds16(B + goffB, sB + loff);
    }
    __syncthreads();
    h16x8 fa[4], fb[4];
#pragma unroll
    for (int i = 0; i < 4; ++i) {
      int ra = wm + 16 * i + fr;
      int ca = (fcc ^ ((ra >> 1) & 3)) * 8;
      fa[i] = *(const h16x8*)(sA + ra * 32 + ca);
      int rb = wn + 16 * i + fr;
      int cb = (fcc ^ ((rb >> 1) & 3)) * 8;
      fb[i] = *(const h16x8*)(sB + rb * 32 + cb);
    }
#pragma unroll
    for (int i = 0; i < 4; ++i)
#pragma unroll
      for (int j = 0; j < 4; ++j)
        acc[i][j] = mfma16(fa[i], fb[j], acc[i][j]);
  }
  float* Cp = Cpart + (size_t)zz * 4096 * 256;
  int crow = (lane >> 4) << 2, ccol = lane & 15;
#pragma unroll
  for (int i = 0; i < 4; ++i)
#pragma unroll
    for (int j = 0; j < 4; ++j) {
      int r0 = bm * 128 + wm + 16 * i + crow;
      int c0 = bn * 128 + wn + 16 * j + ccol;
#pragma unroll
      for (int rg = 0; rg < 4; ++rg)
        Cp[(size_t)(r0 + rg) * 256 + c0] = acc[i][j][rg];
    }
}

// Zk = sum_k scal[k] * rowSinv[k][row] * sum_{z in head k} Cpart[z]
__global__ __launch_bounds__(256) void ks_reduce4(
    const float* __restrict__ Cpart, const float* __restrict__ scal,
    const float* __restrict__ rowSinv, float* __restrict__ Zk) {
  int i = (blockIdx.x * 256 + threadIdx.x) * 4;  // grid 1024
  int row = i >> 8;
  float4 out = {0.f, 0.f, 0.f, 0.f};
#pragma unroll
  for (int k = 0; k < 4; ++k) {
    float4 s = {0.f, 0.f, 0.f, 0.f};
#pragma unroll
    for (int z = 0; z < 4; ++z) {
      float4 p = *(const float4*)(Cpart + (size_t)(k * 4 + z) * 4096 * 256 + i);
      s.x += p.x; s.y += p.y; s.z += p.z; s.w += p.w;
    }
    float sc = scal[k] * rowSinv[k * 4096 + row];
    out.x += sc * s.x; out.y += sc * s.y;
    out.z += sc * s.z; out.w += sc * s.w;
  }
  *(float4*)(Zk + i) = out;
}

// 16-bit transpose
__global__ __launch_bounds__(256) void transpose16(
    const u16* __restrict__ in, u16* __restrict__ out, int rows, int cols) {
  __shared__ u16 t[32][33];
  const u16* ib = in + (size_t)blockIdx.z * rows * cols;
  u16* ob = out + (size_t)blockIdx.z * rows * cols;
  int r0 = blockIdx.x * 32, c0 = blockIdx.y * 32;
  int tx = threadIdx.x & 31, ty = threadIdx.x >> 5;
#pragma unroll
  for (int i = 0; i < 32; i += 8)
    t[ty + i][tx] = ib[(size_t)(r0 + ty + i) * cols + c0 + tx];
  __syncthreads();
#pragma unroll
  for (int i = 0; i < 32; i += 8)
    ob[(size_t)(c0 + ty + i) * rows + r0 + tx] = t[tx][ty + i];
}

// ---------------------------------------------------------------------------
// fused per-row (one wave per row): max -> threshold T -> exp/E-write +
// candidate push -> exact jax-tiebreak top-16 from candidates
// ---------------------------------------------------------------------------
__global__ __launch_bounds__(256) void row_softmax_topk(
    const float* __restrict__ A, float* __restrict__ topv,
    int* __restrict__ topi, h16* __restrict__ E, float* __restrict__ rowSinvK,
    int khead) {
  __shared__ u64 candK[4][256];
  __shared__ int candN[4];
  int wid = threadIdx.x >> 6, lane = threadIdx.x & 63;
  int row = blockIdx.x * 4 + wid;
  const float* arow = A + ((size_t)row << 12);
  if (lane == 0) candN[wid] = 0;
  __syncthreads();
  float lm = -INFINITY;
#pragma unroll
  for (int t = 0; t < 16; ++t) {
    float4 v = *(const float4*)(arow + (t << 8) + (lane << 2));
    lm = fmaxf(lm, fmaxf(fmaxf(v.x, v.y), fmaxf(v.z, v.w)));
  }
  float m = lm;
#pragma unroll
  for (int off = 32; off; off >>= 1) m = fmaxf(m, __shfl_xor(m, off));
  u64 lk = ((u64)fkey(lm) << 32) | (unsigned)lane;
  float T = 0.f;
  for (int r = 0; r < 16; ++r) {
    u64 k2 = wave_max_u64(lk);
    if (lk == k2) lk = 0;
    if (r == 15) T = unfkey((unsigned)(k2 >> 32));
  }
  h16* erow = E + ((size_t)row << 12);
  int* cn = &candN[wid];
  u64* ck = candK[wid];
  float s = 0.f;
  for (int t = 0; t < 16; ++t) {
    int c = (t << 8) + (lane << 2);
    float4 v = *(const float4*)(arow + c);
    float e0 = __expf(v.x - m), e1 = __expf(v.y - m);
    float e2 = __expf(v.z - m), e3 = __expf(v.w - m);
    s += (e0 + e1) + (e2 + e3);
    h16x4 hv = {(h16)e0, (h16)e1, (h16)e2, (h16)e3};
    *(h16x4*)(erow + c) = hv;
    if (v.x >= T) {
      int sl = atomicAdd(cn, 1);
      if (sl < 256) ck[sl] = ((u64)fkey(v.x) << 32) | (unsigned)(~(unsigned)c);
    }
    if (v.y >= T) {
      int sl = atomicAdd(cn, 1);
      if (sl < 256) ck[sl] = ((u64)fkey(v.y) << 32) | (unsigned)(~(unsigned)(c + 1));
    }
    if (v.z >= T) {
      int sl = atomicAdd(cn, 1);
      if (sl < 256) ck[sl] = ((u64)fkey(v.z) << 32) | (unsigned)(~(unsigned)(c + 2));
    }
    if (v.w >= T) {
      int sl = atomicAdd(cn, 1);
      if (sl < 256) ck[sl] = ((u64)fkey(v.w) << 32) | (unsigned)(~(unsigned)(c + 3));
    }
  }
#pragma unroll
  for (int off = 32; off; off >>= 1) s += __shfl_xor(s, off);
  if (lane == 0) rowSinvK[row] = 1.f / s;
  __syncthreads();
  int cnt = min(*cn, 256);
  u64 loc[4] = {0ull, 0ull, 0ull, 0ull};
  int nl = 0;
  for (int j = lane; j < cnt; j += 64)
    if (nl < 4) loc[nl++] = ck[j];
#define CSW(a, b)                     \
  {                                   \
    if (loc[b] > loc[a]) {            \
      u64 tt = loc[a];                \
      loc[a] = loc[b];                \
      loc[b] = tt;                    \
    }                                 \
  }
  CSW(0, 1) CSW(2, 3) CSW(0, 2) CSW(1, 3) CSW(1, 2)
#undef CSW
  float myv = 0.f;
  int myi = 0;
  float sum16 = 0.f;
  for (int r = 0; r < 16; ++r) {
    u64 key = loc[0];
    u64 k2 = wave_max_u64(key);
    float wv = unfkey((unsigned)(k2 >> 32));
    int wi = (int)(~(unsigned)(k2 & 0xffffffffu));
    if (key == k2 && key != 0ull) {
      loc[0] = loc[1];
      loc[1] = loc[2];
      loc[2] = loc[3];
      loc[3] = 0ull;
    }
    sum16 += expf(wv - m);
    if (r == lane) { myv = wv; myi = wi; }
  }
  if (lane < 16) {
    size_t o = (((size_t)khead << 12) + row) * 16 + lane;
    topv[o] = expf(myv - m) / (sum16 + 1e-9f * s);
    topi[o] = myi;
  }
}

// ---------------------------------------------------------------------------
// sparse hypergraph build — atomic-free two-level LDS histogram (+DeIS fused)
// ---------------------------------------------------------------------------
__global__ __launch_bounds__(256) void hist_part(
    const float* __restrict__ topv, const int* __restrict__ topi,
    int* __restrict__ pCnt, float* __restrict__ pDv,
    float* __restrict__ DeIS) {
  __shared__ int lc[4096];
  __shared__ float ld[4096];
  int tid = threadIdx.x, b = blockIdx.x;  // grid 64
  for (int j = tid; j < 4096; j += 256) { lc[j] = 0; ld[j] = 0.f; }
  __syncthreads();
  int base = b * 4096;
#pragma unroll
  for (int j = 0; j < 16; ++j) {
    int t = base + j * 256 + tid;
    atomicAdd(&lc[topi[t]], 1);
    atomicAdd(&ld[topi[t]], topv[t]);
  }
  __syncthreads();
  for (int j = tid; j < 4096; j += 256) {
    pCnt[base + j] = lc[j];
    pDv[base + j] = ld[j];
  }
  // fused per-edge DeIS (e = b*256 + tid covers 16384 edges)
  int e = b * 256 + tid;
  const float4* p = (const float4*)(topv + ((size_t)e << 4));
  float4 a = p[0], bb = p[1], c = p[2], d = p[3];
  float s = ((a.x + a.y) + (a.z + a.w)) + ((bb.x + bb.y) + (bb.z + bb.w)) +
            ((c.x + c.y) + (c.z + c.w)) + ((d.x + d.y) + (d.z + d.w));
  DeIS[e] = 1.0f / sqrtf(s + 1e-9f);
}

// per-bin reduce over 64 blocks: cnt, Dvis, block prefix; + fused v0 init
__global__ __launch_bounds__(256) void col_scan(
    const int* __restrict__ pCnt, const float* __restrict__ pDv,
    int* __restrict__ cnt, float* __restrict__ Dvis,
    int* __restrict__ blockBase, float* __restrict__ v0) {
  int i = blockIdx.x * 256 + threadIdx.x;  // grid 16 -> 4096
  int run = 0;
  float dv = 0.f;
#pragma unroll
  for (int b = 0; b < 64; ++b) {
    blockBase[b * 4096 + i] = run;
    run += pCnt[b * 4096 + i];
    dv += pDv[b * 4096 + i];
  }
  cnt[i] = run;
  Dvis[i] = sqrtf(1.0f / (dv + 1e-9f));
  // fused v0: bit-exact jax.random.normal(key(1), (4096,1), f32)
  {
    int tid = i;
    unsigned j = (unsigned)(tid & 2047);
    unsigned x0 = j, x1 = j + 2048u;
    const unsigned ks0 = 0u, ks1 = 1u, ks2 = 0x1BD11BDAu;
#define TF_R(r)                                \
    {                                          \
      x0 += x1;                                \
      x1 = (x1 << (r)) | (x1 >> (32 - (r)));   \
      x1 ^= x0;                                \
    }
    x0 += ks0; x1 += ks1;
    TF_R(13) TF_R(15) TF_R(26) TF_R(6)  x0 += ks1; x1 += ks2 + 1u;
    TF_R(17) TF_R(29) TF_R(16) TF_R(24) x0 += ks2; x1 += ks0 + 2u;
    TF_R(13) TF_R(15) TF_R(26) TF_R(6)  x0 += ks0; x1 += ks1 + 3u;
    TF_R(17) TF_R(29) TF_R(16) TF_R(24) x0 += ks1; x1 += ks2 + 4u;
    TF_R(13) TF_R(15) TF_R(26) TF_R(6)  x0 += ks2; x1 += ks0 + 5u;
#undef TF_R
    unsigned bits = (tid < 2048) ? x0 : x1;
    float u01 = __uint_as_float((bits >> 9) | 0x3f800000u) - 1.0f;
    const float lo = -0.99999994f;
    float u = fmaxf(lo, u01 * 2.0f + lo);
    float w = -log1pf(-u * u);
    float p;
    if (w < 5.0f) {
      float t = w - 2.5f;
      p = 2.81022636e-08f;
      p = 3.43273939e-07f + p * t;
      p = -3.5233877e-06f + p * t;
      p = -4.39150654e-06f + p * t;
      p = 0.00021858087f + p * t;
      p = -0.00125372503f + p * t;
      p = -0.00417768164f + p * t;
      p = 0.246640727f + p * t;
      p = 1.50140941f + p * t;
    } else {
      float t = sqrtf(w) - 3.0f;
      p = -0.000200214257f;
      p = 0.000100950558f + p * t;
      p = 0.00134934322f + p * t;
      p = -0.00367342844f + p * t;
      p = 0.00573950773f + p * t;
      p = -0.0076224613f + p * t;
      p = 0.00943887047f + p * t;
      p = 1.00167406f + p * t;
      p = 2.83297682f + p * t;
    }
    v0[tid] = 1.41421354f * (p * u);
  }
}

// exclusive scan of cnt[4096] -> rowptr[4097]
__global__ __launch_bounds__(256) void scan_rowptr(const int* __restrict__ cnt,
                                                   int* __restrict__ rowptr) {
  __shared__ int part[256];
  int tid = threadIdx.x;
  int base = tid * 16;
  int loc[16];
  int s = 0;
#pragma unroll
  for (int j = 0; j < 16; ++j) { loc[j] = s; s += cnt[base + j]; }
  part[tid] = s;
  __syncthreads();
  for (int off = 1; off < 256; off <<= 1) {
    int v = (tid >= off) ? part[tid - off] : 0;
    __syncthreads();
    part[tid] += v;
    __syncthreads();
  }
  int pre = (tid == 0) ? 0 : part[tid - 1];
#pragma unroll
  for (int j = 0; j < 16; ++j) rowptr[base + j] = pre + loc[j];
  if (tid == 255) rowptr[4096] = part[255];
}

// fill cvals + CSR transpose via LDS cursors (no global atomics)
__global__ __launch_bounds__(256) void csr_fill3(
    const float* __restrict__ topv, const int* __restrict__ topi,
    const float* __restrict__ Dvis, const float* __restrict__ DeIS,
    const int* __restrict__ rowptr, const int* __restrict__ blockBase,
    float* __restrict__ cvals, int* __restrict__ colE,
    float* __restrict__ cvalR) {
  __shared__ int lcur[4096];
  int tid = threadIdx.x, b = blockIdx.x;  // grid 64
  int base = b * 4096;
  for (int j = tid; j < 4096; j += 256)
    lcur[j] = rowptr[j] + blockBase[base + j];
  __syncthreads();
#pragma unroll
  for (int j = 0; j < 16; ++j) {
    int t = base + j * 256 + tid;
    int i = topi[t];
    int e = t >> 4;
    float c = Dvis[i] * topv[t] * DeIS[e];
    cvals[t] = c;
    int slot = atomicAdd(&lcur[i], 1);
    colE[slot] = e;
    cvalR[slot] = c;
  }
}

// g[e] = sum_p c[e,p] * v[idx[e,p]]
__global__ __launch_bounds__(256) void spmv_edge(
    const float* __restrict__ cvals, const int* __restrict__ topi,
    const float* __restrict__ v, float* __restrict__ g) {
  int e = blockIdx.x * 256 + threadIdx.x;  // grid 64
  float acc = 0.f;
#pragma unroll
  for (int p = 0; p < 16; ++p)
    acc += cvals[e * 16 + p] * v[topi[e * 16 + p]];
  g[e] = acc;
}

// vout[i] = vin[i] - sum_{j in row i} cvalR[j]*g[colE[j]]
__global__ __launch_bounds__(256) void spmv_row(
    const int* __restrict__ rowptr, const int* __restrict__ colE,
    const float* __restrict__ cvalR, const float* __restrict__ g,
    const float* __restrict__ vin, float* __restrict__ vout) {
  int wid = threadIdx.x >> 6, lane = threadIdx.x & 63;
  int row = blockIdx.x * 4 + wid;  // grid 1024
  int s = rowptr[row], e = rowptr[row + 1];
  float acc = 0.f;
  for (int j = s + lane; j < e; j += 64) acc += cvalR[j] * g[colE[j]];
#pragma unroll
  for (int off = 32; off; off >>= 1) acc += __shfl_xor(acc, off);
  if (lane == 0) vout[row] = vin[row] - acc;
}

// lam = clip((w5.w6)/(w5.w5), 1e-3) -> scal[5]
__global__ __launch_bounds__(256) void pi_dots(const float* __restrict__ w5,
                                               const float* __restrict__ w6,
                                               float* __restrict__ scal) {
  __shared__ float r1[256], r2[256];
  int tid = threadIdx.x;
  float a = 0.f, b = 0.f;
  for (int i = tid; i < 4096; i += 256) {
    float x = w5[i];
    a += x * x;
    b += x * w6[i];
  }
  r1[tid] = a; r2[tid] = b;
  __syncthreads();
  for (int off = 128; off; off >>= 1) {
    if (tid < off) { r1[tid] += r1[tid + off]; r2[tid] += r2[tid + off]; }
    __syncthreads();
  }
  if (tid == 0) scal[5] = fmaxf(r2[0] / r1[0], 1e-3f);
}

// G[e,:] = sum_p c[e,p] * M[idx[e,p],:]  — MLP-unrolled
__global__ __launch_bounds__(256) void spmm_edge(
    const float* __restrict__ cvals, const int* __restrict__ topi,
    const float* __restrict__ M, float* __restrict__ G) {
  int wid = threadIdx.x >> 6, lane = threadIdx.x & 63;
  int e = blockIdx.x * 4 + wid;  // grid 4096
  int cb = lane << 2;
  const float* cv = cvals + ((size_t)e << 4);
  const int* ti = topi + ((size_t)e << 4);
  float cc[16];
  int ix[16];
#pragma unroll
  for (int p = 0; p < 16; ++p) { cc[p] = cv[p]; ix[p] = ti[p]; }
  float4 acc[4] = {};
#pragma unroll
  for (int h = 0; h < 2; ++h) {
    float4 g[8];
#pragma unroll
    for (int p = 0; p < 8; ++p)
      g[p] = *(const float4*)(M + ((size_t)ix[h * 8 + p] << 8) + cb);
#pragma unroll
    for (int p = 0; p < 8; ++p) {
      float c = cc[h * 8 + p];
      float4 gg = g[p];
      int a = p & 3;
      acc[a].x += c * gg.x; acc[a].y += c * gg.y;
      acc[a].z += c * gg.z; acc[a].w += c * gg.w;
    }
  }
  float4 r;
  r.x = (acc[0].x + acc[1].x) + (acc[2].x + acc[3].x);
  r.y = (acc[0].y + acc[1].y) + (acc[2].y + acc[3].y);
  r.z = (acc[0].z + acc[1].z) + (acc[2].z + acc[3].z);
  r.w = (acc[0].w + acc[1].w) + (acc[2].w + acc[3].w);
  *(float4*)(G + ((size_t)e << 8) + cb) = r;
}

// Z = S_norm @ M via CSR rows, 8-wide MLP unroll, with fused epilogues:
// MODE 1: T1 = (c1-1)*Xf - c1*Z          (writes T1 f32)
// MODE 2: full cheb/elu/mix epilogue     (writes Zmh/Zml fp16 split)
template <int MODE>
__global__ __launch_bounds__(256) void spmm_row_ep(
    const int* __restrict__ rowptr, const int* __restrict__ colE,
    const float* __restrict__ cvalR, const float* __restrict__ G,
    const float* __restrict__ Xf, float* __restrict__ T1,
    const float* __restrict__ Zk, const float* __restrict__ thetaf,
    const float* __restrict__ scal, h16* __restrict__ Zmh,
    h16* __restrict__ Zml) {
  int wid = threadIdx.x >> 6, lane = threadIdx.x & 63;
  int row = blockIdx.x * 4 + wid;  // grid 1024
  int cb = lane << 2;
  int s = rowptr[row], e = rowptr[row + 1];
  float4 acc[4] = {};
  int j = s;
  for (; j + 8 <= e; j += 8) {
    int ix[8];
    float cc[8];
#pragma unroll
    for (int t = 0; t < 8; ++t) { ix[t] = colE[j + t]; cc[t] = cvalR[j + t]; }
    float4 g[8];
#pragma unroll
    for (int t = 0; t < 8; ++t)
      g[t] = *(const float4*)(G + ((size_t)ix[t] << 8) + cb);
#pragma unroll
    for (int t = 0; t < 8; ++t) {
      float c = cc[t];
      float4 gg = g[t];
      int a = t & 3;
      acc[a].x += c * gg.x; acc[a].y += c * gg.y;
      acc[a].z += c * gg.z; acc[a].w += c * gg.w;
    }
  }
  for (; j < e; ++j) {
    float c = cvalR[j];
    float4 gg = *(const float4*)(G + ((size_t)colE[j] << 8) + cb);
    acc[0].x += c * gg.x; acc[0].y += c * gg.y;
    acc[0].z += c * gg.z; acc[0].w += c * gg.w;
  }
  float4 z;
  z.x = (acc[0].x + acc[1].x) + (acc[2].x + acc[3].x);
  z.y = (acc[0].y + acc[1].y) + (acc[2].y + acc[3].y);
  z.z = (acc[0].z + acc[1].z) + (acc[2].z + acc[3].z);
  z.w = (acc[0].w + acc[1].w) + (acc[2].w + acc[3].w);
  size_t o = ((size_t)row << 8) + cb;
  float c1 = 2.0f / scal[5];
  float4 x = *(const float4*)(Xf + o);
  if constexpr (MODE == 1) {
    float4 t1;
    t1.x = (c1 - 1.0f) * x.x - c1 * z.x;
    t1.y = (c1 - 1.0f) * x.y - c1 * z.y;
    t1.z = (c1 - 1.0f) * x.z - c1 * z.z;
    t1.w = (c1 - 1.0f) * x.w - c1 * z.w;
    *(float4*)(T1 + o) = t1;
  } else {
    float rho = scal[4];
    float4 t1 = *(const float4*)(T1 + o);
    float4 zk = *(const float4*)(Zk + o);
    h16x4 hh, hl;
#pragma unroll
    for (int q = 0; q < 4; ++q) {
      float xv = (&x.x)[q], t1v = (&t1.x)[q], zv = (&z.x)[q], zkv = (&zk.x)[q];
      int d = cb + q;
      float t2 = 2.0f * ((c1 - 1.0f) * t1v - c1 * zv) - xv;
      float oo = xv * thetaf[d] + t1v * thetaf[256 + d] + t2 * thetaf[512 + d];
      float zs = oo > 0.0f ? oo : expm1f(oo);
      float zm = rho * zs + (1.0f - rho) * zkv;
      h16 h = (h16)zm;
      hh[q] = h;
      hl[q] = (h16)(zm - (float)h);
    }
    *(h16x4*)(Zmh + o) = hh;
    *(h16x4*)(Zml + o) = hl;
  }
}

// ---------------------------------------------------------------------------
extern "C" void kernel_launch(void* const* d_in, const int* in_sizes, int n_in,
                              void* d_out, int out_size, void* d_ws,
                              size_t ws_size, hipStream_t stream) {
  (void)in_sizes; (void)n_in; (void)out_size;
  const void* Xin = d_in[0];
  const void* Lin = d_in[1];
  const void* alpha = d_in[2];
  const void* theta = d_in[3];
  const void* rho_raw = d_in[4];
  const void* Wpin = d_in[5];
  const void* bpin = d_in[6];
  float* out = (float*)d_out;

  char* base = (char*)d_ws;
  size_t off = 0;
  auto alloc = [&](size_t bytes) -> char* {
    char* p = base + off;
    off += (bytes + 255) & ~(size_t)255;
    return p;
  };
  float* Abuf = (float*)alloc((size_t)4096 * 4096 * 4);   // A; 16 ks-partials; G
  h16* Eall = (h16*)alloc((size_t)4 * 4096 * 4096 * 2);   // 4 E planes (Yf alias)
  h16* Yhi = (h16*)alloc((size_t)4 * 4096 * 256 * 2);
  h16* Ylo = (h16*)alloc((size_t)4 * 4096 * 256 * 2);
  h16* Xhi = (h16*)alloc((size_t)4096 * 256 * 2);
  h16* Xlo = (h16*)alloc((size_t)4096 * 256 * 2);
  float* Xf = (float*)alloc((size_t)4096 * 256 * 4);
  h16* XT = (h16*)alloc((size_t)256 * 4096 * 2);
  h16* Lhi = (h16*)alloc((size_t)4 * 256 * 256 * 2);
  h16* Llo = (h16*)alloc((size_t)4 * 256 * 256 * 2);
  h16* LThi = (h16*)alloc((size_t)4 * 256 * 256 * 2);
  h16* LTlo = (h16*)alloc((size_t)4 * 256 * 256 * 2);
  h16* Whi = (h16*)alloc((size_t)256 * 256 * 2);
  h16* Wlo = (h16*)alloc((size_t)256 * 256 * 2);
  float* Zk = (float*)alloc((size_t)4096 * 256 * 4);
  float* T1 = (float*)alloc((size_t)4096 * 256 * 4);
  h16* Zmh = (h16*)alloc((size_t)4096 * 256 * 2);
  h16* Zml = (h16*)alloc((size_t)4096 * 256 * 2);
  float* topv = (float*)alloc((size_t)4 * 4096 * 16 * 4);
  int* topi = (int*)alloc((size_t)4 * 4096 * 16 * 4);
  float* cvals = (float*)alloc((size_t)262144 * 4);
  int* colE = (int*)alloc((size_t)262144 * 4);
  float* cvalR = (float*)alloc((size_t)262144 * 4);
  int* pCnt = (int*)alloc((size_t)64 * 4096 * 4);
  float* pDv = (float*)alloc((size_t)64 * 4096 * 4);
  int* blockBase = (int*)alloc((size_t)64 * 4096 * 4);
  int* rowptr = (int*)alloc(4097 * 4);
  int* cnt = (int*)alloc(4096 * 4);
  float* Dvis = (float*)alloc(4096 * 4);
  float* DeIS = (float*)alloc(16384 * 4);
  float* gE = (float*)alloc(16384 * 4);
  float* wA = (float*)alloc(4096 * 4);
  float* wB = (float*)alloc(4096 * 4);
  float* rowSinv = (float*)alloc((size_t)4 * 4096 * 4);
  float* thetaf = (float*)alloc(768 * 4);
  float* biasf = (float*)alloc(256 * 4);
  float* scal = (float*)alloc(256);
  int* flag = (int*)alloc(256);
  if (off > ws_size) return;
  float* Yf = (float*)Eall;  // 16 MB alias; dead before E planes written
  float* Kpart = Abuf;       // 64 MB: 16 partial planes; A dead by then
  float* G = (float*)Abuf;   // 16 MB alias; partials dead after ks_reduce4

  detect_dtype<<<1, 256, 0, stream>>>((const u16*)Xin, flag);
  split_input3<<<1024, 256, 0, stream>>>(Xin, Xhi, Xlo, Xf, 4096 * 256, flag);
  split_LW<<<320, 256, 0, stream>>>(Lin, Lhi, Llo, Wpin, Whi, Wlo, flag);
  prep_small<<<1, 1024, 0, stream>>>(theta, bpin, alpha, rho_raw, thetaf, biasf,
                                     scal, flag);
  transpose16<<<dim3(128, 8, 1), 256, 0, stream>>>((const u16*)Xhi, (u16*)XT,
                                                   4096, 256);
  transpose16<<<dim3(8, 8, 4), 256, 0, stream>>>((const u16*)Lhi, (u16*)LThi,
                                                 256, 256);
  transpose16<<<dim3(8, 8, 4), 256, 0, stream>>>((const u16*)Llo, (u16*)LTlo,
                                                 256, 256);
  // Yf = X @ L_k (split fp16, fused), batched z=4
  gemm3_nt<false><<<dim3(4, 64, 4), 256, 0, stream>>>(
      Xhi, Xlo, LThi, LTlo, Yf, nullptr, 1.0f, 4096, 256, 256,
      0L, 256L * 256L, 4096L * 256L);
  split_f32h<<<2048, 256, 0, stream>>>(Yf, Yhi, Ylo, 4 * 4096 * 256);
  for (int k = 0; k < 4; ++k) {
    // A = Y_k @ X^T / 16 (split fp16, 128x128 tile, global_load_lds)
    gemm3_big<<<dim3(32, 32), 256, 0, stream>>>(
        Yhi + (size_t)k * 4096 * 256, Ylo + (size_t)k * 4096 * 256, Xhi, Xlo,
        Abuf, 0.0625f, 4096, 4096, 256);
    row_softmax_topk<<<1024, 256, 0, stream>>>(
        Abuf, topv, topi, Eall + (size_t)k * 4096 * 4096, rowSinv + k * 4096,
        k);
  }
  // all 4 heads' E @ X in one K-split launch (16 partial planes into Abuf)
  gemm_ks4<<<dim3(2, 32, 16), 256, 0, stream>>>(Eall, XT, Kpart);
  ks_reduce4<<<1024, 256, 0, stream>>>(Kpart, scal, rowSinv, Zk);
  // sparse hypergraph Laplacian — atomic-free two-level histogram build
  hist_part<<<64, 256, 0, stream>>>(topv, topi, pCnt, pDv, DeIS);
  col_scan<<<16, 256, 0, stream>>>(pCnt, pDv, cnt, Dvis, blockBase, wA);
  scan_rowptr<<<1, 256, 0, stream>>>(cnt, rowptr);
  csr_fill3<<<64, 256, 0, stream>>>(topv, topi, Dvis, DeIS, rowptr, blockBase,
                                    cvals, colE, cvalR);
  for (int it = 0; it < 6; ++it) {
    const float* vi = (it & 1) ? wB : wA;
    float* vo = (it & 1) ? wA : wB;
    spmv_edge<<<64, 256, 0, stream>>>(cvals, topi, vi, gE);
    spmv_row<<<1024, 256, 0, stream>>>(rowptr, colE, cvalR, gE, vi, vo);
  }
  pi_dots<<<1, 256, 0, stream>>>(wB, wA, scal);
  // SnX -> T1 (fused) ; SnT1 -> cheb/elu/mix -> Zmh/Zml (fused)
  spmm_edge<<<4096, 256, 0, stream>>>(cvals, topi, Xf, G);
  spmm_row_ep<1><<<1024, 256, 0, stream>>>(rowptr, colE, cvalR, G, Xf, T1,
                                           nullptr, thetaf, scal, nullptr,
                                           nullptr);
  spmm_edge<<<4096, 256, 0, stream>>>(cvals, topi, T1, G);
  spmm_row_ep<2><<<1024, 256, 0, stream>>>(rowptr, colE, cvalR, G, Xf, T1, Zk,
                                           thetaf, scal, Zmh, Zml);
  // out = Zmix @ proj_w^T + proj_b (split fp16, f32 out)
  gemm3_nt<true><<<dim3(4, 64, 1), 256, 0, stream>>>(
      Zmh, Zml, Whi, Wlo, out, biasf, 1.0f, 4096, 256, 256, 0L, 0L, 0L);
}

// Round 12
// 679.903 us; speedup vs baseline: 1.8888x; 1.0040x over previous
//
#include <hip/hip_runtime.h>

typedef unsigned short u16;
typedef unsigned long long u64;
typedef _Float16 h16;
typedef __attribute__((ext_vector_type(8))) _Float16 h16x8;
typedef __attribute__((ext_vector_type(4))) _Float16 h16x4;
typedef __attribute__((ext_vector_type(4))) float f32x4;

__device__ __forceinline__ float b2f(u16 u) {
  unsigned x = ((unsigned)u) << 16;
  return __uint_as_float(x);
}
__device__ __forceinline__ unsigned fkey(float f) {
  unsigned b = __float_as_uint(f);
  return (b & 0x80000000u) ? ~b : (b | 0x80000000u);
}
__device__ __forceinline__ float unfkey(unsigned u) {
  unsigned b = (u & 0x80000000u) ? (u ^ 0x80000000u) : ~u;
  return __uint_as_float(b);
}
__device__ __forceinline__ f32x4 mfma16(h16x8 a, h16x8 b, f32x4 c) {
  return __builtin_amdgcn_mfma_f32_16x16x32_f16(a, b, c, 0, 0, 0);
}
__device__ __forceinline__ void gl_lds16(const void* g, void* l) {
  __builtin_amdgcn_global_load_lds(
      (const __attribute__((address_space(1))) unsigned*)g,
      (__attribute__((address_space(3))) unsigned*)l, 16, 0, 0);
}
__device__ __forceinline__ u64 wave_max_u64(u64 k) {
#pragma unroll
  for (int off = 32; off; off >>= 1) {
    u64 o = __shfl_xor(k, off);
    if (o > k) k = o;
  }
  return k;
}
__device__ __forceinline__ float cvt_in(const void* p, int i, int f) {
  return f ? ((const float*)p)[i] : b2f(((const u16*)p)[i]);
}

// dtype detector (insurance): flag=1 means inputs are f32 (expected)
__global__ void detect_dtype(const u16* __restrict__ X, int* __restrict__ flag) {
  __shared__ int cnt;
  if (threadIdx.x == 0) cnt = 0;
  __syncthreads();
  int sane = 0;
#pragma unroll
  for (int j = 0; j < 16; ++j) {
    u16 u = X[(threadIdx.x * 16 + j) * 2];
    int e = (u >> 7) & 0xff;
    if (u == 0 || (e >= 112 && e <= 142)) sane++;
  }
  atomicAdd(&cnt, sane);
  __syncthreads();
  if (threadIdx.x == 0) *flag = (cnt < 3072) ? 1 : 0;
}

// split X to hi/lo fp16 + f32 copy
__global__ __launch_bounds__(256) void split_input3(
    const void* __restrict__ in, h16* __restrict__ hi, h16* __restrict__ lo,
    float* __restrict__ f32out, int n, const int* __restrict__ flag) {
  int f = *flag;
  int stride = gridDim.x * 256;
  for (int i = blockIdx.x * 256 + threadIdx.x; i < n; i += stride) {
    float x = cvt_in(in, i, f);
    h16 h = (h16)x;
    hi[i] = h;
    lo[i] = (h16)(x - (float)h);
    if (f32out) f32out[i] = x;
  }
}

// split L (blocks 0..255) and W (blocks 256..319)
__global__ __launch_bounds__(256) void split_LW(
    const void* __restrict__ Lin, h16* __restrict__ Lhi, h16* __restrict__ Llo,
    const void* __restrict__ Win, h16* __restrict__ Whi, h16* __restrict__ Wlo,
    const int* __restrict__ flag) {
  int f = *flag;
  int tid = threadIdx.x;
  if (blockIdx.x < 256) {
#pragma unroll
    for (int j = 0; j < 4; ++j) {
      int i = blockIdx.x * 1024 + j * 256 + tid;
      float x = cvt_in(Lin, i, f);
      h16 h = (h16)x;
      Lhi[i] = h;
      Llo[i] = (h16)(x - (float)h);
    }
  } else {
    int b = blockIdx.x - 256;
#pragma unroll
    for (int j = 0; j < 4; ++j) {
      int i = b * 1024 + j * 256 + tid;
      float x = cvt_in(Win, i, f);
      h16 h = (h16)x;
      Whi[i] = h;
      Wlo[i] = (h16)(x - (float)h);
    }
  }
}

// split f32 buffer to hi/lo fp16
__global__ __launch_bounds__(256) void split_f32h(
    const float* __restrict__ in, h16* __restrict__ hi, h16* __restrict__ lo,
    int n) {
  int stride = gridDim.x * 256;
  for (int i = blockIdx.x * 256 + threadIdx.x; i < n; i += stride) {
    float x = in[i];
    h16 h = (h16)x;
    hi[i] = h;
    lo[i] = (h16)(x - (float)h);
  }
}

// theta+bias conv + scalars
__global__ __launch_bounds__(1024) void prep_small(
    const void* __restrict__ theta, const void* __restrict__ bpin,
    const void* __restrict__ alpha, const void* __restrict__ rho_raw,
    float* __restrict__ thetaf, float* __restrict__ biasf,
    float* __restrict__ scal, const int* __restrict__ flag) {
  int f = *flag;
  int tid = threadIdx.x;
  if (tid < 768)
    thetaf[tid] = cvt_in(theta, tid, f);
  else
    biasf[tid - 768] = cvt_in(bpin, tid - 768, f);
  if (tid == 0) {
    float a[4], e[4], m = -1e30f, s = 0.f;
    for (int i = 0; i < 4; ++i) {
      a[i] = cvt_in(alpha, i, f);
      m = fmaxf(m, a[i]);
    }
    for (int i = 0; i < 4; ++i) { e[i] = expf(a[i] - m); s += e[i]; }
    for (int i = 0; i < 4; ++i) scal[i] = e[i] / s;
    float rr = cvt_in(rho_raw, 0, f);
    scal[4] = 1.f / (1.f + expf(-rr));
  }
}

// ---------------------------------------------------------------------------
// Split-precision NT GEMM (64x64 tile): C = alpha*(Ah Bh^T + Ah Bl^T + Al Bh^T)
// ---------------------------------------------------------------------------
template <bool BIAS>
__global__ __launch_bounds__(256) void gemm3_nt(
    const h16* __restrict__ Ah, const h16* __restrict__ Al,
    const h16* __restrict__ Bh, const h16* __restrict__ Bl,
    float* __restrict__ C, const float* __restrict__ bias, float alpha,
    int M, int Nc, int Kd, long batchA, long batchB, long batchC) {
  const h16* Abh = Ah + (size_t)blockIdx.z * batchA;
  const h16* Abl = Al + (size_t)blockIdx.z * batchA;
  const h16* Bbh = Bh + (size_t)blockIdx.z * batchB;
  const h16* Bbl = Bl + (size_t)blockIdx.z * batchB;
  float* Cb = C + (size_t)blockIdx.z * batchC;
  int bn = blockIdx.x, bm = blockIdx.y;
  int tid = threadIdx.x;
  int wid = tid >> 6, lane = tid & 63;
  __shared__ h16 Ash[64 * 40], Asl[64 * 40], Bsh[64 * 40], Bsl[64 * 40];
  f32x4 acc00 = {}, acc01 = {}, acc10 = {}, acc11 = {};
  int lr = tid >> 2;
  int lc = (tid & 3) << 3;
  size_t aoff = (size_t)(bm * 64 + lr) * Kd + lc;
  size_t boff = (size_t)(bn * 64 + lr) * Kd + lc;
  int wm = (wid & 1) * 32, wn = (wid >> 1) * 32;
  int fr = lane & 15;
  int fc = (lane >> 4) << 3;
  for (int k0 = 0; k0 < Kd; k0 += 32) {
    uint4 avh = *(const uint4*)(Abh + aoff + k0);
    uint4 avl = *(const uint4*)(Abl + aoff + k0);
    uint4 bvh = *(const uint4*)(Bbh + boff + k0);
    uint4 bvl = *(const uint4*)(Bbl + boff + k0);
    __syncthreads();
    *(uint4*)(Ash + lr * 40 + lc) = avh;
    *(uint4*)(Asl + lr * 40 + lc) = avl;
    *(uint4*)(Bsh + lr * 40 + lc) = bvh;
    *(uint4*)(Bsl + lr * 40 + lc) = bvl;
    __syncthreads();
    h16x8 a0h = *(const h16x8*)(Ash + (wm + fr) * 40 + fc);
    h16x8 a1h = *(const h16x8*)(Ash + (wm + 16 + fr) * 40 + fc);
    h16x8 b0h = *(const h16x8*)(Bsh + (wn + fr) * 40 + fc);
    h16x8 b1h = *(const h16x8*)(Bsh + (wn + 16 + fr) * 40 + fc);
    h16x8 a0l = *(const h16x8*)(Asl + (wm + fr) * 40 + fc);
    h16x8 a1l = *(const h16x8*)(Asl + (wm + 16 + fr) * 40 + fc);
    h16x8 b0l = *(const h16x8*)(Bsl + (wn + fr) * 40 + fc);
    h16x8 b1l = *(const h16x8*)(Bsl + (wn + 16 + fr) * 40 + fc);
    acc00 = mfma16(a0h, b0h, acc00);
    acc01 = mfma16(a0h, b1h, acc01);
    acc10 = mfma16(a1h, b0h, acc10);
    acc11 = mfma16(a1h, b1h, acc11);
    acc00 = mfma16(a0h, b0l, acc00);
    acc01 = mfma16(a0h, b1l, acc01);
    acc10 = mfma16(a1h, b0l, acc10);
    acc11 = mfma16(a1h, b1l, acc11);
    acc00 = mfma16(a0l, b0h, acc00);
    acc01 = mfma16(a0l, b1h, acc01);
    acc10 = mfma16(a1l, b0h, acc10);
    acc11 = mfma16(a1l, b1h, acc11);
  }
  int crow = (lane >> 4) << 2;
  int ccol = lane & 15;
  f32x4 accs[2][2] = {{acc00, acc01}, {acc10, acc11}};
#pragma unroll
  for (int i = 0; i < 2; ++i)
#pragma unroll
    for (int j = 0; j < 2; ++j) {
      int r0 = bm * 64 + wm + 16 * i + crow;
      int c0 = bn * 64 + wn + 16 * j + ccol;
#pragma unroll
      for (int rg = 0; rg < 4; ++rg) {
        float v = accs[i][j][rg] * alpha;
        if constexpr (BIAS) v += bias[c0];
        Cb[(size_t)(r0 + rg) * Nc + c0] = v;
      }
    }
}

// ---------------------------------------------------------------------------
// Split-precision NT GEMM, 128x128 tile, global_load_lds staging, XOR swizzle.
// ---------------------------------------------------------------------------
__global__ __launch_bounds__(256) void gemm3_big(
    const h16* __restrict__ Ah, const h16* __restrict__ Al,
    const h16* __restrict__ Bh, const h16* __restrict__ Bl,
    float* __restrict__ C, float alpha, int M, int Nc, int Kd) {
  __shared__ h16 sAh[128 * 32], sAl[128 * 32], sBh[128 * 32], sBl[128 * 32];
  int tid = threadIdx.x, wid = tid >> 6, lane = tid & 63;
  int bm = blockIdx.y, bn = blockIdx.x;
  int srow = 32 * wid + (lane >> 2);
  int scnk = lane & 3;
  int fr = lane & 15, fcc = lane >> 4;
  f32x4 acc[4][4] = {};
  const h16* gA[2] = {Ah, Al};
  const h16* gB[2] = {Bh, Bl};
  h16* sA[2] = {sAh, sAl};
  h16* sB[2] = {sBh, sBl};
  int wm = (wid & 1) * 64, wn = (wid >> 1) * 64;
  for (int k0 = 0; k0 < Kd; k0 += 32) {
    __syncthreads();
#pragma unroll
    for (int h = 0; h < 2; ++h) {
      int r = srow + 16 * h;
      int cs = scnk ^ ((r >> 1) & 3);
      size_t goffA = (size_t)(bm * 128 + r) * Kd + k0 + cs * 8;
      size_t goffB = (size_t)(bn * 128 + r) * Kd + k0 + cs * 8;
      int loff = (32 * wid + 16 * h) * 32;
#pragma unroll
      for (int p = 0; p < 2; ++p) {
        gl_lds16(gA[p] + goffA, sA[p] + loff);
        gl_lds16(gB[p] + goffB, sB[p] + loff);
      }
    }
    __syncthreads();
    h16x8 fa[2][4], fb[2][4];
#pragma unroll
    for (int i = 0; i < 4; ++i) {
      int ra = wm + 16 * i + fr;
      int ca = (fcc ^ ((ra >> 1) & 3)) * 8;
      fa[0][i] = *(const h16x8*)(sAh + ra * 32 + ca);
      fa[1][i] = *(const h16x8*)(sAl + ra * 32 + ca);
      int rb = wn + 16 * i + fr;
      int cb = (fcc ^ ((rb >> 1) & 3)) * 8;
      fb[0][i] = *(const h16x8*)(sBh + rb * 32 + cb);
      fb[1][i] = *(const h16x8*)(sBl + rb * 32 + cb);
    }
#pragma unroll
    for (int i = 0; i < 4; ++i)
#pragma unroll
      for (int j = 0; j < 4; ++j) {
        acc[i][j] = mfma16(fa[0][i], fb[0][j], acc[i][j]);
        acc[i][j] = mfma16(fa[0][i], fb[1][j], acc[i][j]);
        acc[i][j] = mfma16(fa[1][i], fb[0][j], acc[i][j]);
      }
  }
  int crow = (lane >> 4) << 2, ccol = lane & 15;
#pragma unroll
  for (int i = 0; i < 4; ++i)
#pragma unroll
    for (int j = 0; j < 4; ++j) {
      int r0 = bm * 128 + wm + 16 * i + crow;
      int c0 = bn * 128 + wn + 16 * j + ccol;
#pragma unroll
      for (int rg = 0; rg < 4; ++rg)
        C[(size_t)(r0 + rg) * Nc + c0] = acc[i][j][rg] * alpha;
    }
}

// ---------------------------------------------------------------------------
// E@X for all 4 heads, K-split, bn=1: block = 128 rows x 256 cols, Kc=1024.
// z = head*4 + kslice. E fetched exactly once. Partials Cpart[z][4096][256].
// ---------------------------------------------------------------------------
__global__ __launch_bounds__(256) void gemm_ks4(
    const h16* __restrict__ Eall, const h16* __restrict__ B,
    float* __restrict__ Cpart) {
  __shared__ h16 sA[128 * 32], sB[256 * 32];
  int tid = threadIdx.x, wid = tid >> 6, lane = tid & 63;
  int bm = blockIdx.y, zz = blockIdx.z;  // grid (1, 32, 16)
  int head = zz >> 2, kz = zz & 3;
  const h16* A = Eall + (size_t)head * 4096 * 4096;
  int kbase = kz * 1024;
  int srowA = 32 * wid + (lane >> 2);
  int srowB = 64 * wid + (lane >> 2);
  int scnk = lane & 3;
  int fr = lane & 15, fcc = lane >> 4;
  f32x4 acc[4][8] = {};
  int wm = (wid & 1) * 64, wn = (wid >> 1) * 128;
  for (int k0 = 0; k0 < 1024; k0 += 32) {
    __syncthreads();
#pragma unroll
    for (int h = 0; h < 2; ++h) {
      int r = srowA + 16 * h;
      int cs = scnk ^ ((r >> 1) & 3);
      size_t goffA = (size_t)(bm * 128 + r) * 4096 + kbase + k0 + cs * 8;
      gl_lds16(A + goffA, sA + (32 * wid + 16 * h) * 32);
    }
#pragma unroll
    for (int h = 0; h < 4; ++h) {
      int r = srowB + 16 * h;
      int cs = scnk ^ ((r >> 1) & 3);
      size_t goffB = (size_t)r * 4096 + kbase + k0 + cs * 8;
      gl_lds16(B + goffB, sB + (64 * wid + 16 * h) * 32);
    }
    __syncthreads();
    h16x8 fa[4], fb[8];
#pragma unroll
    for (int i = 0; i < 4; ++i) {
      int ra = wm + 16 * i + fr;
      int ca = (fcc ^ ((ra >> 1) & 3)) * 8;
      fa[i] = *(const h16x8*)(sA + ra * 32 + ca);
    }
#pragma unroll
    for (int j = 0; j < 8; ++j) {
      int rb = wn + 16 * j + fr;
      int cb = (fcc ^ ((rb >> 1) & 3)) * 8;
      fb[j] = *(const h16x8*)(sB + rb * 32 + cb);
    }
#pragma unroll
    for (int i = 0; i < 4; ++i)
#pragma unroll
      for (int j = 0; j < 8; ++j)
        acc[i][j] = mfma16(fa[i], fb[j], acc[i][j]);
  }
  float* Cp = Cpart + (size_t)zz * 4096 * 256;
  int crow = (lane >> 4) << 2, ccol = lane & 15;
#pragma unroll
  for (int i = 0; i < 4; ++i)
#pragma unroll
    for (int j = 0; j < 8; ++j) {
      int r0 = bm * 128 + wm + 16 * i + crow;
      int c0 = wn + 16 * j + ccol;
#pragma unroll
      for (int rg = 0; rg < 4; ++rg)
        Cp[(size_t)(r0 + rg) * 256 + c0] = acc[i][j][rg];
    }
}

// Zk = sum_k scal[k] * rowSinv[k][row] * sum_{z in head k} Cpart[z]
__global__ __launch_bounds__(256) void ks_reduce4(
    const float* __restrict__ Cpart, const float* __restrict__ scal,
    const float* __restrict__ rowSinv, float* __restrict__ Zk) {
  int i = (blockIdx.x * 256 + threadIdx.x) * 4;  // grid 1024
  int row = i >> 8;
  float4 out = {0.f, 0.f, 0.f, 0.f};
#pragma unroll
  for (int k = 0; k < 4; ++k) {
    float4 s = {0.f, 0.f, 0.f, 0.f};
#pragma unroll
    for (int z = 0; z < 4; ++z) {
      float4 p = *(const float4*)(Cpart + (size_t)(k * 4 + z) * 4096 * 256 + i);
      s.x += p.x; s.y += p.y; s.z += p.z; s.w += p.w;
    }
    float sc = scal[k] * rowSinv[k * 4096 + row];
    out.x += sc * s.x; out.y += sc * s.y;
    out.z += sc * s.z; out.w += sc * s.w;
  }
  *(float4*)(Zk + i) = out;
}

// 16-bit transpose
__global__ __launch_bounds__(256) void transpose16(
    const u16* __restrict__ in, u16* __restrict__ out, int rows, int cols) {
  __shared__ u16 t[32][33];
  const u16* ib = in + (size_t)blockIdx.z * rows * cols;
  u16* ob = out + (size_t)blockIdx.z * rows * cols;
  int r0 = blockIdx.x * 32, c0 = blockIdx.y * 32;
  int tx = threadIdx.x & 31, ty = threadIdx.x >> 5;
#pragma unroll
  for (int i = 0; i < 32; i += 8)
    t[ty + i][tx] = ib[(size_t)(r0 + ty + i) * cols + c0 + tx];
  __syncthreads();
#pragma unroll
  for (int i = 0; i < 32; i += 8)
    ob[(size_t)(c0 + ty + i) * rows + r0 + tx] = t[tx][ty + i];
}

// ---------------------------------------------------------------------------
// fused per-row (one wave per row): max -> threshold T -> exp/E-write +
// candidate push -> exact jax-tiebreak top-16 from candidates
// ---------------------------------------------------------------------------
__global__ __launch_bounds__(256) void row_softmax_topk(
    const float* __restrict__ A, float* __restrict__ topv,
    int* __restrict__ topi, h16* __restrict__ E, float* __restrict__ rowSinvK,
    int khead) {
  __shared__ u64 candK[4][256];
  __shared__ int candN[4];
  int wid = threadIdx.x >> 6, lane = threadIdx.x & 63;
  int row = blockIdx.x * 4 + wid;
  const float* arow = A + ((size_t)row << 12);
  if (lane == 0) candN[wid] = 0;
  __syncthreads();
  float lm = -INFINITY;
#pragma unroll
  for (int t = 0; t < 16; ++t) {
    float4 v = *(const float4*)(arow + (t << 8) + (lane << 2));
    lm = fmaxf(lm, fmaxf(fmaxf(v.x, v.y), fmaxf(v.z, v.w)));
  }
  float m = lm;
#pragma unroll
  for (int off = 32; off; off >>= 1) m = fmaxf(m, __shfl_xor(m, off));
  u64 lk = ((u64)fkey(lm) << 32) | (unsigned)lane;
  float T = 0.f;
  for (int r = 0; r < 16; ++r) {
    u64 k2 = wave_max_u64(lk);
    if (lk == k2) lk = 0;
    if (r == 15) T = unfkey((unsigned)(k2 >> 32));
  }
  h16* erow = E + ((size_t)row << 12);
  int* cn = &candN[wid];
  u64* ck = candK[wid];
  float s = 0.f;
  for (int t = 0; t < 16; ++t) {
    int c = (t << 8) + (lane << 2);
    float4 v = *(const float4*)(arow + c);
    float e0 = __expf(v.x - m), e1 = __expf(v.y - m);
    float e2 = __expf(v.z - m), e3 = __expf(v.w - m);
    s += (e0 + e1) + (e2 + e3);
    h16x4 hv = {(h16)e0, (h16)e1, (h16)e2, (h16)e3};
    *(h16x4*)(erow + c) = hv;
    if (v.x >= T) {
      int sl = atomicAdd(cn, 1);
      if (sl < 256) ck[sl] = ((u64)fkey(v.x) << 32) | (unsigned)(~(unsigned)c);
    }
    if (v.y >= T) {
      int sl = atomicAdd(cn, 1);
      if (sl < 256) ck[sl] = ((u64)fkey(v.y) << 32) | (unsigned)(~(unsigned)(c + 1));
    }
    if (v.z >= T) {
      int sl = atomicAdd(cn, 1);
      if (sl < 256) ck[sl] = ((u64)fkey(v.z) << 32) | (unsigned)(~(unsigned)(c + 2));
    }
    if (v.w >= T) {
      int sl = atomicAdd(cn, 1);
      if (sl < 256) ck[sl] = ((u64)fkey(v.w) << 32) | (unsigned)(~(unsigned)(c + 3));
    }
  }
#pragma unroll
  for (int off = 32; off; off >>= 1) s += __shfl_xor(s, off);
  if (lane == 0) rowSinvK[row] = 1.f / s;
  __syncthreads();
  int cnt = min(*cn, 256);
  u64 loc[4] = {0ull, 0ull, 0ull, 0ull};
  int nl = 0;
  for (int j = lane; j < cnt; j += 64)
    if (nl < 4) loc[nl++] = ck[j];
#define CSW(a, b)                     \
  {                                   \
    if (loc[b] > loc[a]) {            \
      u64 tt = loc[a];                \
      loc[a] = loc[b];                \
      loc[b] = tt;                    \
    }                                 \
  }
  CSW(0, 1) CSW(2, 3) CSW(0, 2) CSW(1, 3) CSW(1, 2)
#undef CSW
  float myv = 0.f;
  int myi = 0;
  float sum16 = 0.f;
  for (int r = 0; r < 16; ++r) {
    u64 key = loc[0];
    u64 k2 = wave_max_u64(key);
    float wv = unfkey((unsigned)(k2 >> 32));
    int wi = (int)(~(unsigned)(k2 & 0xffffffffu));
    if (key == k2 && key != 0ull) {
      loc[0] = loc[1];
      loc[1] = loc[2];
      loc[2] = loc[3];
      loc[3] = 0ull;
    }
    sum16 += expf(wv - m);
    if (r == lane) { myv = wv; myi = wi; }
  }
  if (lane < 16) {
    size_t o = (((size_t)khead << 12) + row) * 16 + lane;
    topv[o] = expf(myv - m) / (sum16 + 1e-9f * s);
    topi[o] = myi;
  }
}

// ---------------------------------------------------------------------------
// sparse hypergraph build — atomic-free two-level LDS histogram (+DeIS fused)
// ---------------------------------------------------------------------------
__global__ __launch_bounds__(256) void hist_part(
    const float* __restrict__ topv, const int* __restrict__ topi,
    int* __restrict__ pCnt, float* __restrict__ pDv,
    float* __restrict__ DeIS) {
  __shared__ int lc[4096];
  __shared__ float ld[4096];
  int tid = threadIdx.x, b = blockIdx.x;  // grid 64
  for (int j = tid; j < 4096; j += 256) { lc[j] = 0; ld[j] = 0.f; }
  __syncthreads();
  int base = b * 4096;
#pragma unroll
  for (int j = 0; j < 16; ++j) {
    int t = base + j * 256 + tid;
    atomicAdd(&lc[topi[t]], 1);
    atomicAdd(&ld[topi[t]], topv[t]);
  }
  __syncthreads();
  for (int j = tid; j < 4096; j += 256) {
    pCnt[base + j] = lc[j];
    pDv[base + j] = ld[j];
  }
  int e = b * 256 + tid;
  const float4* p = (const float4*)(topv + ((size_t)e << 4));
  float4 a = p[0], bb = p[1], c = p[2], d = p[3];
  float s = ((a.x + a.y) + (a.z + a.w)) + ((bb.x + bb.y) + (bb.z + bb.w)) +
            ((c.x + c.y) + (c.z + c.w)) + ((d.x + d.y) + (d.z + d.w));
  DeIS[e] = 1.0f / sqrtf(s + 1e-9f);
}

// per-bin reduce over 64 blocks: cnt, Dvis, block prefix; + fused v0 init
__global__ __launch_bounds__(256) void col_scan(
    const int* __restrict__ pCnt, const float* __restrict__ pDv,
    int* __restrict__ cnt, float* __restrict__ Dvis,
    int* __restrict__ blockBase, float* __restrict__ v0) {
  int i = blockIdx.x * 256 + threadIdx.x;  // grid 16 -> 4096
  int run = 0;
  float dv = 0.f;
#pragma unroll
  for (int b = 0; b < 64; ++b) {
    blockBase[b * 4096 + i] = run;
    run += pCnt[b * 4096 + i];
    dv += pDv[b * 4096 + i];
  }
  cnt[i] = run;
  Dvis[i] = sqrtf(1.0f / (dv + 1e-9f));
  {
    int tid = i;
    unsigned j = (unsigned)(tid & 2047);
    unsigned x0 = j, x1 = j + 2048u;
    const unsigned ks0 = 0u, ks1 = 1u, ks2 = 0x1BD11BDAu;
#define TF_R(r)                                \
    {                                          \
      x0 += x1;                                \
      x1 = (x1 << (r)) | (x1 >> (32 - (r)));   \
      x1 ^= x0;                                \
    }
    x0 += ks0; x1 += ks1;
    TF_R(13) TF_R(15) TF_R(26) TF_R(6)  x0 += ks1; x1 += ks2 + 1u;
    TF_R(17) TF_R(29) TF_R(16) TF_R(24) x0 += ks2; x1 += ks0 + 2u;
    TF_R(13) TF_R(15) TF_R(26) TF_R(6)  x0 += ks0; x1 += ks1 + 3u;
    TF_R(17) TF_R(29) TF_R(16) TF_R(24) x0 += ks1; x1 += ks2 + 4u;
    TF_R(13) TF_R(15) TF_R(26) TF_R(6)  x0 += ks2; x1 += ks0 + 5u;
#undef TF_R
    unsigned bits = (tid < 2048) ? x0 : x1;
    float u01 = __uint_as_float((bits >> 9) | 0x3f800000u) - 1.0f;
    const float lo = -0.99999994f;
    float u = fmaxf(lo, u01 * 2.0f + lo);
    float w = -log1pf(-u * u);
    float p;
    if (w < 5.0f) {
      float t = w - 2.5f;
      p = 2.81022636e-08f;
      p = 3.43273939e-07f + p * t;
      p = -3.5233877e-06f + p * t;
      p = -4.39150654e-06f + p * t;
      p = 0.00021858087f + p * t;
      p = -0.00125372503f + p * t;
      p = -0.00417768164f + p * t;
      p = 0.246640727f + p * t;
      p = 1.50140941f + p * t;
    } else {
      float t = sqrtf(w) - 3.0f;
      p = -0.000200214257f;
      p = 0.000100950558f + p * t;
      p = 0.00134934322f + p * t;
      p = -0.00367342844f + p * t;
      p = 0.00573950773f + p * t;
      p = -0.0076224613f + p * t;
      p = 0.00943887047f + p * t;
      p = 1.00167406f + p * t;
      p = 2.83297682f + p * t;
    }
    v0[tid] = 1.41421354f * (p * u);
  }
}

// exclusive scan of cnt[4096] -> rowptr[4097]
__global__ __launch_bounds__(256) void scan_rowptr(const int* __restrict__ cnt,
                                                   int* __restrict__ rowptr) {
  __shared__ int part[256];
  int tid = threadIdx.x;
  int base = tid * 16;
  int loc[16];
  int s = 0;
#pragma unroll
  for (int j = 0; j < 16; ++j) { loc[j] = s; s += cnt[base + j]; }
  part[tid] = s;
  __syncthreads();
  for (int off = 1; off < 256; off <<= 1) {
    int v = (tid >= off) ? part[tid - off] : 0;
    __syncthreads();
    part[tid] += v;
    __syncthreads();
  }
  int pre = (tid == 0) ? 0 : part[tid - 1];
#pragma unroll
  for (int j = 0; j < 16; ++j) rowptr[base + j] = pre + loc[j];
  if (tid == 255) rowptr[4096] = part[255];
}

// fill cvals + CSR transpose via LDS cursors (no global atomics)
__global__ __launch_bounds__(256) void csr_fill3(
    const float* __restrict__ topv, const int* __restrict__ topi,
    const float* __restrict__ Dvis, const float* __restrict__ DeIS,
    const int* __restrict__ rowptr, const int* __restrict__ blockBase,
    float* __restrict__ cvals, int* __restrict__ colE,
    float* __restrict__ cvalR) {
  __shared__ int lcur[4096];
  int tid = threadIdx.x, b = blockIdx.x;  // grid 64
  int base = b * 4096;
  for (int j = tid; j < 4096; j += 256)
    lcur[j] = rowptr[j] + blockBase[base + j];
  __syncthreads();
#pragma unroll
  for (int j = 0; j < 16; ++j) {
    int t = base + j * 256 + tid;
    int i = topi[t];
    int e = t >> 4;
    float c = Dvis[i] * topv[t] * DeIS[e];
    cvals[t] = c;
    int slot = atomicAdd(&lcur[i], 1);
    colE[slot] = e;
    cvalR[slot] = c;
  }
}

// g[e] = sum_p c[e,p] * v[idx[e,p]]
__global__ __launch_bounds__(256) void spmv_edge(
    const float* __restrict__ cvals, const int* __restrict__ topi,
    const float* __restrict__ v, float* __restrict__ g) {
  int e = blockIdx.x * 256 + threadIdx.x;  // grid 64
  float acc = 0.f;
#pragma unroll
  for (int p = 0; p < 16; ++p)
    acc += cvals[e * 16 + p] * v[topi[e * 16 + p]];
  g[e] = acc;
}

// vout[i] = vin[i] - sum_{j in row i} cvalR[j]*g[colE[j]]
__global__ __launch_bounds__(256) void spmv_row(
    const int* __restrict__ rowptr, const int* __restrict__ colE,
    const float* __restrict__ cvalR, const float* __restrict__ g,
    const float* __restrict__ vin, float* __restrict__ vout) {
  int wid = threadIdx.x >> 6, lane = threadIdx.x & 63;
  int row = blockIdx.x * 4 + wid;  // grid 1024
  int s = rowptr[row], e = rowptr[row + 1];
  float acc = 0.f;
  for (int j = s + lane; j < e; j += 64) acc += cvalR[j] * g[colE[j]];
#pragma unroll
  for (int off = 32; off; off >>= 1) acc += __shfl_xor(acc, off);
  if (lane == 0) vout[row] = vin[row] - acc;
}

// lam = clip((w5.w6)/(w5.w5), 1e-3) -> scal[5]
__global__ __launch_bounds__(256) void pi_dots(const float* __restrict__ w5,
                                               const float* __restrict__ w6,
                                               float* __restrict__ scal) {
  __shared__ float r1[256], r2[256];
  int tid = threadIdx.x;
  float a = 0.f, b = 0.f;
  for (int i = tid; i < 4096; i += 256) {
    float x = w5[i];
    a += x * x;
    b += x * w6[i];
  }
  r1[tid] = a; r2[tid] = b;
  __syncthreads();
  for (int off = 128; off; off >>= 1) {
    if (tid < off) { r1[tid] += r1[tid + off]; r2[tid] += r2[tid + off]; }
    __syncthreads();
  }
  if (tid == 0) scal[5] = fmaxf(r2[0] / r1[0], 1e-3f);
}

// G[e,:] = sum_p c[e,p] * M[idx[e,p],:]  — MLP-unrolled
__global__ __launch_bounds__(256) void spmm_edge(
    const float* __restrict__ cvals, const int* __restrict__ topi,
    const float* __restrict__ M, float* __restrict__ G) {
  int wid = threadIdx.x >> 6, lane = threadIdx.x & 63;
  int e = blockIdx.x * 4 + wid;  // grid 4096
  int cb = lane << 2;
  const float* cv = cvals + ((size_t)e << 4);
  const int* ti = topi + ((size_t)e << 4);
  float cc[16];
  int ix[16];
#pragma unroll
  for (int p = 0; p < 16; ++p) { cc[p] = cv[p]; ix[p] = ti[p]; }
  float4 acc[4] = {};
#pragma unroll
  for (int h = 0; h < 2; ++h) {
    float4 g[8];
#pragma unroll
    for (int p = 0; p < 8; ++p)
      g[p] = *(const float4*)(M + ((size_t)ix[h * 8 + p] << 8) + cb);
#pragma unroll
    for (int p = 0; p < 8; ++p) {
      float c = cc[h * 8 + p];
      float4 gg = g[p];
      int a = p & 3;
      acc[a].x += c * gg.x; acc[a].y += c * gg.y;
      acc[a].z += c * gg.z; acc[a].w += c * gg.w;
    }
  }
  float4 r;
  r.x = (acc[0].x + acc[1].x) + (acc[2].x + acc[3].x);
  r.y = (acc[0].y + acc[1].y) + (acc[2].y + acc[3].y);
  r.z = (acc[0].z + acc[1].z) + (acc[2].z + acc[3].z);
  r.w = (acc[0].w + acc[1].w) + (acc[2].w + acc[3].w);
  *(float4*)(G + ((size_t)e << 8) + cb) = r;
}

// Z = S_norm @ M via CSR rows + fused epilogues
template <int MODE>
__global__ __launch_bounds__(256) void spmm_row_ep(
    const int* __restrict__ rowptr, const int* __restrict__ colE,
    const float* __restrict__ cvalR, const float* __restrict__ G,
    const float* __restrict__ Xf, float* __restrict__ T1,
    const float* __restrict__ Zk, const float* __restrict__ thetaf,
    const float* __restrict__ scal, h16* __restrict__ Zmh,
    h16* __restrict__ Zml) {
  int wid = threadIdx.x >> 6, lane = threadIdx.x & 63;
  int row = blockIdx.x * 4 + wid;  // grid 1024
  int cb = lane << 2;
  int s = rowptr[row], e = rowptr[row + 1];
  float4 acc[4] = {};
  int j = s;
  for (; j + 8 <= e; j += 8) {
    int ix[8];
    float cc[8];
#pragma unroll
    for (int t = 0; t < 8; ++t) { ix[t] = colE[j + t]; cc[t] = cvalR[j + t]; }
    float4 g[8];
#pragma unroll
    for (int t = 0; t < 8; ++t)
      g[t] = *(const float4*)(G + ((size_t)ix[t] << 8) + cb);
#pragma unroll
    for (int t = 0; t < 8; ++t) {
      float c = cc[t];
      float4 gg = g[t];
      int a = t & 3;
      acc[a].x += c * gg.x; acc[a].y += c * gg.y;
      acc[a].z += c * gg.z; acc[a].w += c * gg.w;
    }
  }
  for (; j < e; ++j) {
    float c = cvalR[j];
    float4 gg = *(const float4*)(G + ((size_t)colE[j] << 8) + cb);
    acc[0].x += c * gg.x; acc[0].y += c * gg.y;
    acc[0].z += c * gg.z; acc[0].w += c * gg.w;
  }
  float4 z;
  z.x = (acc[0].x + acc[1].x) + (acc[2].x + acc[3].x);
  z.y = (acc[0].y + acc[1].y) + (acc[2].y + acc[3].y);
  z.z = (acc[0].z + acc[1].z) + (acc[2].z + acc[3].z);
  z.w = (acc[0].w + acc[1].w) + (acc[2].w + acc[3].w);
  size_t o = ((size_t)row << 8) + cb;
  float c1 = 2.0f / scal[5];
  float4 x = *(const float4*)(Xf + o);
  if constexpr (MODE == 1) {
    float4 t1;
    t1.x = (c1 - 1.0f) * x.x - c1 * z.x;
    t1.y = (c1 - 1.0f) * x.y - c1 * z.y;
    t1.z = (c1 - 1.0f) * x.z - c1 * z.z;
    t1.w = (c1 - 1.0f) * x.w - c1 * z.w;
    *(float4*)(T1 + o) = t1;
  } else {
    float rho = scal[4];
    float4 t1 = *(const float4*)(T1 + o);
    float4 zk = *(const float4*)(Zk + o);
    h16x4 hh, hl;
#pragma unroll
    for (int q = 0; q < 4; ++q) {
      float xv = (&x.x)[q], t1v = (&t1.x)[q], zv = (&z.x)[q], zkv = (&zk.x)[q];
      int d = cb + q;
      float t2 = 2.0f * ((c1 - 1.0f) * t1v - c1 * zv) - xv;
      float oo = xv * thetaf[d] + t1v * thetaf[256 + d] + t2 * thetaf[512 + d];
      float zs = oo > 0.0f ? oo : expm1f(oo);
      float zm = rho * zs + (1.0f - rho) * zkv;
      h16 h = (h16)zm;
      hh[q] = h;
      hl[q] = (h16)(zm - (float)h);
    }
    *(h16x4*)(Zmh + o) = hh;
    *(h16x4*)(Zml + o) = hl;
  }
}

// ---------------------------------------------------------------------------
extern "C" void kernel_launch(void* const* d_in, const int* in_sizes, int n_in,
                              void* d_out, int out_size, void* d_ws,
                              size_t ws_size, hipStream_t stream) {
  (void)in_sizes; (void)n_in; (void)out_size;
  const void* Xin = d_in[0];
  const void* Lin = d_in[1];
  const void* alpha = d_in[2];
  const void* theta = d_in[3];
  const void* rho_raw = d_in[4];
  const void* Wpin = d_in[5];
  const void* bpin = d_in[6];
  float* out = (float*)d_out;

  char* base = (char*)d_ws;
  size_t off = 0;
  auto alloc = [&](size_t bytes) -> char* {
    char* p = base + off;
    off += (bytes + 255) & ~(size_t)255;
    return p;
  };
  float* Abuf = (float*)alloc((size_t)4096 * 4096 * 4);   // A; 16 ks-partials; G
  h16* Eall = (h16*)alloc((size_t)4 * 4096 * 4096 * 2);   // 4 E planes (Yf alias)
  h16* Yhi = (h16*)alloc((size_t)4 * 4096 * 256 * 2);
  h16* Ylo = (h16*)alloc((size_t)4 * 4096 * 256 * 2);
  h16* Xhi = (h16*)alloc((size_t)4096 * 256 * 2);
  h16* Xlo = (h16*)alloc((size_t)4096 * 256 * 2);
  float* Xf = (float*)alloc((size_t)4096 * 256 * 4);
  h16* XT = (h16*)alloc((size_t)256 * 4096 * 2);
  h16* Lhi = (h16*)alloc((size_t)4 * 256 * 256 * 2);
  h16* Llo = (h16*)alloc((size_t)4 * 256 * 256 * 2);
  h16* LThi = (h16*)alloc((size_t)4 * 256 * 256 * 2);
  h16* LTlo = (h16*)alloc((size_t)4 * 256 * 256 * 2);
  h16* Whi = (h16*)alloc((size_t)256 * 256 * 2);
  h16* Wlo = (h16*)alloc((size_t)256 * 256 * 2);
  float* Zk = (float*)alloc((size_t)4096 * 256 * 4);
  float* T1 = (float*)alloc((size_t)4096 * 256 * 4);
  h16* Zmh = (h16*)alloc((size_t)4096 * 256 * 2);
  h16* Zml = (h16*)alloc((size_t)4096 * 256 * 2);
  float* topv = (float*)alloc((size_t)4 * 4096 * 16 * 4);
  int* topi = (int*)alloc((size_t)4 * 4096 * 16 * 4);
  float* cvals = (float*)alloc((size_t)262144 * 4);
  int* colE = (int*)alloc((size_t)262144 * 4);
  float* cvalR = (float*)alloc((size_t)262144 * 4);
  int* pCnt = (int*)alloc((size_t)64 * 4096 * 4);
  float* pDv = (float*)alloc((size_t)64 * 4096 * 4);
  int* blockBase = (int*)alloc((size_t)64 * 4096 * 4);
  int* rowptr = (int*)alloc(4097 * 4);
  int* cnt = (int*)alloc(4096 * 4);
  float* Dvis = (float*)alloc(4096 * 4);
  float* DeIS = (float*)alloc(16384 * 4);
  float* gE = (float*)alloc(16384 * 4);
  float* wA = (float*)alloc(4096 * 4);
  float* wB = (float*)alloc(4096 * 4);
  float* rowSinv = (float*)alloc((size_t)4 * 4096 * 4);
  float* thetaf = (float*)alloc(768 * 4);
  float* biasf = (float*)alloc(256 * 4);
  float* scal = (float*)alloc(256);
  int* flag = (int*)alloc(256);
  if (off > ws_size) return;
  float* Yf = (float*)Eall;  // 16 MB alias; dead before E planes written
  float* Kpart = Abuf;       // 64 MB: 16 partial planes; A dead by then
  float* G = (float*)Abuf;   // 16 MB alias; partials dead after ks_reduce4

  detect_dtype<<<1, 256, 0, stream>>>((const u16*)Xin, flag);
  split_input3<<<1024, 256, 0, stream>>>(Xin, Xhi, Xlo, Xf, 4096 * 256, flag);
  split_LW<<<320, 256, 0, stream>>>(Lin, Lhi, Llo, Wpin, Whi, Wlo, flag);
  prep_small<<<1, 1024, 0, stream>>>(theta, bpin, alpha, rho_raw, thetaf, biasf,
                                     scal, flag);
  transpose16<<<dim3(128, 8, 1), 256, 0, stream>>>((const u16*)Xhi, (u16*)XT,
                                                   4096, 256);
  transpose16<<<dim3(8, 8, 4), 256, 0, stream>>>((const u16*)Lhi, (u16*)LThi,
                                                 256, 256);
  transpose16<<<dim3(8, 8, 4), 256, 0, stream>>>((const u16*)Llo, (u16*)LTlo,
                                                 256, 256);
  // Yf = X @ L_k (split fp16, fused), batched z=4
  gemm3_nt<false><<<dim3(4, 64, 4), 256, 0, stream>>>(
      Xhi, Xlo, LThi, LTlo, Yf, nullptr, 1.0f, 4096, 256, 256,
      0L, 256L * 256L, 4096L * 256L);
  split_f32h<<<2048, 256, 0, stream>>>(Yf, Yhi, Ylo, 4 * 4096 * 256);
  for (int k = 0; k < 4; ++k) {
    gemm3_big<<<dim3(32, 32), 256, 0, stream>>>(
        Yhi + (size_t)k * 4096 * 256, Ylo + (size_t)k * 4096 * 256, Xhi, Xlo,
        Abuf, 0.0625f, 4096, 4096, 256);
    row_softmax_topk<<<1024, 256, 0, stream>>>(
        Abuf, topv, topi, Eall + (size_t)k * 4096 * 4096, rowSinv + k * 4096,
        k);
  }
  // all 4 heads' E @ X, bn=1 K-split (E fetched once), 16 partial planes
  gemm_ks4<<<dim3(1, 32, 16), 256, 0, stream>>>(Eall, XT, Kpart);
  ks_reduce4<<<1024, 256, 0, stream>>>(Kpart, scal, rowSinv, Zk);
  // sparse hypergraph Laplacian — atomic-free two-level histogram build
  hist_part<<<64, 256, 0, stream>>>(topv, topi, pCnt, pDv, DeIS);
  col_scan<<<16, 256, 0, stream>>>(pCnt, pDv, cnt, Dvis, blockBase, wA);
  scan_rowptr<<<1, 256, 0, stream>>>(cnt, rowptr);
  csr_fill3<<<64, 256, 0, stream>>>(topv, topi, Dvis, DeIS, rowptr, blockBase,
                                    cvals, colE, cvalR);
  // power iteration (regular launches — cooperative launch fails graph capture)
  for (int it = 0; it < 6; ++it) {
    const float* vi = (it & 1) ? wB : wA;
    float* vo = (it & 1) ? wA : wB;
    spmv_edge<<<64, 256, 0, stream>>>(cvals, topi, vi, gE);
    spmv_row<<<1024, 256, 0, stream>>>(rowptr, colE, cvalR, gE, vi, vo);
  }
  pi_dots<<<1, 256, 0, stream>>>(wB, wA, scal);
  // SnX -> T1 (fused) ; SnT1 -> cheb/elu/mix -> Zmh/Zml (fused)
  spmm_edge<<<4096, 256, 0, stream>>>(cvals, topi, Xf, G);
  spmm_row_ep<1><<<1024, 256, 0, stream>>>(rowptr, colE, cvalR, G, Xf, T1,
                                           nullptr, thetaf, scal, nullptr,
                                           nullptr);
  spmm_edge<<<4096, 256, 0, stream>>>(cvals, topi, T1, G);
  spmm_row_ep<2><<<1024, 256, 0, stream>>>(rowptr, colE, cvalR, G, Xf, T1, Zk,
                                           thetaf, scal, Zmh, Zml);
  // out = Zmix @ proj_w^T + proj_b (split fp16, f32 out)
  gemm3_nt<true><<<dim3(4, 64, 1), 256, 0, stream>>>(
      Zmh, Zml, Whi, Wlo, out, biasf, 1.0f, 4096, 256, 256, 0L, 0L, 0L);
}

// Round 13
// 668.025 us; speedup vs baseline: 1.9224x; 1.0178x over previous
//
#include <hip/hip_runtime.h>

typedef unsigned short u16;
typedef unsigned long long u64;
typedef _Float16 h16;
typedef __attribute__((ext_vector_type(8))) _Float16 h16x8;
typedef __attribute__((ext_vector_type(4))) _Float16 h16x4;
typedef __attribute__((ext_vector_type(4))) float f32x4;

__device__ __forceinline__ float b2f(u16 u) {
  unsigned x = ((unsigned)u) << 16;
  return __uint_as_float(x);
}
__device__ __forceinline__ unsigned fkey(float f) {
  unsigned b = __float_as_uint(f);
  return (b & 0x80000000u) ? ~b : (b | 0x80000000u);
}
__device__ __forceinline__ float unfkey(unsigned u) {
  unsigned b = (u & 0x80000000u) ? (u ^ 0x80000000u) : ~u;
  return __uint_as_float(b);
}
__device__ __forceinline__ f32x4 mfma16(h16x8 a, h16x8 b, f32x4 c) {
  return __builtin_amdgcn_mfma_f32_16x16x32_f16(a, b, c, 0, 0, 0);
}
__device__ __forceinline__ void gl_lds16(const void* g, void* l) {
  __builtin_amdgcn_global_load_lds(
      (const __attribute__((address_space(1))) unsigned*)g,
      (__attribute__((address_space(3))) unsigned*)l, 16, 0, 0);
}
__device__ __forceinline__ u64 wave_max_u64(u64 k) {
#pragma unroll
  for (int off = 32; off; off >>= 1) {
    u64 o = __shfl_xor(k, off);
    if (o > k) k = o;
  }
  return k;
}
__device__ __forceinline__ float cvt_in(const void* p, int i, int f) {
  return f ? ((const float*)p)[i] : b2f(((const u16*)p)[i]);
}

// dtype detector (insurance): flag=1 means inputs are f32 (expected)
__global__ void detect_dtype(const u16* __restrict__ X, int* __restrict__ flag) {
  __shared__ int cnt;
  if (threadIdx.x == 0) cnt = 0;
  __syncthreads();
  int sane = 0;
#pragma unroll
  for (int j = 0; j < 16; ++j) {
    u16 u = X[(threadIdx.x * 16 + j) * 2];
    int e = (u >> 7) & 0xff;
    if (u == 0 || (e >= 112 && e <= 142)) sane++;
  }
  atomicAdd(&cnt, sane);
  __syncthreads();
  if (threadIdx.x == 0) *flag = (cnt < 3072) ? 1 : 0;
}

// split X to hi/lo fp16 + f32 copy
__global__ __launch_bounds__(256) void split_input3(
    const void* __restrict__ in, h16* __restrict__ hi, h16* __restrict__ lo,
    float* __restrict__ f32out, int n, const int* __restrict__ flag) {
  int f = *flag;
  int stride = gridDim.x * 256;
  for (int i = blockIdx.x * 256 + threadIdx.x; i < n; i += stride) {
    float x = cvt_in(in, i, f);
    h16 h = (h16)x;
    hi[i] = h;
    lo[i] = (h16)(x - (float)h);
    if (f32out) f32out[i] = x;
  }
}

// split L (blocks 0..255) and W (blocks 256..319)
__global__ __launch_bounds__(256) void split_LW(
    const void* __restrict__ Lin, h16* __restrict__ Lhi, h16* __restrict__ Llo,
    const void* __restrict__ Win, h16* __restrict__ Whi, h16* __restrict__ Wlo,
    const int* __restrict__ flag) {
  int f = *flag;
  int tid = threadIdx.x;
  if (blockIdx.x < 256) {
#pragma unroll
    for (int j = 0; j < 4; ++j) {
      int i = blockIdx.x * 1024 + j * 256 + tid;
      float x = cvt_in(Lin, i, f);
      h16 h = (h16)x;
      Lhi[i] = h;
      Llo[i] = (h16)(x - (float)h);
    }
  } else {
    int b = blockIdx.x - 256;
#pragma unroll
    for (int j = 0; j < 4; ++j) {
      int i = b * 1024 + j * 256 + tid;
      float x = cvt_in(Win, i, f);
      h16 h = (h16)x;
      Whi[i] = h;
      Wlo[i] = (h16)(x - (float)h);
    }
  }
}

// split f32 buffer to hi/lo fp16
__global__ __launch_bounds__(256) void split_f32h(
    const float* __restrict__ in, h16* __restrict__ hi, h16* __restrict__ lo,
    int n) {
  int stride = gridDim.x * 256;
  for (int i = blockIdx.x * 256 + threadIdx.x; i < n; i += stride) {
    float x = in[i];
    h16 h = (h16)x;
    hi[i] = h;
    lo[i] = (h16)(x - (float)h);
  }
}

// theta+bias conv + scalars
__global__ __launch_bounds__(1024) void prep_small(
    const void* __restrict__ theta, const void* __restrict__ bpin,
    const void* __restrict__ alpha, const void* __restrict__ rho_raw,
    float* __restrict__ thetaf, float* __restrict__ biasf,
    float* __restrict__ scal, const int* __restrict__ flag) {
  int f = *flag;
  int tid = threadIdx.x;
  if (tid < 768)
    thetaf[tid] = cvt_in(theta, tid, f);
  else
    biasf[tid - 768] = cvt_in(bpin, tid - 768, f);
  if (tid == 0) {
    float a[4], e[4], m = -1e30f, s = 0.f;
    for (int i = 0; i < 4; ++i) {
      a[i] = cvt_in(alpha, i, f);
      m = fmaxf(m, a[i]);
    }
    for (int i = 0; i < 4; ++i) { e[i] = expf(a[i] - m); s += e[i]; }
    for (int i = 0; i < 4; ++i) scal[i] = e[i] / s;
    float rr = cvt_in(rho_raw, 0, f);
    scal[4] = 1.f / (1.f + expf(-rr));
  }
}

// ---------------------------------------------------------------------------
// Split-precision NT GEMM (64x64 tile): C = alpha*(Ah Bh^T + Ah Bl^T + Al Bh^T)
// ---------------------------------------------------------------------------
template <bool BIAS>
__global__ __launch_bounds__(256) void gemm3_nt(
    const h16* __restrict__ Ah, const h16* __restrict__ Al,
    const h16* __restrict__ Bh, const h16* __restrict__ Bl,
    float* __restrict__ C, const float* __restrict__ bias, float alpha,
    int M, int Nc, int Kd, long batchA, long batchB, long batchC) {
  const h16* Abh = Ah + (size_t)blockIdx.z * batchA;
  const h16* Abl = Al + (size_t)blockIdx.z * batchA;
  const h16* Bbh = Bh + (size_t)blockIdx.z * batchB;
  const h16* Bbl = Bl + (size_t)blockIdx.z * batchB;
  float* Cb = C + (size_t)blockIdx.z * batchC;
  int bn = blockIdx.x, bm = blockIdx.y;
  int tid = threadIdx.x;
  int wid = tid >> 6, lane = tid & 63;
  __shared__ h16 Ash[64 * 40], Asl[64 * 40], Bsh[64 * 40], Bsl[64 * 40];
  f32x4 acc00 = {}, acc01 = {}, acc10 = {}, acc11 = {};
  int lr = tid >> 2;
  int lc = (tid & 3) << 3;
  size_t aoff = (size_t)(bm * 64 + lr) * Kd + lc;
  size_t boff = (size_t)(bn * 64 + lr) * Kd + lc;
  int wm = (wid & 1) * 32, wn = (wid >> 1) * 32;
  int fr = lane & 15;
  int fc = (lane >> 4) << 3;
  for (int k0 = 0; k0 < Kd; k0 += 32) {
    uint4 avh = *(const uint4*)(Abh + aoff + k0);
    uint4 avl = *(const uint4*)(Abl + aoff + k0);
    uint4 bvh = *(const uint4*)(Bbh + boff + k0);
    uint4 bvl = *(const uint4*)(Bbl + boff + k0);
    __syncthreads();
    *(uint4*)(Ash + lr * 40 + lc) = avh;
    *(uint4*)(Asl + lr * 40 + lc) = avl;
    *(uint4*)(Bsh + lr * 40 + lc) = bvh;
    *(uint4*)(Bsl + lr * 40 + lc) = bvl;
    __syncthreads();
    h16x8 a0h = *(const h16x8*)(Ash + (wm + fr) * 40 + fc);
    h16x8 a1h = *(const h16x8*)(Ash + (wm + 16 + fr) * 40 + fc);
    h16x8 b0h = *(const h16x8*)(Bsh + (wn + fr) * 40 + fc);
    h16x8 b1h = *(const h16x8*)(Bsh + (wn + 16 + fr) * 40 + fc);
    h16x8 a0l = *(const h16x8*)(Asl + (wm + fr) * 40 + fc);
    h16x8 a1l = *(const h16x8*)(Asl + (wm + 16 + fr) * 40 + fc);
    h16x8 b0l = *(const h16x8*)(Bsl + (wn + fr) * 40 + fc);
    h16x8 b1l = *(const h16x8*)(Bsl + (wn + 16 + fr) * 40 + fc);
    acc00 = mfma16(a0h, b0h, acc00);
    acc01 = mfma16(a0h, b1h, acc01);
    acc10 = mfma16(a1h, b0h, acc10);
    acc11 = mfma16(a1h, b1h, acc11);
    acc00 = mfma16(a0h, b0l, acc00);
    acc01 = mfma16(a0h, b1l, acc01);
    acc10 = mfma16(a1h, b0l, acc10);
    acc11 = mfma16(a1h, b1l, acc11);
    acc00 = mfma16(a0l, b0h, acc00);
    acc01 = mfma16(a0l, b1h, acc01);
    acc10 = mfma16(a1l, b0h, acc10);
    acc11 = mfma16(a1l, b1h, acc11);
  }
  int crow = (lane >> 4) << 2;
  int ccol = lane & 15;
  f32x4 accs[2][2] = {{acc00, acc01}, {acc10, acc11}};
#pragma unroll
  for (int i = 0; i < 2; ++i)
#pragma unroll
    for (int j = 0; j < 2; ++j) {
      int r0 = bm * 64 + wm + 16 * i + crow;
      int c0 = bn * 64 + wn + 16 * j + ccol;
#pragma unroll
      for (int rg = 0; rg < 4; ++rg) {
        float v = accs[i][j][rg] * alpha;
        if constexpr (BIAS) v += bias[c0];
        Cb[(size_t)(r0 + rg) * Nc + c0] = v;
      }
    }
}

// ---------------------------------------------------------------------------
// Split-precision NT GEMM, 128x128 tile, global_load_lds staging, XOR swizzle.
// ---------------------------------------------------------------------------
__global__ __launch_bounds__(256) void gemm3_big(
    const h16* __restrict__ Ah, const h16* __restrict__ Al,
    const h16* __restrict__ Bh, const h16* __restrict__ Bl,
    float* __restrict__ C, float alpha, int M, int Nc, int Kd) {
  __shared__ h16 sAh[128 * 32], sAl[128 * 32], sBh[128 * 32], sBl[128 * 32];
  int tid = threadIdx.x, wid = tid >> 6, lane = tid & 63;
  int bm = blockIdx.y, bn = blockIdx.x;
  int srow = 32 * wid + (lane >> 2);
  int scnk = lane & 3;
  int fr = lane & 15, fcc = lane >> 4;
  f32x4 acc[4][4] = {};
  const h16* gA[2] = {Ah, Al};
  const h16* gB[2] = {Bh, Bl};
  h16* sA[2] = {sAh, sAl};
  h16* sB[2] = {sBh, sBl};
  int wm = (wid & 1) * 64, wn = (wid >> 1) * 64;
  for (int k0 = 0; k0 < Kd; k0 += 32) {
    __syncthreads();
#pragma unroll
    for (int h = 0; h < 2; ++h) {
      int r = srow + 16 * h;
      int cs = scnk ^ ((r >> 1) & 3);
      size_t goffA = (size_t)(bm * 128 + r) * Kd + k0 + cs * 8;
      size_t goffB = (size_t)(bn * 128 + r) * Kd + k0 + cs * 8;
      int loff = (32 * wid + 16 * h) * 32;
#pragma unroll
      for (int p = 0; p < 2; ++p) {
        gl_lds16(gA[p] + goffA, sA[p] + loff);
        gl_lds16(gB[p] + goffB, sB[p] + loff);
      }
    }
    __syncthreads();
    h16x8 fa[2][4], fb[2][4];
#pragma unroll
    for (int i = 0; i < 4; ++i) {
      int ra = wm + 16 * i + fr;
      int ca = (fcc ^ ((ra >> 1) & 3)) * 8;
      fa[0][i] = *(const h16x8*)(sAh + ra * 32 + ca);
      fa[1][i] = *(const h16x8*)(sAl + ra * 32 + ca);
      int rb = wn + 16 * i + fr;
      int cb = (fcc ^ ((rb >> 1) & 3)) * 8;
      fb[0][i] = *(const h16x8*)(sBh + rb * 32 + cb);
      fb[1][i] = *(const h16x8*)(sBl + rb * 32 + cb);
    }
#pragma unroll
    for (int i = 0; i < 4; ++i)
#pragma unroll
      for (int j = 0; j < 4; ++j) {
        acc[i][j] = mfma16(fa[0][i], fb[0][j], acc[i][j]);
        acc[i][j] = mfma16(fa[0][i], fb[1][j], acc[i][j]);
        acc[i][j] = mfma16(fa[1][i], fb[0][j], acc[i][j]);
      }
  }
  int crow = (lane >> 4) << 2, ccol = lane & 15;
#pragma unroll
  for (int i = 0; i < 4; ++i)
#pragma unroll
    for (int j = 0; j < 4; ++j) {
      int r0 = bm * 128 + wm + 16 * i + crow;
      int c0 = bn * 128 + wn + 16 * j + ccol;
#pragma unroll
      for (int rg = 0; rg < 4; ++rg)
        C[(size_t)(r0 + rg) * Nc + c0] = acc[i][j][rg] * alpha;
    }
}

// ---------------------------------------------------------------------------
// fp16 NT GEMM for all 4 heads' E@X, K-split: z = head*4 + kslice (Kc=1024).
// 128x128 tile, bn in {0,1}. Writes f32 partials Cpart[z][4096][256].
// (round-10 measured config: 92 VGPR, 16 KB LDS, 1024 blocks = 4/CU)
// ---------------------------------------------------------------------------
__global__ __launch_bounds__(256) void gemm_ks4(
    const h16* __restrict__ Eall, const h16* __restrict__ B,
    float* __restrict__ Cpart) {
  __shared__ h16 sA[128 * 32], sB[128 * 32];
  int tid = threadIdx.x, wid = tid >> 6, lane = tid & 63;
  int bm = blockIdx.y, bn = blockIdx.x, zz = blockIdx.z;  // grid (2, 32, 16)
  int head = zz >> 2, kz = zz & 3;
  const h16* A = Eall + (size_t)head * 4096 * 4096;
  int kbase = kz * 1024;
  int srow = 32 * wid + (lane >> 2);
  int scnk = lane & 3;
  int fr = lane & 15, fcc = lane >> 4;
  f32x4 acc[4][4] = {};
  int wm = (wid & 1) * 64, wn = (wid >> 1) * 64;
  for (int k0 = 0; k0 < 1024; k0 += 32) {
    __syncthreads();
#pragma unroll
    for (int h = 0; h < 2; ++h) {
      int r = srow + 16 * h;
      int cs = scnk ^ ((r >> 1) & 3);
      size_t goffA = (size_t)(bm * 128 + r) * 4096 + kbase + k0 + cs * 8;
      size_t goffB = (size_t)(bn * 128 + r) * 4096 + kbase + k0 + cs * 8;
      int loff = (32 * wid + 16 * h) * 32;
      gl_lds16(A + goffA, sA + loff);
      gl_lds16(B + goffB, sB + loff);
    }
    __syncthreads();
    h16x8 fa[4], fb[4];
#pragma unroll
    for (int i = 0; i < 4; ++i) {
      int ra = wm + 16 * i + fr;
      int ca = (fcc ^ ((ra >> 1) & 3)) * 8;
      fa[i] = *(const h16x8*)(sA + ra * 32 + ca);
      int rb = wn + 16 * i + fr;
      int cb = (fcc ^ ((rb >> 1) & 3)) * 8;
      fb[i] = *(const h16x8*)(sB + rb * 32 + cb);
    }
#pragma unroll
    for (int i = 0; i < 4; ++i)
#pragma unroll
      for (int j = 0; j < 4; ++j)
        acc[i][j] = mfma16(fa[i], fb[j], acc[i][j]);
  }
  float* Cp = Cpart + (size_t)zz * 4096 * 256;
  int crow = (lane >> 4) << 2, ccol = lane & 15;
#pragma unroll
  for (int i = 0; i < 4; ++i)
#pragma unroll
    for (int j = 0; j < 4; ++j) {
      int r0 = bm * 128 + wm + 16 * i + crow;
      int c0 = bn * 128 + wn + 16 * j + ccol;
#pragma unroll
      for (int rg = 0; rg < 4; ++rg)
        Cp[(size_t)(r0 + rg) * 256 + c0] = acc[i][j][rg];
    }
}

// Zk = sum_k scal[k] * rowSinv[k][row] * sum_{z in head k} Cpart[z]
__global__ __launch_bounds__(256) void ks_reduce4(
    const float* __restrict__ Cpart, const float* __restrict__ scal,
    const float* __restrict__ rowSinv, float* __restrict__ Zk) {
  int i = (blockIdx.x * 256 + threadIdx.x) * 4;  // grid 1024
  int row = i >> 8;
  float4 out = {0.f, 0.f, 0.f, 0.f};
#pragma unroll
  for (int k = 0; k < 4; ++k) {
    float4 s = {0.f, 0.f, 0.f, 0.f};
#pragma unroll
    for (int z = 0; z < 4; ++z) {
      float4 p = *(const float4*)(Cpart + (size_t)(k * 4 + z) * 4096 * 256 + i);
      s.x += p.x; s.y += p.y; s.z += p.z; s.w += p.w;
    }
    float sc = scal[k] * rowSinv[k * 4096 + row];
    out.x += sc * s.x; out.y += sc * s.y;
    out.z += sc * s.z; out.w += sc * s.w;
  }
  *(float4*)(Zk + i) = out;
}

// 16-bit transpose
__global__ __launch_bounds__(256) void transpose16(
    const u16* __restrict__ in, u16* __restrict__ out, int rows, int cols) {
  __shared__ u16 t[32][33];
  const u16* ib = in + (size_t)blockIdx.z * rows * cols;
  u16* ob = out + (size_t)blockIdx.z * rows * cols;
  int r0 = blockIdx.x * 32, c0 = blockIdx.y * 32;
  int tx = threadIdx.x & 31, ty = threadIdx.x >> 5;
#pragma unroll
  for (int i = 0; i < 32; i += 8)
    t[ty + i][tx] = ib[(size_t)(r0 + ty + i) * cols + c0 + tx];
  __syncthreads();
#pragma unroll
  for (int i = 0; i < 32; i += 8)
    ob[(size_t)(c0 + ty + i) * rows + r0 + tx] = t[tx][ty + i];
}

// ---------------------------------------------------------------------------
// fused per-row (one wave per row): max -> threshold T -> exp/E-write +
// candidate push -> exact jax-tiebreak top-16 from candidates
// ---------------------------------------------------------------------------
__global__ __launch_bounds__(256) void row_softmax_topk(
    const float* __restrict__ A, float* __restrict__ topv,
    int* __restrict__ topi, h16* __restrict__ E, float* __restrict__ rowSinvK,
    int khead) {
  __shared__ u64 candK[4][256];
  __shared__ int candN[4];
  int wid = threadIdx.x >> 6, lane = threadIdx.x & 63;
  int row = blockIdx.x * 4 + wid;
  const float* arow = A + ((size_t)row << 12);
  if (lane == 0) candN[wid] = 0;
  __syncthreads();
  float lm = -INFINITY;
#pragma unroll
  for (int t = 0; t < 16; ++t) {
    float4 v = *(const float4*)(arow + (t << 8) + (lane << 2));
    lm = fmaxf(lm, fmaxf(fmaxf(v.x, v.y), fmaxf(v.z, v.w)));
  }
  float m = lm;
#pragma unroll
  for (int off = 32; off; off >>= 1) m = fmaxf(m, __shfl_xor(m, off));
  u64 lk = ((u64)fkey(lm) << 32) | (unsigned)lane;
  float T = 0.f;
  for (int r = 0; r < 16; ++r) {
    u64 k2 = wave_max_u64(lk);
    if (lk == k2) lk = 0;
    if (r == 15) T = unfkey((unsigned)(k2 >> 32));
  }
  h16* erow = E + ((size_t)row << 12);
  int* cn = &candN[wid];
  u64* ck = candK[wid];
  float s = 0.f;
  for (int t = 0; t < 16; ++t) {
    int c = (t << 8) + (lane << 2);
    float4 v = *(const float4*)(arow + c);
    float e0 = __expf(v.x - m), e1 = __expf(v.y - m);
    float e2 = __expf(v.z - m), e3 = __expf(v.w - m);
    s += (e0 + e1) + (e2 + e3);
    h16x4 hv = {(h16)e0, (h16)e1, (h16)e2, (h16)e3};
    *(h16x4*)(erow + c) = hv;
    if (v.x >= T) {
      int sl = atomicAdd(cn, 1);
      if (sl < 256) ck[sl] = ((u64)fkey(v.x) << 32) | (unsigned)(~(unsigned)c);
    }
    if (v.y >= T) {
      int sl = atomicAdd(cn, 1);
      if (sl < 256) ck[sl] = ((u64)fkey(v.y) << 32) | (unsigned)(~(unsigned)(c + 1));
    }
    if (v.z >= T) {
      int sl = atomicAdd(cn, 1);
      if (sl < 256) ck[sl] = ((u64)fkey(v.z) << 32) | (unsigned)(~(unsigned)(c + 2));
    }
    if (v.w >= T) {
      int sl = atomicAdd(cn, 1);
      if (sl < 256) ck[sl] = ((u64)fkey(v.w) << 32) | (unsigned)(~(unsigned)(c + 3));
    }
  }
#pragma unroll
  for (int off = 32; off; off >>= 1) s += __shfl_xor(s, off);
  if (lane == 0) rowSinvK[row] = 1.f / s;
  __syncthreads();
  int cnt = min(*cn, 256);
  u64 loc[4] = {0ull, 0ull, 0ull, 0ull};
  int nl = 0;
  for (int j = lane; j < cnt; j += 64)
    if (nl < 4) loc[nl++] = ck[j];
#define CSW(a, b)                     \
  {                                   \
    if (loc[b] > loc[a]) {            \
      u64 tt = loc[a];                \
      loc[a] = loc[b];                \
      loc[b] = tt;                    \
    }                                 \
  }
  CSW(0, 1) CSW(2, 3) CSW(0, 2) CSW(1, 3) CSW(1, 2)
#undef CSW
  float myv = 0.f;
  int myi = 0;
  float sum16 = 0.f;
  for (int r = 0; r < 16; ++r) {
    u64 key = loc[0];
    u64 k2 = wave_max_u64(key);
    float wv = unfkey((unsigned)(k2 >> 32));
    int wi = (int)(~(unsigned)(k2 & 0xffffffffu));
    if (key == k2 && key != 0ull) {
      loc[0] = loc[1];
      loc[1] = loc[2];
      loc[2] = loc[3];
      loc[3] = 0ull;
    }
    sum16 += expf(wv - m);
    if (r == lane) { myv = wv; myi = wi; }
  }
  if (lane < 16) {
    size_t o = (((size_t)khead << 12) + row) * 16 + lane;
    topv[o] = expf(myv - m) / (sum16 + 1e-9f * s);
    topi[o] = myi;
  }
}

// ---------------------------------------------------------------------------
// sparse hypergraph build — atomic-free two-level LDS histogram (+DeIS fused)
// ---------------------------------------------------------------------------
__global__ __launch_bounds__(256) void hist_part(
    const float* __restrict__ topv, const int* __restrict__ topi,
    int* __restrict__ pCnt, float* __restrict__ pDv,
    float* __restrict__ DeIS) {
  __shared__ int lc[4096];
  __shared__ float ld[4096];
  int tid = threadIdx.x, b = blockIdx.x;  // grid 64
  for (int j = tid; j < 4096; j += 256) { lc[j] = 0; ld[j] = 0.f; }
  __syncthreads();
  int base = b * 4096;
#pragma unroll
  for (int j = 0; j < 16; ++j) {
    int t = base + j * 256 + tid;
    atomicAdd(&lc[topi[t]], 1);
    atomicAdd(&ld[topi[t]], topv[t]);
  }
  __syncthreads();
  for (int j = tid; j < 4096; j += 256) {
    pCnt[base + j] = lc[j];
    pDv[base + j] = ld[j];
  }
  int e = b * 256 + tid;
  const float4* p = (const float4*)(topv + ((size_t)e << 4));
  float4 a = p[0], bb = p[1], c = p[2], d = p[3];
  float s = ((a.x + a.y) + (a.z + a.w)) + ((bb.x + bb.y) + (bb.z + bb.w)) +
            ((c.x + c.y) + (c.z + c.w)) + ((d.x + d.y) + (d.z + d.w));
  DeIS[e] = 1.0f / sqrtf(s + 1e-9f);
}

// per-bin reduce over 64 blocks: cnt, Dvis, block prefix; + fused v0 init
__global__ __launch_bounds__(256) void col_scan(
    const int* __restrict__ pCnt, const float* __restrict__ pDv,
    int* __restrict__ cnt, float* __restrict__ Dvis,
    int* __restrict__ blockBase, float* __restrict__ v0) {
  int i = blockIdx.x * 256 + threadIdx.x;  // grid 16 -> 4096
  int run = 0;
  float dv = 0.f;
#pragma unroll
  for (int b = 0; b < 64; ++b) {
    blockBase[b * 4096 + i] = run;
    run += pCnt[b * 4096 + i];
    dv += pDv[b * 4096 + i];
  }
  cnt[i] = run;
  Dvis[i] = sqrtf(1.0f / (dv + 1e-9f));
  {
    int tid = i;
    unsigned j = (unsigned)(tid & 2047);
    unsigned x0 = j, x1 = j + 2048u;
    const unsigned ks0 = 0u, ks1 = 1u, ks2 = 0x1BD11BDAu;
#define TF_R(r)                                \
    {                                          \
      x0 += x1;                                \
      x1 = (x1 << (r)) | (x1 >> (32 - (r)));   \
      x1 ^= x0;                                \
    }
    x0 += ks0; x1 += ks1;
    TF_R(13) TF_R(15) TF_R(26) TF_R(6)  x0 += ks1; x1 += ks2 + 1u;
    TF_R(17) TF_R(29) TF_R(16) TF_R(24) x0 += ks2; x1 += ks0 + 2u;
    TF_R(13) TF_R(15) TF_R(26) TF_R(6)  x0 += ks0; x1 += ks1 + 3u;
    TF_R(17) TF_R(29) TF_R(16) TF_R(24) x0 += ks1; x1 += ks2 + 4u;
    TF_R(13) TF_R(15) TF_R(26) TF_R(6)  x0 += ks2; x1 += ks0 + 5u;
#undef TF_R
    unsigned bits = (tid < 2048) ? x0 : x1;
    float u01 = __uint_as_float((bits >> 9) | 0x3f800000u) - 1.0f;
    const float lo = -0.99999994f;
    float u = fmaxf(lo, u01 * 2.0f + lo);
    float w = -log1pf(-u * u);
    float p;
    if (w < 5.0f) {
      float t = w - 2.5f;
      p = 2.81022636e-08f;
      p = 3.43273939e-07f + p * t;
      p = -3.5233877e-06f + p * t;
      p = -4.39150654e-06f + p * t;
      p = 0.00021858087f + p * t;
      p = -0.00125372503f + p * t;
      p = -0.00417768164f + p * t;
      p = 0.246640727f + p * t;
      p = 1.50140941f + p * t;
    } else {
      float t = sqrtf(w) - 3.0f;
      p = -0.000200214257f;
      p = 0.000100950558f + p * t;
      p = 0.00134934322f + p * t;
      p = -0.00367342844f + p * t;
      p = 0.00573950773f + p * t;
      p = -0.0076224613f + p * t;
      p = 0.00943887047f + p * t;
      p = 1.00167406f + p * t;
      p = 2.83297682f + p * t;
    }
    v0[tid] = 1.41421354f * (p * u);
  }
}

// exclusive scan of cnt[4096] -> rowptr[4097]
__global__ __launch_bounds__(256) void scan_rowptr(const int* __restrict__ cnt,
                                                   int* __restrict__ rowptr) {
  __shared__ int part[256];
  int tid = threadIdx.x;
  int base = tid * 16;
  int loc[16];
  int s = 0;
#pragma unroll
  for (int j = 0; j < 16; ++j) { loc[j] = s; s += cnt[base + j]; }
  part[tid] = s;
  __syncthreads();
  for (int off = 1; off < 256; off <<= 1) {
    int v = (tid >= off) ? part[tid - off] : 0;
    __syncthreads();
    part[tid] += v;
    __syncthreads();
  }
  int pre = (tid == 0) ? 0 : part[tid - 1];
#pragma unroll
  for (int j = 0; j < 16; ++j) rowptr[base + j] = pre + loc[j];
  if (tid == 255) rowptr[4096] = part[255];
}

// fill cvals + CSR transpose via LDS cursors (no global atomics)
__global__ __launch_bounds__(256) void csr_fill3(
    const float* __restrict__ topv, const int* __restrict__ topi,
    const float* __restrict__ Dvis, const float* __restrict__ DeIS,
    const int* __restrict__ rowptr, const int* __restrict__ blockBase,
    float* __restrict__ cvals, int* __restrict__ colE,
    float* __restrict__ cvalR) {
  __shared__ int lcur[4096];
  int tid = threadIdx.x, b = blockIdx.x;  // grid 64
  int base = b * 4096;
  for (int j = tid; j < 4096; j += 256)
    lcur[j] = rowptr[j] + blockBase[base + j];
  __syncthreads();
#pragma unroll
  for (int j = 0; j < 16; ++j) {
    int t = base + j * 256 + tid;
    int i = topi[t];
    int e = t >> 4;
    float c = Dvis[i] * topv[t] * DeIS[e];
    cvals[t] = c;
    int slot = atomicAdd(&lcur[i], 1);
    colE[slot] = e;
    cvalR[slot] = c;
  }
}

// g[e] = sum_p c[e,p] * v[idx[e,p]]
__global__ __launch_bounds__(256) void spmv_edge(
    const float* __restrict__ cvals, const int* __restrict__ topi,
    const float* __restrict__ v, float* __restrict__ g) {
  int e = blockIdx.x * 256 + threadIdx.x;  // grid 64
  float acc = 0.f;
#pragma unroll
  for (int p = 0; p < 16; ++p)
    acc += cvals[e * 16 + p] * v[topi[e * 16 + p]];
  g[e] = acc;
}

// vout[i] = vin[i] - sum_{j in row i} cvalR[j]*g[colE[j]]
__global__ __launch_bounds__(256) void spmv_row(
    const int* __restrict__ rowptr, const int* __restrict__ colE,
    const float* __restrict__ cvalR, const float* __restrict__ g,
    const float* __restrict__ vin, float* __restrict__ vout) {
  int wid = threadIdx.x >> 6, lane = threadIdx.x & 63;
  int row = blockIdx.x * 4 + wid;  // grid 1024
  int s = rowptr[row], e = rowptr[row + 1];
  float acc = 0.f;
  for (int j = s + lane; j < e; j += 64) acc += cvalR[j] * g[colE[j]];
#pragma unroll
  for (int off = 32; off; off >>= 1) acc += __shfl_xor(acc, off);
  if (lane == 0) vout[row] = vin[row] - acc;
}

// lam = clip((w5.w6)/(w5.w5), 1e-3) -> scal[5]
__global__ __launch_bounds__(256) void pi_dots(const float* __restrict__ w5,
                                               const float* __restrict__ w6,
                                               float* __restrict__ scal) {
  __shared__ float r1[256], r2[256];
  int tid = threadIdx.x;
  float a = 0.f, b = 0.f;
  for (int i = tid; i < 4096; i += 256) {
    float x = w5[i];
    a += x * x;
    b += x * w6[i];
  }
  r1[tid] = a; r2[tid] = b;
  __syncthreads();
  for (int off = 128; off; off >>= 1) {
    if (tid < off) { r1[tid] += r1[tid + off]; r2[tid] += r2[tid + off]; }
    __syncthreads();
  }
  if (tid == 0) scal[5] = fmaxf(r2[0] / r1[0], 1e-3f);
}

// G[e,:] = sum_p c[e,p] * M[idx[e,p],:]  — MLP-unrolled
__global__ __launch_bounds__(256) void spmm_edge(
    const float* __restrict__ cvals, const int* __restrict__ topi,
    const float* __restrict__ M, float* __restrict__ G) {
  int wid = threadIdx.x >> 6, lane = threadIdx.x & 63;
  int e = blockIdx.x * 4 + wid;  // grid 4096
  int cb = lane << 2;
  const float* cv = cvals + ((size_t)e << 4);
  const int* ti = topi + ((size_t)e << 4);
  float cc[16];
  int ix[16];
#pragma unroll
  for (int p = 0; p < 16; ++p) { cc[p] = cv[p]; ix[p] = ti[p]; }
  float4 acc[4] = {};
#pragma unroll
  for (int h = 0; h < 2; ++h) {
    float4 g[8];
#pragma unroll
    for (int p = 0; p < 8; ++p)
      g[p] = *(const float4*)(M + ((size_t)ix[h * 8 + p] << 8) + cb);
#pragma unroll
    for (int p = 0; p < 8; ++p) {
      float c = cc[h * 8 + p];
      float4 gg = g[p];
      int a = p & 3;
      acc[a].x += c * gg.x; acc[a].y += c * gg.y;
      acc[a].z += c * gg.z; acc[a].w += c * gg.w;
    }
  }
  float4 r;
  r.x = (acc[0].x + acc[1].x) + (acc[2].x + acc[3].x);
  r.y = (acc[0].y + acc[1].y) + (acc[2].y + acc[3].y);
  r.z = (acc[0].z + acc[1].z) + (acc[2].z + acc[3].z);
  r.w = (acc[0].w + acc[1].w) + (acc[2].w + acc[3].w);
  *(float4*)(G + ((size_t)e << 8) + cb) = r;
}

// Z = S_norm @ M via CSR rows + fused epilogues
template <int MODE>
__global__ __launch_bounds__(256) void spmm_row_ep(
    const int* __restrict__ rowptr, const int* __restrict__ colE,
    const float* __restrict__ cvalR, const float* __restrict__ G,
    const float* __restrict__ Xf, float* __restrict__ T1,
    const float* __restrict__ Zk, const float* __restrict__ thetaf,
    const float* __restrict__ scal, h16* __restrict__ Zmh,
    h16* __restrict__ Zml) {
  int wid = threadIdx.x >> 6, lane = threadIdx.x & 63;
  int row = blockIdx.x * 4 + wid;  // grid 1024
  int cb = lane << 2;
  int s = rowptr[row], e = rowptr[row + 1];
  float4 acc[4] = {};
  int j = s;
  for (; j + 8 <= e; j += 8) {
    int ix[8];
    float cc[8];
#pragma unroll
    for (int t = 0; t < 8; ++t) { ix[t] = colE[j + t]; cc[t] = cvalR[j + t]; }
    float4 g[8];
#pragma unroll
    for (int t = 0; t < 8; ++t)
      g[t] = *(const float4*)(G + ((size_t)ix[t] << 8) + cb);
#pragma unroll
    for (int t = 0; t < 8; ++t) {
      float c = cc[t];
      float4 gg = g[t];
      int a = t & 3;
      acc[a].x += c * gg.x; acc[a].y += c * gg.y;
      acc[a].z += c * gg.z; acc[a].w += c * gg.w;
    }
  }
  for (; j < e; ++j) {
    float c = cvalR[j];
    float4 gg = *(const float4*)(G + ((size_t)colE[j] << 8) + cb);
    acc[0].x += c * gg.x; acc[0].y += c * gg.y;
    acc[0].z += c * gg.z; acc[0].w += c * gg.w;
  }
  float4 z;
  z.x = (acc[0].x + acc[1].x) + (acc[2].x + acc[3].x);
  z.y = (acc[0].y + acc[1].y) + (acc[2].y + acc[3].y);
  z.z = (acc[0].z + acc[1].z) + (acc[2].z + acc[3].z);
  z.w = (acc[0].w + acc[1].w) + (acc[2].w + acc[3].w);
  size_t o = ((size_t)row << 8) + cb;
  float c1 = 2.0f / scal[5];
  float4 x = *(const float4*)(Xf + o);
  if constexpr (MODE == 1) {
    float4 t1;
    t1.x = (c1 - 1.0f) * x.x - c1 * z.x;
    t1.y = (c1 - 1.0f) * x.y - c1 * z.y;
    t1.z = (c1 - 1.0f) * x.z - c1 * z.z;
    t1.w = (c1 - 1.0f) * x.w - c1 * z.w;
    *(float4*)(T1 + o) = t1;
  } else {
    float rho = scal[4];
    float4 t1 = *(const float4*)(T1 + o);
    float4 zk = *(const float4*)(Zk + o);
    h16x4 hh, hl;
#pragma unroll
    for (int q = 0; q < 4; ++q) {
      float xv = (&x.x)[q], t1v = (&t1.x)[q], zv = (&z.x)[q], zkv = (&zk.x)[q];
      int d = cb + q;
      float t2 = 2.0f * ((c1 - 1.0f) * t1v - c1 * zv) - xv;
      float oo = xv * thetaf[d] + t1v * thetaf[256 + d] + t2 * thetaf[512 + d];
      float zs = oo > 0.0f ? oo : expm1f(oo);
      float zm = rho * zs + (1.0f - rho) * zkv;
      h16 h = (h16)zm;
      hh[q] = h;
      hl[q] = (h16)(zm - (float)h);
    }
    *(h16x4*)(Zmh + o) = hh;
    *(h16x4*)(Zml + o) = hl;
  }
}

// ---------------------------------------------------------------------------
extern "C" void kernel_launch(void* const* d_in, const int* in_sizes, int n_in,
                              void* d_out, int out_size, void* d_ws,
                              size_t ws_size, hipStream_t stream) {
  (void)in_sizes; (void)n_in; (void)out_size;
  const void* Xin = d_in[0];
  const void* Lin = d_in[1];
  const void* alpha = d_in[2];
  const void* theta = d_in[3];
  const void* rho_raw = d_in[4];
  const void* Wpin = d_in[5];
  const void* bpin = d_in[6];
  float* out = (float*)d_out;

  char* base = (char*)d_ws;
  size_t off = 0;
  auto alloc = [&](size_t bytes) -> char* {
    char* p = base + off;
    off += (bytes + 255) & ~(size_t)255;
    return p;
  };
  float* Abuf = (float*)alloc((size_t)4096 * 4096 * 4);   // A; 16 ks-partials; G
  h16* Eall = (h16*)alloc((size_t)4 * 4096 * 4096 * 2);   // 4 E planes (Yf alias)
  h16* Yhi = (h16*)alloc((size_t)4 * 4096 * 256 * 2);
  h16* Ylo = (h16*)alloc((size_t)4 * 4096 * 256 * 2);
  h16* Xhi = (h16*)alloc((size_t)4096 * 256 * 2);
  h16* Xlo = (h16*)alloc((size_t)4096 * 256 * 2);
  float* Xf = (float*)alloc((size_t)4096 * 256 * 4);
  h16* XT = (h16*)alloc((size_t)256 * 4096 * 2);
  h16* Lhi = (h16*)alloc((size_t)4 * 256 * 256 * 2);
  h16* Llo = (h16*)alloc((size_t)4 * 256 * 256 * 2);
  h16* LThi = (h16*)alloc((size_t)4 * 256 * 256 * 2);
  h16* LTlo = (h16*)alloc((size_t)4 * 256 * 256 * 2);
  h16* Whi = (h16*)alloc((size_t)256 * 256 * 2);
  h16* Wlo = (h16*)alloc((size_t)256 * 256 * 2);
  float* Zk = (float*)alloc((size_t)4096 * 256 * 4);
  float* T1 = (float*)alloc((size_t)4096 * 256 * 4);
  h16* Zmh = (h16*)alloc((size_t)4096 * 256 * 2);
  h16* Zml = (h16*)alloc((size_t)4096 * 256 * 2);
  float* topv = (float*)alloc((size_t)4 * 4096 * 16 * 4);
  int* topi = (int*)alloc((size_t)4 * 4096 * 16 * 4);
  float* cvals = (float*)alloc((size_t)262144 * 4);
  int* colE = (int*)alloc((size_t)262144 * 4);
  float* cvalR = (float*)alloc((size_t)262144 * 4);
  int* pCnt = (int*)alloc((size_t)64 * 4096 * 4);
  float* pDv = (float*)alloc((size_t)64 * 4096 * 4);
  int* blockBase = (int*)alloc((size_t)64 * 4096 * 4);
  int* rowptr = (int*)alloc(4097 * 4);
  int* cnt = (int*)alloc(4096 * 4);
  float* Dvis = (float*)alloc(4096 * 4);
  float* DeIS = (float*)alloc(16384 * 4);
  float* gE = (float*)alloc(16384 * 4);
  float* wA = (float*)alloc(4096 * 4);
  float* wB = (float*)alloc(4096 * 4);
  float* rowSinv = (float*)alloc((size_t)4 * 4096 * 4);
  float* thetaf = (float*)alloc(768 * 4);
  float* biasf = (float*)alloc(256 * 4);
  float* scal = (float*)alloc(256);
  int* flag = (int*)alloc(256);
  if (off > ws_size) return;
  float* Yf = (float*)Eall;  // 16 MB alias; dead before E planes written
  float* Kpart = Abuf;       // 64 MB: 16 partial planes; A dead by then
  float* G = (float*)Abuf;   // 16 MB alias; partials dead after ks_reduce4

  detect_dtype<<<1, 256, 0, stream>>>((const u16*)Xin, flag);
  split_input3<<<1024, 256, 0, stream>>>(Xin, Xhi, Xlo, Xf, 4096 * 256, flag);
  split_LW<<<320, 256, 0, stream>>>(Lin, Lhi, Llo, Wpin, Whi, Wlo, flag);
  prep_small<<<1, 1024, 0, stream>>>(theta, bpin, alpha, rho_raw, thetaf, biasf,
                                     scal, flag);
  transpose16<<<dim3(128, 8, 1), 256, 0, stream>>>((const u16*)Xhi, (u16*)XT,
                                                   4096, 256);
  transpose16<<<dim3(8, 8, 4), 256, 0, stream>>>((const u16*)Lhi, (u16*)LThi,
                                                 256, 256);
  transpose16<<<dim3(8, 8, 4), 256, 0, stream>>>((const u16*)Llo, (u16*)LTlo,
                                                 256, 256);
  // Yf = X @ L_k (split fp16, fused), batched z=4
  gemm3_nt<false><<<dim3(4, 64, 4), 256, 0, stream>>>(
      Xhi, Xlo, LThi, LTlo, Yf, nullptr, 1.0f, 4096, 256, 256,
      0L, 256L * 256L, 4096L * 256L);
  split_f32h<<<2048, 256, 0, stream>>>(Yf, Yhi, Ylo, 4 * 4096 * 256);
  for (int k = 0; k < 4; ++k) {
    gemm3_big<<<dim3(32, 32), 256, 0, stream>>>(
        Yhi + (size_t)k * 4096 * 256, Ylo + (size_t)k * 4096 * 256, Xhi, Xlo,
        Abuf, 0.0625f, 4096, 4096, 256);
    row_softmax_topk<<<1024, 256, 0, stream>>>(
        Abuf, topv, topi, Eall + (size_t)k * 4096 * 4096, rowSinv + k * 4096,
        k);
  }
  // all 4 heads' E @ X in one K-split launch (round-10 config: 1024 blocks)
  gemm_ks4<<<dim3(2, 32, 16), 256, 0, stream>>>(Eall, XT, Kpart);
  ks_reduce4<<<1024, 256, 0, stream>>>(Kpart, scal, rowSinv, Zk);
  // sparse hypergraph Laplacian — atomic-free two-level histogram build
  hist_part<<<64, 256, 0, stream>>>(topv, topi, pCnt, pDv, DeIS);
  col_scan<<<16, 256, 0, stream>>>(pCnt, pDv, cnt, Dvis, blockBase, wA);
  scan_rowptr<<<1, 256, 0, stream>>>(cnt, rowptr);
  csr_fill3<<<64, 256, 0, stream>>>(topv, topi, Dvis, DeIS, rowptr, blockBase,
                                    cvals, colE, cvalR);
  // power iteration (regular launches — cooperative launch fails graph capture)
  for (int it = 0; it < 6; ++it) {
    const float* vi = (it & 1) ? wB : wA;
    float* vo = (it & 1) ? wA : wB;
    spmv_edge<<<64, 256, 0, stream>>>(cvals, topi, vi, gE);
    spmv_row<<<1024, 256, 0, stream>>>(rowptr, colE, cvalR, gE, vi, vo);
  }
  pi_dots<<<1, 256, 0, stream>>>(wB, wA, scal);
  // SnX -> T1 (fused) ; SnT1 -> cheb/elu/mix -> Zmh/Zml (fused)
  spmm_edge<<<4096, 256, 0, stream>>>(cvals, topi, Xf, G);
  spmm_row_ep<1><<<1024, 256, 0, stream>>>(rowptr, colE, cvalR, G, Xf, T1,
                                           nullptr, thetaf, scal, nullptr,
                                           nullptr);
  spmm_edge<<<4096, 256, 0, stream>>>(cvals, topi, T1, G);
  spmm_row_ep<2><<<1024, 256, 0, stream>>>(rowptr, colE, cvalR, G, Xf, T1, Zk,
                                           thetaf, scal, Zmh, Zml);
  // out = Zmix @ proj_w^T + proj_b (split fp16, f32 out)
  gemm3_nt<true><<<dim3(4, 64, 1), 256, 0, stream>>>(
      Zmh, Zml, Whi, Wlo, out, biasf, 1.0f, 4096, 256, 256, 0L, 0L, 0L);
}

// Round 14
// 662.643 us; speedup vs baseline: 1.9380x; 1.0081x over previous
//
#include <hip/hip_runtime.h>

typedef unsigned short u16;
typedef unsigned long long u64;
typedef _Float16 h16;
typedef __attribute__((ext_vector_type(8))) _Float16 h16x8;
typedef __attribute__((ext_vector_type(4))) _Float16 h16x4;
typedef __attribute__((ext_vector_type(4))) float f32x4;

__device__ __forceinline__ float b2f(u16 u) {
  unsigned x = ((unsigned)u) << 16;
  return __uint_as_float(x);
}
__device__ __forceinline__ unsigned fkey(float f) {
  unsigned b = __float_as_uint(f);
  return (b & 0x80000000u) ? ~b : (b | 0x80000000u);
}
__device__ __forceinline__ float unfkey(unsigned u) {
  unsigned b = (u & 0x80000000u) ? (u ^ 0x80000000u) : ~u;
  return __uint_as_float(b);
}
__device__ __forceinline__ f32x4 mfma16(h16x8 a, h16x8 b, f32x4 c) {
  return __builtin_amdgcn_mfma_f32_16x16x32_f16(a, b, c, 0, 0, 0);
}
__device__ __forceinline__ void gl_lds16(const void* g, void* l) {
  __builtin_amdgcn_global_load_lds(
      (const __attribute__((address_space(1))) unsigned*)g,
      (__attribute__((address_space(3))) unsigned*)l, 16, 0, 0);
}
__device__ __forceinline__ u64 wave_max_u64(u64 k) {
#pragma unroll
  for (int off = 32; off; off >>= 1) {
    u64 o = __shfl_xor(k, off);
    if (o > k) k = o;
  }
  return k;
}
__device__ __forceinline__ float cvt_in(const void* p, int i, int f) {
  return f ? ((const float*)p)[i] : b2f(((const u16*)p)[i]);
}

// per-block dtype detection from X's first 8192 u16 slots (same sample set
// as the old detect_dtype kernel); returns 1 if inputs are f32 (expected)
__device__ __forceinline__ int detect_f32_local(const u16* __restrict__ X) {
  __shared__ int dcnt;
  if (threadIdx.x == 0) dcnt = 0;
  __syncthreads();
  int sane = 0;
  for (int j = threadIdx.x; j < 4096; j += blockDim.x) {
    u16 u = X[j * 2];
    int e = (u >> 7) & 0xff;
    if (u == 0 || (e >= 112 && e <= 142)) sane++;
  }
  atomicAdd(&dcnt, sane);
  __syncthreads();
  return (dcnt < 3072) ? 1 : 0;
}

// split X to hi/lo fp16 + f32 copy (local dtype detect)
__global__ __launch_bounds__(256) void split_input3(
    const void* __restrict__ in, h16* __restrict__ hi, h16* __restrict__ lo,
    float* __restrict__ f32out, int n) {
  int f = detect_f32_local((const u16*)in);
  int stride = gridDim.x * 256;
  for (int i = blockIdx.x * 256 + threadIdx.x; i < n; i += stride) {
    float x = cvt_in(in, i, f);
    h16 h = (h16)x;
    hi[i] = h;
    lo[i] = (h16)(x - (float)h);
    if (f32out) f32out[i] = x;
  }
}

// split L (blocks 0..255) and W (blocks 256..319); local detect from X
__global__ __launch_bounds__(256) void split_LW(
    const void* __restrict__ Xin, const void* __restrict__ Lin,
    h16* __restrict__ Lhi, h16* __restrict__ Llo, const void* __restrict__ Win,
    h16* __restrict__ Whi, h16* __restrict__ Wlo) {
  int f = detect_f32_local((const u16*)Xin);
  int tid = threadIdx.x;
  if (blockIdx.x < 256) {
#pragma unroll
    for (int j = 0; j < 4; ++j) {
      int i = blockIdx.x * 1024 + j * 256 + tid;
      float x = cvt_in(Lin, i, f);
      h16 h = (h16)x;
      Lhi[i] = h;
      Llo[i] = (h16)(x - (float)h);
    }
  } else {
    int b = blockIdx.x - 256;
#pragma unroll
    for (int j = 0; j < 4; ++j) {
      int i = b * 1024 + j * 256 + tid;
      float x = cvt_in(Win, i, f);
      h16 h = (h16)x;
      Whi[i] = h;
      Wlo[i] = (h16)(x - (float)h);
    }
  }
}

// theta+bias conv + scalars (local detect from X)
__global__ __launch_bounds__(1024) void prep_small(
    const void* __restrict__ Xin, const void* __restrict__ theta,
    const void* __restrict__ bpin, const void* __restrict__ alpha,
    const void* __restrict__ rho_raw, float* __restrict__ thetaf,
    float* __restrict__ biasf, float* __restrict__ scal) {
  int f = detect_f32_local((const u16*)Xin);
  int tid = threadIdx.x;
  if (tid < 768)
    thetaf[tid] = cvt_in(theta, tid, f);
  else if (tid < 1024)
    biasf[tid - 768] = cvt_in(bpin, tid - 768, f);
  if (tid == 0) {
    float a[4], e[4], m = -1e30f, s = 0.f;
    for (int i = 0; i < 4; ++i) {
      a[i] = cvt_in(alpha, i, f);
      m = fmaxf(m, a[i]);
    }
    for (int i = 0; i < 4; ++i) { e[i] = expf(a[i] - m); s += e[i]; }
    for (int i = 0; i < 4; ++i) scal[i] = e[i] / s;
    float rr = cvt_in(rho_raw, 0, f);
    scal[4] = 1.f / (1.f + expf(-rr));
  }
}

// ---------------------------------------------------------------------------
// Split-precision NT GEMM (64x64 tile): alpha*(Ah Bh^T + Ah Bl^T + Al Bh^T)
// SPLITOUT=1: write hi/lo fp16 planes (Y path); else f32 C (+bias).
// ---------------------------------------------------------------------------
template <bool BIAS, bool SPLITOUT>
__global__ __launch_bounds__(256) void gemm3_nt(
    const h16* __restrict__ Ah, const h16* __restrict__ Al,
    const h16* __restrict__ Bh, const h16* __restrict__ Bl,
    float* __restrict__ C, h16* __restrict__ Yh, h16* __restrict__ Yl,
    const float* __restrict__ bias, float alpha, int M, int Nc, int Kd,
    long batchA, long batchB, long batchC) {
  const h16* Abh = Ah + (size_t)blockIdx.z * batchA;
  const h16* Abl = Al + (size_t)blockIdx.z * batchA;
  const h16* Bbh = Bh + (size_t)blockIdx.z * batchB;
  const h16* Bbl = Bl + (size_t)blockIdx.z * batchB;
  int bn = blockIdx.x, bm = blockIdx.y;
  int tid = threadIdx.x;
  int wid = tid >> 6, lane = tid & 63;
  __shared__ h16 Ash[64 * 40], Asl[64 * 40], Bsh[64 * 40], Bsl[64 * 40];
  f32x4 acc00 = {}, acc01 = {}, acc10 = {}, acc11 = {};
  int lr = tid >> 2;
  int lc = (tid & 3) << 3;
  size_t aoff = (size_t)(bm * 64 + lr) * Kd + lc;
  size_t boff = (size_t)(bn * 64 + lr) * Kd + lc;
  int wm = (wid & 1) * 32, wn = (wid >> 1) * 32;
  int fr = lane & 15;
  int fc = (lane >> 4) << 3;
  for (int k0 = 0; k0 < Kd; k0 += 32) {
    uint4 avh = *(const uint4*)(Abh + aoff + k0);
    uint4 avl = *(const uint4*)(Abl + aoff + k0);
    uint4 bvh = *(const uint4*)(Bbh + boff + k0);
    uint4 bvl = *(const uint4*)(Bbl + boff + k0);
    __syncthreads();
    *(uint4*)(Ash + lr * 40 + lc) = avh;
    *(uint4*)(Asl + lr * 40 + lc) = avl;
    *(uint4*)(Bsh + lr * 40 + lc) = bvh;
    *(uint4*)(Bsl + lr * 40 + lc) = bvl;
    __syncthreads();
    h16x8 a0h = *(const h16x8*)(Ash + (wm + fr) * 40 + fc);
    h16x8 a1h = *(const h16x8*)(Ash + (wm + 16 + fr) * 40 + fc);
    h16x8 b0h = *(const h16x8*)(Bsh + (wn + fr) * 40 + fc);
    h16x8 b1h = *(const h16x8*)(Bsh + (wn + 16 + fr) * 40 + fc);
    h16x8 a0l = *(const h16x8*)(Asl + (wm + fr) * 40 + fc);
    h16x8 a1l = *(const h16x8*)(Asl + (wm + 16 + fr) * 40 + fc);
    h16x8 b0l = *(const h16x8*)(Bsl + (wn + fr) * 40 + fc);
    h16x8 b1l = *(const h16x8*)(Bsl + (wn + 16 + fr) * 40 + fc);
    acc00 = mfma16(a0h, b0h, acc00);
    acc01 = mfma16(a0h, b1h, acc01);
    acc10 = mfma16(a1h, b0h, acc10);
    acc11 = mfma16(a1h, b1h, acc11);
    acc00 = mfma16(a0h, b0l, acc00);
    acc01 = mfma16(a0h, b1l, acc01);
    acc10 = mfma16(a1h, b0l, acc10);
    acc11 = mfma16(a1h, b1l, acc11);
    acc00 = mfma16(a0l, b0h, acc00);
    acc01 = mfma16(a0l, b1h, acc01);
    acc10 = mfma16(a1l, b0h, acc10);
    acc11 = mfma16(a1l, b1h, acc11);
  }
  int crow = (lane >> 4) << 2;
  int ccol = lane & 15;
  f32x4 accs[2][2] = {{acc00, acc01}, {acc10, acc11}};
#pragma unroll
  for (int i = 0; i < 2; ++i)
#pragma unroll
    for (int j = 0; j < 2; ++j) {
      int r0 = bm * 64 + wm + 16 * i + crow;
      int c0 = bn * 64 + wn + 16 * j + ccol;
#pragma unroll
      for (int rg = 0; rg < 4; ++rg) {
        size_t off = (size_t)(r0 + rg) * Nc + c0;
        float v = accs[i][j][rg] * alpha;
        if constexpr (SPLITOUT) {
          h16* Yhb = Yh + (size_t)blockIdx.z * batchC;
          h16* Ylb = Yl + (size_t)blockIdx.z * batchC;
          h16 hh = (h16)v;
          Yhb[off] = hh;
          Ylb[off] = (h16)(v - (float)hh);
        } else {
          if constexpr (BIAS) v += bias[c0];
          float* Cb = C + (size_t)blockIdx.z * batchC;
          Cb[off] = v;
        }
      }
    }
}

// ---------------------------------------------------------------------------
// Split-precision NT GEMM, 128x128 tile, global_load_lds staging, XOR swizzle.
// ---------------------------------------------------------------------------
__global__ __launch_bounds__(256) void gemm3_big(
    const h16* __restrict__ Ah, const h16* __restrict__ Al,
    const h16* __restrict__ Bh, const h16* __restrict__ Bl,
    float* __restrict__ C, float alpha, int M, int Nc, int Kd) {
  __shared__ h16 sAh[128 * 32], sAl[128 * 32], sBh[128 * 32], sBl[128 * 32];
  int tid = threadIdx.x, wid = tid >> 6, lane = tid & 63;
  int bm = blockIdx.y, bn = blockIdx.x;
  int srow = 32 * wid + (lane >> 2);
  int scnk = lane & 3;
  int fr = lane & 15, fcc = lane >> 4;
  f32x4 acc[4][4] = {};
  const h16* gA[2] = {Ah, Al};
  const h16* gB[2] = {Bh, Bl};
  h16* sA[2] = {sAh, sAl};
  h16* sB[2] = {sBh, sBl};
  int wm = (wid & 1) * 64, wn = (wid >> 1) * 64;
  for (int k0 = 0; k0 < Kd; k0 += 32) {
    __syncthreads();
#pragma unroll
    for (int h = 0; h < 2; ++h) {
      int r = srow + 16 * h;
      int cs = scnk ^ ((r >> 1) & 3);
      size_t goffA = (size_t)(bm * 128 + r) * Kd + k0 + cs * 8;
      size_t goffB = (size_t)(bn * 128 + r) * Kd + k0 + cs * 8;
      int loff = (32 * wid + 16 * h) * 32;
#pragma unroll
      for (int p = 0; p < 2; ++p) {
        gl_lds16(gA[p] + goffA, sA[p] + loff);
        gl_lds16(gB[p] + goffB, sB[p] + loff);
      }
    }
    __syncthreads();
    h16x8 fa[2][4], fb[2][4];
#pragma unroll
    for (int i = 0; i < 4; ++i) {
      int ra = wm + 16 * i + fr;
      int ca = (fcc ^ ((ra >> 1) & 3)) * 8;
      fa[0][i] = *(const h16x8*)(sAh + ra * 32 + ca);
      fa[1][i] = *(const h16x8*)(sAl + ra * 32 + ca);
      int rb = wn + 16 * i + fr;
      int cb = (fcc ^ ((rb >> 1) & 3)) * 8;
      fb[0][i] = *(const h16x8*)(sBh + rb * 32 + cb);
      fb[1][i] = *(const h16x8*)(sBl + rb * 32 + cb);
    }
#pragma unroll
    for (int i = 0; i < 4; ++i)
#pragma unroll
      for (int j = 0; j < 4; ++j) {
        acc[i][j] = mfma16(fa[0][i], fb[0][j], acc[i][j]);
        acc[i][j] = mfma16(fa[0][i], fb[1][j], acc[i][j]);
        acc[i][j] = mfma16(fa[1][i], fb[0][j], acc[i][j]);
      }
  }
  int crow = (lane >> 4) << 2, ccol = lane & 15;
#pragma unroll
  for (int i = 0; i < 4; ++i)
#pragma unroll
    for (int j = 0; j < 4; ++j) {
      int r0 = bm * 128 + wm + 16 * i + crow;
      int c0 = bn * 128 + wn + 16 * j + ccol;
#pragma unroll
      for (int rg = 0; rg < 4; ++rg)
        C[(size_t)(r0 + rg) * Nc + c0] = acc[i][j][rg] * alpha;
    }
}

// ---------------------------------------------------------------------------
// fp16 NT GEMM for all 4 heads' E@X, K-split: z = head*4 + kslice (Kc=1024).
// (round-10 measured config: 92 VGPR, 16 KB LDS, 1024 blocks = 4/CU)
// ---------------------------------------------------------------------------
__global__ __launch_bounds__(256) void gemm_ks4(
    const h16* __restrict__ Eall, const h16* __restrict__ B,
    float* __restrict__ Cpart) {
  __shared__ h16 sA[128 * 32], sB[128 * 32];
  int tid = threadIdx.x, wid = tid >> 6, lane = tid & 63;
  int bm = blockIdx.y, bn = blockIdx.x, zz = blockIdx.z;  // grid (2, 32, 16)
  int head = zz >> 2, kz = zz & 3;
  const h16* A = Eall + (size_t)head * 4096 * 4096;
  int kbase = kz * 1024;
  int srow = 32 * wid + (lane >> 2);
  int scnk = lane & 3;
  int fr = lane & 15, fcc = lane >> 4;
  f32x4 acc[4][4] = {};
  int wm = (wid & 1) * 64, wn = (wid >> 1) * 64;
  for (int k0 = 0; k0 < 1024; k0 += 32) {
    __syncthreads();
#pragma unroll
    for (int h = 0; h < 2; ++h) {
      int r = srow + 16 * h;
      int cs = scnk ^ ((r >> 1) & 3);
      size_t goffA = (size_t)(bm * 128 + r) * 4096 + kbase + k0 + cs * 8;
      size_t goffB = (size_t)(bn * 128 + r) * 4096 + kbase + k0 + cs * 8;
      int loff = (32 * wid + 16 * h) * 32;
      gl_lds16(A + goffA, sA + loff);
      gl_lds16(B + goffB, sB + loff);
    }
    __syncthreads();
    h16x8 fa[4], fb[4];
#pragma unroll
    for (int i = 0; i < 4; ++i) {
      int ra = wm + 16 * i + fr;
      int ca = (fcc ^ ((ra >> 1) & 3)) * 8;
      fa[i] = *(const h16x8*)(sA + ra * 32 + ca);
      int rb = wn + 16 * i + fr;
      int cb = (fcc ^ ((rb >> 1) & 3)) * 8;
      fb[i] = *(const h16x8*)(sB + rb * 32 + cb);
    }
#pragma unroll
    for (int i = 0; i < 4; ++i)
#pragma unroll
      for (int j = 0; j < 4; ++j)
        acc[i][j] = mfma16(fa[i], fb[j], acc[i][j]);
  }
  float* Cp = Cpart + (size_t)zz * 4096 * 256;
  int crow = (lane >> 4) << 2, ccol = lane & 15;
#pragma unroll
  for (int i = 0; i < 4; ++i)
#pragma unroll
    for (int j = 0; j < 4; ++j) {
      int r0 = bm * 128 + wm + 16 * i + crow;
      int c0 = bn * 128 + wn + 16 * j + ccol;
#pragma unroll
      for (int rg = 0; rg < 4; ++rg)
        Cp[(size_t)(r0 + rg) * 256 + c0] = acc[i][j][rg];
    }
}

// merged: blocks 0..1023 = ks_reduce4 (Zk); blocks 1024..1087 = hist_part
__global__ __launch_bounds__(256) void ksred_hist(
    const float* __restrict__ Cpart, const float* __restrict__ scal,
    const float* __restrict__ rowSinv, float* __restrict__ Zk,
    const float* __restrict__ topv, const int* __restrict__ topi,
    int* __restrict__ pCnt, float* __restrict__ pDv,
    float* __restrict__ DeIS) {
  __shared__ int lc[4096];
  __shared__ float ld[4096];
  int tid = threadIdx.x;
  if (blockIdx.x < 1024) {
    int i = (blockIdx.x * 256 + tid) * 4;
    int row = i >> 8;
    float4 out = {0.f, 0.f, 0.f, 0.f};
#pragma unroll
    for (int k = 0; k < 4; ++k) {
      float4 s = {0.f, 0.f, 0.f, 0.f};
#pragma unroll
      for (int z = 0; z < 4; ++z) {
        float4 p =
            *(const float4*)(Cpart + (size_t)(k * 4 + z) * 4096 * 256 + i);
        s.x += p.x; s.y += p.y; s.z += p.z; s.w += p.w;
      }
      float sc = scal[k] * rowSinv[k * 4096 + row];
      out.x += sc * s.x; out.y += sc * s.y;
      out.z += sc * s.z; out.w += sc * s.w;
    }
    *(float4*)(Zk + i) = out;
  } else {
    int b = blockIdx.x - 1024;  // 0..63
    for (int j = tid; j < 4096; j += 256) { lc[j] = 0; ld[j] = 0.f; }
    __syncthreads();
    int base = b * 4096;
#pragma unroll
    for (int j = 0; j < 16; ++j) {
      int t = base + j * 256 + tid;
      atomicAdd(&lc[topi[t]], 1);
      atomicAdd(&ld[topi[t]], topv[t]);
    }
    __syncthreads();
    for (int j = tid; j < 4096; j += 256) {
      pCnt[base + j] = lc[j];
      pDv[base + j] = ld[j];
    }
    int e = b * 256 + tid;
    const float4* p = (const float4*)(topv + ((size_t)e << 4));
    float4 a = p[0], bb = p[1], c = p[2], d = p[3];
    float s = ((a.x + a.y) + (a.z + a.w)) + ((bb.x + bb.y) + (bb.z + bb.w)) +
              ((c.x + c.y) + (c.z + c.w)) + ((d.x + d.y) + (d.z + d.w));
    DeIS[e] = 1.0f / sqrtf(s + 1e-9f);
  }
}

// 16-bit transpose
__global__ __launch_bounds__(256) void transpose16(
    const u16* __restrict__ in, u16* __restrict__ out, int rows, int cols) {
  __shared__ u16 t[32][33];
  const u16* ib = in + (size_t)blockIdx.z * rows * cols;
  u16* ob = out + (size_t)blockIdx.z * rows * cols;
  int r0 = blockIdx.x * 32, c0 = blockIdx.y * 32;
  int tx = threadIdx.x & 31, ty = threadIdx.x >> 5;
#pragma unroll
  for (int i = 0; i < 32; i += 8)
    t[ty + i][tx] = ib[(size_t)(r0 + ty + i) * cols + c0 + tx];
  __syncthreads();
#pragma unroll
  for (int i = 0; i < 32; i += 8)
    ob[(size_t)(c0 + ty + i) * rows + r0 + tx] = t[tx][ty + i];
}

// ---------------------------------------------------------------------------
// fused per-row (one wave per row): max -> threshold T -> exp/E-write +
// candidate push -> exact jax-tiebreak top-16 from candidates
// ---------------------------------------------------------------------------
__global__ __launch_bounds__(256) void row_softmax_topk(
    const float* __restrict__ A, float* __restrict__ topv,
    int* __restrict__ topi, h16* __restrict__ E, float* __restrict__ rowSinvK,
    int khead) {
  __shared__ u64 candK[4][256];
  __shared__ int candN[4];
  int wid = threadIdx.x >> 6, lane = threadIdx.x & 63;
  int row = blockIdx.x * 4 + wid;
  const float* arow = A + ((size_t)row << 12);
  if (lane == 0) candN[wid] = 0;
  __syncthreads();
  float lm = -INFINITY;
#pragma unroll
  for (int t = 0; t < 16; ++t) {
    float4 v = *(const float4*)(arow + (t << 8) + (lane << 2));
    lm = fmaxf(lm, fmaxf(fmaxf(v.x, v.y), fmaxf(v.z, v.w)));
  }
  float m = lm;
#pragma unroll
  for (int off = 32; off; off >>= 1) m = fmaxf(m, __shfl_xor(m, off));
  u64 lk = ((u64)fkey(lm) << 32) | (unsigned)lane;
  float T = 0.f;
  for (int r = 0; r < 16; ++r) {
    u64 k2 = wave_max_u64(lk);
    if (lk == k2) lk = 0;
    if (r == 15) T = unfkey((unsigned)(k2 >> 32));
  }
  h16* erow = E + ((size_t)row << 12);
  int* cn = &candN[wid];
  u64* ck = candK[wid];
  float s = 0.f;
  for (int t = 0; t < 16; ++t) {
    int c = (t << 8) + (lane << 2);
    float4 v = *(const float4*)(arow + c);
    float e0 = __expf(v.x - m), e1 = __expf(v.y - m);
    float e2 = __expf(v.z - m), e3 = __expf(v.w - m);
    s += (e0 + e1) + (e2 + e3);
    h16x4 hv = {(h16)e0, (h16)e1, (h16)e2, (h16)e3};
    *(h16x4*)(erow + c) = hv;
    if (v.x >= T) {
      int sl = atomicAdd(cn, 1);
      if (sl < 256) ck[sl] = ((u64)fkey(v.x) << 32) | (unsigned)(~(unsigned)c);
    }
    if (v.y >= T) {
      int sl = atomicAdd(cn, 1);
      if (sl < 256) ck[sl] = ((u64)fkey(v.y) << 32) | (unsigned)(~(unsigned)(c + 1));
    }
    if (v.z >= T) {
      int sl = atomicAdd(cn, 1);
      if (sl < 256) ck[sl] = ((u64)fkey(v.z) << 32) | (unsigned)(~(unsigned)(c + 2));
    }
    if (v.w >= T) {
      int sl = atomicAdd(cn, 1);
      if (sl < 256) ck[sl] = ((u64)fkey(v.w) << 32) | (unsigned)(~(unsigned)(c + 3));
    }
  }
#pragma unroll
  for (int off = 32; off; off >>= 1) s += __shfl_xor(s, off);
  if (lane == 0) rowSinvK[row] = 1.f / s;
  __syncthreads();
  int cnt = min(*cn, 256);
  u64 loc[4] = {0ull, 0ull, 0ull, 0ull};
  int nl = 0;
  for (int j = lane; j < cnt; j += 64)
    if (nl < 4) loc[nl++] = ck[j];
#define CSW(a, b)                     \
  {                                   \
    if (loc[b] > loc[a]) {            \
      u64 tt = loc[a];                \
      loc[a] = loc[b];                \
      loc[b] = tt;                    \
    }                                 \
  }
  CSW(0, 1) CSW(2, 3) CSW(0, 2) CSW(1, 3) CSW(1, 2)
#undef CSW
  float myv = 0.f;
  int myi = 0;
  float sum16 = 0.f;
  for (int r = 0; r < 16; ++r) {
    u64 key = loc[0];
    u64 k2 = wave_max_u64(key);
    float wv = unfkey((unsigned)(k2 >> 32));
    int wi = (int)(~(unsigned)(k2 & 0xffffffffu));
    if (key == k2 && key != 0ull) {
      loc[0] = loc[1];
      loc[1] = loc[2];
      loc[2] = loc[3];
      loc[3] = 0ull;
    }
    sum16 += expf(wv - m);
    if (r == lane) { myv = wv; myi = wi; }
  }
  if (lane < 16) {
    size_t o = (((size_t)khead << 12) + row) * 16 + lane;
    topv[o] = expf(myv - m) / (sum16 + 1e-9f * s);
    topi[o] = myi;
  }
}

// per-bin reduce over 64 blocks: cnt, Dvis, block prefix; + fused v0 init
__global__ __launch_bounds__(256) void col_scan(
    const int* __restrict__ pCnt, const float* __restrict__ pDv,
    int* __restrict__ cnt, float* __restrict__ Dvis,
    int* __restrict__ blockBase, float* __restrict__ v0) {
  int i = blockIdx.x * 256 + threadIdx.x;  // grid 16 -> 4096
  int run = 0;
  float dv = 0.f;
#pragma unroll
  for (int b = 0; b < 64; ++b) {
    blockBase[b * 4096 + i] = run;
    run += pCnt[b * 4096 + i];
    dv += pDv[b * 4096 + i];
  }
  cnt[i] = run;
  Dvis[i] = sqrtf(1.0f / (dv + 1e-9f));
  {
    int tid = i;
    unsigned j = (unsigned)(tid & 2047);
    unsigned x0 = j, x1 = j + 2048u;
    const unsigned ks0 = 0u, ks1 = 1u, ks2 = 0x1BD11BDAu;
#define TF_R(r)                                \
    {                                          \
      x0 += x1;                                \
      x1 = (x1 << (r)) | (x1 >> (32 - (r)));   \
      x1 ^= x0;                                \
    }
    x0 += ks0; x1 += ks1;
    TF_R(13) TF_R(15) TF_R(26) TF_R(6)  x0 += ks1; x1 += ks2 + 1u;
    TF_R(17) TF_R(29) TF_R(16) TF_R(24) x0 += ks2; x1 += ks0 + 2u;
    TF_R(13) TF_R(15) TF_R(26) TF_R(6)  x0 += ks0; x1 += ks1 + 3u;
    TF_R(17) TF_R(29) TF_R(16) TF_R(24) x0 += ks1; x1 += ks2 + 4u;
    TF_R(13) TF_R(15) TF_R(26) TF_R(6)  x0 += ks2; x1 += ks0 + 5u;
#undef TF_R
    unsigned bits = (tid < 2048) ? x0 : x1;
    float u01 = __uint_as_float((bits >> 9) | 0x3f800000u) - 1.0f;
    const float lo = -0.99999994f;
    float u = fmaxf(lo, u01 * 2.0f + lo);
    float w = -log1pf(-u * u);
    float p;
    if (w < 5.0f) {
      float t = w - 2.5f;
      p = 2.81022636e-08f;
      p = 3.43273939e-07f + p * t;
      p = -3.5233877e-06f + p * t;
      p = -4.39150654e-06f + p * t;
      p = 0.00021858087f + p * t;
      p = -0.00125372503f + p * t;
      p = -0.00417768164f + p * t;
      p = 0.246640727f + p * t;
      p = 1.50140941f + p * t;
    } else {
      float t = sqrtf(w) - 3.0f;
      p = -0.000200214257f;
      p = 0.000100950558f + p * t;
      p = 0.00134934322f + p * t;
      p = -0.00367342844f + p * t;
      p = 0.00573950773f + p * t;
      p = -0.0076224613f + p * t;
      p = 0.00943887047f + p * t;
      p = 1.00167406f + p * t;
      p = 2.83297682f + p * t;
    }
    v0[tid] = 1.41421354f * (p * u);
  }
}

// exclusive scan of cnt[4096] -> rowptr[4097]
__global__ __launch_bounds__(256) void scan_rowptr(const int* __restrict__ cnt,
                                                   int* __restrict__ rowptr) {
  __shared__ int part[256];
  int tid = threadIdx.x;
  int base = tid * 16;
  int loc[16];
  int s = 0;
#pragma unroll
  for (int j = 0; j < 16; ++j) { loc[j] = s; s += cnt[base + j]; }
  part[tid] = s;
  __syncthreads();
  for (int off = 1; off < 256; off <<= 1) {
    int v = (tid >= off) ? part[tid - off] : 0;
    __syncthreads();
    part[tid] += v;
    __syncthreads();
  }
  int pre = (tid == 0) ? 0 : part[tid - 1];
#pragma unroll
  for (int j = 0; j < 16; ++j) rowptr[base + j] = pre + loc[j];
  if (tid == 255) rowptr[4096] = part[255];
}

// fill cvals + CSR transpose via LDS cursors (no global atomics)
__global__ __launch_bounds__(256) void csr_fill3(
    const float* __restrict__ topv, const int* __restrict__ topi,
    const float* __restrict__ Dvis, const float* __restrict__ DeIS,
    const int* __restrict__ rowptr, const int* __restrict__ blockBase,
    float* __restrict__ cvals, int* __restrict__ colE,
    float* __restrict__ cvalR) {
  __shared__ int lcur[4096];
  int tid = threadIdx.x, b = blockIdx.x;  // grid 64
  int base = b * 4096;
  for (int j = tid; j < 4096; j += 256)
    lcur[j] = rowptr[j] + blockBase[base + j];
  __syncthreads();
#pragma unroll
  for (int j = 0; j < 16; ++j) {
    int t = base + j * 256 + tid;
    int i = topi[t];
    int e = t >> 4;
    float c = Dvis[i] * topv[t] * DeIS[e];
    cvals[t] = c;
    int slot = atomicAdd(&lcur[i], 1);
    colE[slot] = e;
    cvalR[slot] = c;
  }
}

// g[e] = sum_p c[e,p] * v[idx[e,p]]
__global__ __launch_bounds__(256) void spmv_edge(
    const float* __restrict__ cvals, const int* __restrict__ topi,
    const float* __restrict__ v, float* __restrict__ g) {
  int e = blockIdx.x * 256 + threadIdx.x;  // grid 64
  float acc = 0.f;
#pragma unroll
  for (int p = 0; p < 16; ++p)
    acc += cvals[e * 16 + p] * v[topi[e * 16 + p]];
  g[e] = acc;
}

// vout[i] = vin[i] - sum_{j in row i} cvalR[j]*g[colE[j]]
__global__ __launch_bounds__(256) void spmv_row(
    const int* __restrict__ rowptr, const int* __restrict__ colE,
    const float* __restrict__ cvalR, const float* __restrict__ g,
    const float* __restrict__ vin, float* __restrict__ vout) {
  int wid = threadIdx.x >> 6, lane = threadIdx.x & 63;
  int row = blockIdx.x * 4 + wid;  // grid 1024
  int s = rowptr[row], e = rowptr[row + 1];
  float acc = 0.f;
  for (int j = s + lane; j < e; j += 64) acc += cvalR[j] * g[colE[j]];
#pragma unroll
  for (int off = 32; off; off >>= 1) acc += __shfl_xor(acc, off);
  if (lane == 0) vout[row] = vin[row] - acc;
}

// lam = clip((w5.w6)/(w5.w5), 1e-3) -> scal[5]
__global__ __launch_bounds__(256) void pi_dots(const float* __restrict__ w5,
                                               const float* __restrict__ w6,
                                               float* __restrict__ scal) {
  __shared__ float r1[256], r2[256];
  int tid = threadIdx.x;
  float a = 0.f, b = 0.f;
  for (int i = tid; i < 4096; i += 256) {
    float x = w5[i];
    a += x * x;
    b += x * w6[i];
  }
  r1[tid] = a; r2[tid] = b;
  __syncthreads();
  for (int off = 128; off; off >>= 1) {
    if (tid < off) { r1[tid] += r1[tid + off]; r2[tid] += r2[tid + off]; }
    __syncthreads();
  }
  if (tid == 0) scal[5] = fmaxf(r2[0] / r1[0], 1e-3f);
}

// G[e,:] = sum_p c[e,p] * M[idx[e,p],:]  — MLP-unrolled
__global__ __launch_bounds__(256) void spmm_edge(
    const float* __restrict__ cvals, const int* __restrict__ topi,
    const float* __restrict__ M, float* __restrict__ G) {
  int wid = threadIdx.x >> 6, lane = threadIdx.x & 63;
  int e = blockIdx.x * 4 + wid;  // grid 4096
  int cb = lane << 2;
  const float* cv = cvals + ((size_t)e << 4);
  const int* ti = topi + ((size_t)e << 4);
  float cc[16];
  int ix[16];
#pragma unroll
  for (int p = 0; p < 16; ++p) { cc[p] = cv[p]; ix[p] = ti[p]; }
  float4 acc[4] = {};
#pragma unroll
  for (int h = 0; h < 2; ++h) {
    float4 g[8];
#pragma unroll
    for (int p = 0; p < 8; ++p)
      g[p] = *(const float4*)(M + ((size_t)ix[h * 8 + p] << 8) + cb);
#pragma unroll
    for (int p = 0; p < 8; ++p) {
      float c = cc[h * 8 + p];
      float4 gg = g[p];
      int a = p & 3;
      acc[a].x += c * gg.x; acc[a].y += c * gg.y;
      acc[a].z += c * gg.z; acc[a].w += c * gg.w;
    }
  }
  float4 r;
  r.x = (acc[0].x + acc[1].x) + (acc[2].x + acc[3].x);
  r.y = (acc[0].y + acc[1].y) + (acc[2].y + acc[3].y);
  r.z = (acc[0].z + acc[1].z) + (acc[2].z + acc[3].z);
  r.w = (acc[0].w + acc[1].w) + (acc[2].w + acc[3].w);
  *(float4*)(G + ((size_t)e << 8) + cb) = r;
}

// Z = S_norm @ M via CSR rows + fused epilogues
template <int MODE>
__global__ __launch_bounds__(256) void spmm_row_ep(
    const int* __restrict__ rowptr, const int* __restrict__ colE,
    const float* __restrict__ cvalR, const float* __restrict__ G,
    const float* __restrict__ Xf, float* __restrict__ T1,
    const float* __restrict__ Zk, const float* __restrict__ thetaf,
    const float* __restrict__ scal, h16* __restrict__ Zmh,
    h16* __restrict__ Zml) {
  int wid = threadIdx.x >> 6, lane = threadIdx.x & 63;
  int row = blockIdx.x * 4 + wid;  // grid 1024
  int cb = lane << 2;
  int s = rowptr[row], e = rowptr[row + 1];
  float4 acc[4] = {};
  int j = s;
  for (; j + 8 <= e; j += 8) {
    int ix[8];
    float cc[8];
#pragma unroll
    for (int t = 0; t < 8; ++t) { ix[t] = colE[j + t]; cc[t] = cvalR[j + t]; }
    float4 g[8];
#pragma unroll
    for (int t = 0; t < 8; ++t)
      g[t] = *(const float4*)(G + ((size_t)ix[t] << 8) + cb);
#pragma unroll
    for (int t = 0; t < 8; ++t) {
      float c = cc[t];
      float4 gg = g[t];
      int a = t & 3;
      acc[a].x += c * gg.x; acc[a].y += c * gg.y;
      acc[a].z += c * gg.z; acc[a].w += c * gg.w;
    }
  }
  for (; j < e; ++j) {
    float c = cvalR[j];
    float4 gg = *(const float4*)(G + ((size_t)colE[j] << 8) + cb);
    acc[0].x += c * gg.x; acc[0].y += c * gg.y;
    acc[0].z += c * gg.z; acc[0].w += c * gg.w;
  }
  float4 z;
  z.x = (acc[0].x + acc[1].x) + (acc[2].x + acc[3].x);
  z.y = (acc[0].y + acc[1].y) + (acc[2].y + acc[3].y);
  z.z = (acc[0].z + acc[1].z) + (acc[2].z + acc[3].z);
  z.w = (acc[0].w + acc[1].w) + (acc[2].w + acc[3].w);
  size_t o = ((size_t)row << 8) + cb;
  float c1 = 2.0f / scal[5];
  float4 x = *(const float4*)(Xf + o);
  if constexpr (MODE == 1) {
    float4 t1;
    t1.x = (c1 - 1.0f) * x.x - c1 * z.x;
    t1.y = (c1 - 1.0f) * x.y - c1 * z.y;
    t1.z = (c1 - 1.0f) * x.z - c1 * z.z;
    t1.w = (c1 - 1.0f) * x.w - c1 * z.w;
    *(float4*)(T1 + o) = t1;
  } else {
    float rho = scal[4];
    float4 t1 = *(const float4*)(T1 + o);
    float4 zk = *(const float4*)(Zk + o);
    h16x4 hh, hl;
#pragma unroll
    for (int q = 0; q < 4; ++q) {
      float xv = (&x.x)[q], t1v = (&t1.x)[q], zv = (&z.x)[q], zkv = (&zk.x)[q];
      int d = cb + q;
      float t2 = 2.0f * ((c1 - 1.0f) * t1v - c1 * zv) - xv;
      float oo = xv * thetaf[d] + t1v * thetaf[256 + d] + t2 * thetaf[512 + d];
      float zs = oo > 0.0f ? oo : expm1f(oo);
      float zm = rho * zs + (1.0f - rho) * zkv;
      h16 h = (h16)zm;
      hh[q] = h;
      hl[q] = (h16)(zm - (float)h);
    }
    *(h16x4*)(Zmh + o) = hh;
    *(h16x4*)(Zml + o) = hl;
  }
}

// ---------------------------------------------------------------------------
extern "C" void kernel_launch(void* const* d_in, const int* in_sizes, int n_in,
                              void* d_out, int out_size, void* d_ws,
                              size_t ws_size, hipStream_t stream) {
  (void)in_sizes; (void)n_in; (void)out_size;
  const void* Xin = d_in[0];
  const void* Lin = d_in[1];
  const void* alpha = d_in[2];
  const void* theta = d_in[3];
  const void* rho_raw = d_in[4];
  const void* Wpin = d_in[5];
  const void* bpin = d_in[6];
  float* out = (float*)d_out;

  char* base = (char*)d_ws;
  size_t off = 0;
  auto alloc = [&](size_t bytes) -> char* {
    char* p = base + off;
    off += (bytes + 255) & ~(size_t)255;
    return p;
  };
  float* Abuf = (float*)alloc((size_t)4096 * 4096 * 4);   // A; 16 ks-partials; G
  h16* Eall = (h16*)alloc((size_t)4 * 4096 * 4096 * 2);   // 4 E planes
  h16* Yhi = (h16*)alloc((size_t)4 * 4096 * 256 * 2);
  h16* Ylo = (h16*)alloc((size_t)4 * 4096 * 256 * 2);
  h16* Xhi = (h16*)alloc((size_t)4096 * 256 * 2);
  h16* Xlo = (h16*)alloc((size_t)4096 * 256 * 2);
  float* Xf = (float*)alloc((size_t)4096 * 256 * 4);
  h16* XT = (h16*)alloc((size_t)256 * 4096 * 2);
  h16* Lhi = (h16*)alloc((size_t)4 * 256 * 256 * 2);
  h16* Llo = (h16*)alloc((size_t)4 * 256 * 256 * 2);   // contiguous after Lhi
  h16* LThi = (h16*)alloc((size_t)4 * 256 * 256 * 2);
  h16* LTlo = (h16*)alloc((size_t)4 * 256 * 256 * 2);  // contiguous after LThi
  h16* Whi = (h16*)alloc((size_t)256 * 256 * 2);
  h16* Wlo = (h16*)alloc((size_t)256 * 256 * 2);
  float* Zk = (float*)alloc((size_t)4096 * 256 * 4);
  float* T1 = (float*)alloc((size_t)4096 * 256 * 4);
  h16* Zmh = (h16*)alloc((size_t)4096 * 256 * 2);
  h16* Zml = (h16*)alloc((size_t)4096 * 256 * 2);
  float* topv = (float*)alloc((size_t)4 * 4096 * 16 * 4);
  int* topi = (int*)alloc((size_t)4 * 4096 * 16 * 4);
  float* cvals = (float*)alloc((size_t)262144 * 4);
  int* colE = (int*)alloc((size_t)262144 * 4);
  float* cvalR = (float*)alloc((size_t)262144 * 4);
  int* pCnt = (int*)alloc((size_t)64 * 4096 * 4);
  float* pDv = (float*)alloc((size_t)64 * 4096 * 4);
  int* blockBase = (int*)alloc((size_t)64 * 4096 * 4);
  int* rowptr = (int*)alloc(4097 * 4);
  int* cnt = (int*)alloc(4096 * 4);
  float* Dvis = (float*)alloc(4096 * 4);
  float* DeIS = (float*)alloc(16384 * 4);
  float* gE = (float*)alloc(16384 * 4);
  float* wA = (float*)alloc(4096 * 4);
  float* wB = (float*)alloc(4096 * 4);
  float* rowSinv = (float*)alloc((size_t)4 * 4096 * 4);
  float* thetaf = (float*)alloc(768 * 4);
  float* biasf = (float*)alloc(256 * 4);
  float* scal = (float*)alloc(256);
  if (off > ws_size) return;
  float* Kpart = Abuf;  // 64 MB: 16 partial planes; A dead by then
  float* G = Abuf;      // 16 MB alias; partials dead after ksred_hist

  split_input3<<<1024, 256, 0, stream>>>(Xin, Xhi, Xlo, Xf, 4096 * 256);
  split_LW<<<320, 256, 0, stream>>>(Xin, Lin, Lhi, Llo, Wpin, Whi, Wlo);
  prep_small<<<1, 1024, 0, stream>>>(Xin, theta, bpin, alpha, rho_raw, thetaf,
                                     biasf, scal);
  transpose16<<<dim3(128, 8, 1), 256, 0, stream>>>((const u16*)Xhi, (u16*)XT,
                                                   4096, 256);
  // both L planes (Lhi|Llo contiguous -> LThi|LTlo contiguous), z = 8
  transpose16<<<dim3(8, 8, 8), 256, 0, stream>>>((const u16*)Lhi, (u16*)LThi,
                                                 256, 256);
  // Y = X @ L_k (split fp16, fused), hi/lo written directly, batched z=4
  gemm3_nt<false, true><<<dim3(4, 64, 4), 256, 0, stream>>>(
      Xhi, Xlo, LThi, LTlo, nullptr, Yhi, Ylo, nullptr, 1.0f, 4096, 256, 256,
      0L, 256L * 256L, 4096L * 256L);
  for (int k = 0; k < 4; ++k) {
    gemm3_big<<<dim3(32, 32), 256, 0, stream>>>(
        Yhi + (size_t)k * 4096 * 256, Ylo + (size_t)k * 4096 * 256, Xhi, Xlo,
        Abuf, 0.0625f, 4096, 4096, 256);
    row_softmax_topk<<<1024, 256, 0, stream>>>(
        Abuf, topv, topi, Eall + (size_t)k * 4096 * 4096, rowSinv + k * 4096,
        k);
  }
  // all 4 heads' E @ X in one K-split launch (1024 blocks = 4/CU)
  gemm_ks4<<<dim3(2, 32, 16), 256, 0, stream>>>(Eall, XT, Kpart);
  // Zk reduce (blocks 0..1023) + histogram build (blocks 1024..1087)
  ksred_hist<<<1088, 256, 0, stream>>>(Kpart, scal, rowSinv, Zk, topv, topi,
                                       pCnt, pDv, DeIS);
  col_scan<<<16, 256, 0, stream>>>(pCnt, pDv, cnt, Dvis, blockBase, wA);
  scan_rowptr<<<1, 256, 0, stream>>>(cnt, rowptr);
  csr_fill3<<<64, 256, 0, stream>>>(topv, topi, Dvis, DeIS, rowptr, blockBase,
                                    cvals, colE, cvalR);
  // power iteration (regular launches — cooperative launch fails graph capture)
  for (int it = 0; it < 6; ++it) {
    const float* vi = (it & 1) ? wB : wA;
    float* vo = (it & 1) ? wA : wB;
    spmv_edge<<<64, 256, 0, stream>>>(cvals, topi, vi, gE);
    spmv_row<<<1024, 256, 0, stream>>>(rowptr, colE, cvalR, gE, vi, vo);
  }
  pi_dots<<<1, 256, 0, stream>>>(wB, wA, scal);
  // SnX -> T1 (fused) ; SnT1 -> cheb/elu/mix -> Zmh/Zml (fused)
  spmm_edge<<<4096, 256, 0, stream>>>(cvals, topi, Xf, G);
  spmm_row_ep<1><<<1024, 256, 0, stream>>>(rowptr, colE, cvalR, G, Xf, T1,
                                           nullptr, thetaf, scal, nullptr,
                                           nullptr);
  spmm_edge<<<4096, 256, 0, stream>>>(cvals, topi, T1, G);
  spmm_row_ep<2><<<1024, 256, 0, stream>>>(rowptr, colE, cvalR, G, Xf, T1, Zk,
                                           thetaf, scal, Zmh, Zml);
  // out = Zmix @ proj_w^T + proj_b (split fp16, f32 out)
  gemm3_nt<true, false><<<dim3(4, 64, 1), 256, 0, stream>>>(
      Zmh, Zml, Whi, Wlo, out, nullptr, nullptr, biasf, 1.0f, 4096, 256, 256,
      0L, 0L, 0L);
}